// Round 1
// baseline (2019.261 us; speedup 1.0000x reference)
//
#include <hip/hip_runtime.h>
#include <hip/hip_bf16.h>
#include <math.h>

// Problem constants
constexpr int DM = 1024;   // d_model
constexpr int SEQ = 2048;  // sequence length
constexpr int BATCH = 2;
constexpr int NH = 16;     // heads
constexpr int DH = 64;     // head dim
constexpr int MROWS = BATCH * SEQ;  // 4096
constexpr float SCALE = 0.125f;     // 1/sqrt(64)

// ---------------- Tiled fp32 GEMM: C[64x64 tile] = A[M,K] @ W[K,N] ----------
#define GTILE 64
#define GBK   16
#define GLDSP 68   // pad to 68 floats: keeps 16B alignment, breaks bank stride

__device__ __forceinline__ void gemm_tile_compute(const float* __restrict__ A,
                                                  const float* __restrict__ W,
                                                  int row0, int col0,
                                                  float (&acc)[4][4]) {
    __shared__ float As[GBK][GLDSP];
    __shared__ float Ws[GBK][GLDSP];
    const int tid = threadIdx.x;
    const int tx = tid & 15;        // col group (4 cols each)
    const int ty = tid >> 4;        // row group (4 rows each)
    const int ac = tid & 15;        // A-load k-col
    const int ar = tid >> 4;        // A-load row base
    const int wn = tid & 63;        // W-load n-col
    const int wc = tid >> 6;        // W-load k-row base

#pragma unroll
    for (int i = 0; i < 4; i++)
#pragma unroll
        for (int j = 0; j < 4; j++) acc[i][j] = 0.f;

    for (int kk = 0; kk < DM; kk += GBK) {
        __syncthreads();
#pragma unroll
        for (int q = 0; q < 4; q++) {
            int r = ar + 16 * q;
            As[ac][r] = A[(size_t)(row0 + r) * DM + kk + ac];
        }
#pragma unroll
        for (int q = 0; q < 4; q++) {
            int c = wc + 4 * q;
            Ws[c][wn] = W[(size_t)(kk + c) * DM + col0 + wn];
        }
        __syncthreads();
#pragma unroll
        for (int c = 0; c < GBK; c++) {
            float4 av = *(const float4*)&As[c][ty * 4];
            float4 wv = *(const float4*)&Ws[c][tx * 4];
            float a_[4] = {av.x, av.y, av.z, av.w};
            float w_[4] = {wv.x, wv.y, wv.z, wv.w};
#pragma unroll
            for (int i = 0; i < 4; i++)
#pragma unroll
                for (int j = 0; j < 4; j++)
                    acc[i][j] = fmaf(a_[i], w_[j], acc[i][j]);
        }
    }
}

// QKV projection: out layout [B, H, S, DH], bias fused. gridDim.z selects q/k/v.
__global__ __launch_bounds__(256) void qkv_gemm(
    const float* __restrict__ x,
    const float* __restrict__ Wq, const float* __restrict__ Wk, const float* __restrict__ Wv,
    const float* __restrict__ bq, const float* __restrict__ bk, const float* __restrict__ bv,
    float* __restrict__ q, float* __restrict__ k, float* __restrict__ v) {
    const float* W; const float* bias; float* out;
    if (blockIdx.z == 0)      { W = Wq; bias = bq; out = q; }
    else if (blockIdx.z == 1) { W = Wk; bias = bk; out = k; }
    else                      { W = Wv; bias = bv; out = v; }

    const int row0 = blockIdx.y * GTILE;
    const int col0 = blockIdx.x * GTILE;
    float acc[4][4];
    gemm_tile_compute(x, W, row0, col0, acc);

    const int tx = threadIdx.x & 15, ty = threadIdx.x >> 4;
    const int h = col0 / DH;            // tile width == DH, so one head per tile
    const int d0 = tx * 4;
#pragma unroll
    for (int i = 0; i < 4; i++) {
        int m = row0 + ty * 4 + i;
        int b = m >> 11;                // m / SEQ
        int s = m & (SEQ - 1);
        float4 val;
        val.x = acc[i][0] + bias[col0 + d0 + 0];
        val.y = acc[i][1] + bias[col0 + d0 + 1];
        val.z = acc[i][2] + bias[col0 + d0 + 2];
        val.w = acc[i][3] + bias[col0 + d0 + 3];
        float* dst = out + ((size_t)((b * NH + h) * SEQ + s)) * DH + d0;
        *(float4*)dst = val;
    }
}

// Output projection: plain [M, DM] output with bias.
__global__ __launch_bounds__(256) void out_gemm(
    const float* __restrict__ ctx, const float* __restrict__ Wo,
    const float* __restrict__ bo, float* __restrict__ out) {
    const int row0 = blockIdx.y * GTILE;
    const int col0 = blockIdx.x * GTILE;
    float acc[4][4];
    gemm_tile_compute(ctx, Wo, row0, col0, acc);

    const int tx = threadIdx.x & 15, ty = threadIdx.x >> 4;
    const int n0 = col0 + tx * 4;
#pragma unroll
    for (int i = 0; i < 4; i++) {
        int m = row0 + ty * 4 + i;
        float4 val;
        val.x = acc[i][0] + bo[n0 + 0];
        val.y = acc[i][1] + bo[n0 + 1];
        val.z = acc[i][2] + bo[n0 + 2];
        val.w = acc[i][3] + bo[n0 + 3];
        *(float4*)&out[(size_t)m * DM + n0] = val;
    }
}

// ---------------- Partial RoPE on q and k, [B,H,S,DH] layout ----------------
// rot dim 16, half 8: new[d] = t[d]*cos - t[d+8]*sin; new[d+8] = t[d]*sin + t[d+8]*cos
__global__ __launch_bounds__(256) void rope_kernel(float* __restrict__ q,
                                                   float* __restrict__ k) {
    const int idx = blockIdx.x * 256 + threadIdx.x;   // [0, 2*B*H*S*8)
    const int d = idx & 7;
    const int row = idx >> 3;                          // [0, 2*B*H*S)
    constexpr int NROWS = BATCH * NH * SEQ;            // 65536
    float* t = (row < NROWS) ? q : k;
    const int r = row & (NROWS - 1);
    const int s = r & (SEQ - 1);                       // position
    const float inv_freq = __expf(-(float)d * (logf(10000.f) / 8.f));
    const float ang = (float)s * inv_freq;
    float c, si;
    __sincosf(ang, &si, &c);
    float* base = t + (size_t)r * DH;
    const float t1 = base[d];
    const float t2 = base[d + 8];
    base[d]     = t1 * c - t2 * si;
    base[d + 8] = t1 * si + t2 * c;
}

// ---------------- Causal flash attention, fp32 -------------------------------
// One block per (bh, q-block of 256 rows). One thread per q row.
// K/V tiles of 64 rows staged in LDS. Online softmax with lazy rescale.
#define QBLK 256
#define KBLK 64

__global__ __launch_bounds__(256) void attn_kernel(
    const float* __restrict__ q, const float* __restrict__ k,
    const float* __restrict__ v, float* __restrict__ ctx) {
    const int bh = blockIdx.y;
    const int q0 = blockIdx.x * QBLK;
    const float* qb = q + (size_t)bh * SEQ * DH;
    const float* kb = k + (size_t)bh * SEQ * DH;
    const float* vb = v + (size_t)bh * SEQ * DH;
    const int tid = threadIdx.x;
    const int my_q = q0 + tid;

    float qr[DH];
#pragma unroll
    for (int d = 0; d < DH; d++) qr[d] = qb[(size_t)my_q * DH + d];

    float o[DH];
#pragma unroll
    for (int d = 0; d < DH; d++) o[d] = 0.f;
    float m = -INFINITY, l = 0.f;

    __shared__ float Kt[KBLK][DH];
    __shared__ float Vt[KBLK][DH];

    const int kmax = q0 + QBLK;   // exclusive upper bound of needed keys
    for (int kb0 = 0; kb0 < kmax; kb0 += KBLK) {
        __syncthreads();
        // cooperative tile load: 4096 floats each = 4 float4 per thread
#pragma unroll
        for (int jj = 0; jj < 4; jj++) {
            int e = tid + jj * 256;
            int r = e >> 4, c4 = (e & 15) << 2;
            *(float4*)&Kt[r][c4] = *(const float4*)&kb[(size_t)(kb0 + r) * DH + c4];
            *(float4*)&Vt[r][c4] = *(const float4*)&vb[(size_t)(kb0 + r) * DH + c4];
        }
        __syncthreads();

        const int jend = min(KBLK, my_q - kb0 + 1);  // causal: key <= my_q
        for (int j = 0; j < jend; j++) {
            float s = 0.f;
#pragma unroll
            for (int d = 0; d < DH; d++) s = fmaf(qr[d], Kt[j][d], s);
            s *= SCALE;
            if (s > m) {
                float corr = __expf(m - s);   // first iter: exp(-inf)=0
                l *= corr;
#pragma unroll
                for (int d = 0; d < DH; d++) o[d] *= corr;
                m = s;
            }
            float p = __expf(s - m);
            l += p;
#pragma unroll
            for (int d = 0; d < DH; d++) o[d] = fmaf(p, Vt[j][d], o[d]);
        }
    }

    const float inv_l = 1.f / l;
    const int b = bh >> 4, h = bh & 15;
    float* outp = ctx + ((size_t)(b * SEQ + my_q)) * DM + h * DH;
#pragma unroll
    for (int d = 0; d < DH; d++) outp[d] = o[d] * inv_l;
}

// ---------------- launch ------------------------------------------------------
extern "C" void kernel_launch(void* const* d_in, const int* in_sizes, int n_in,
                              void* d_out, int out_size, void* d_ws, size_t ws_size,
                              hipStream_t stream) {
    const float* x  = (const float*)d_in[0];
    const float* Wq = (const float*)d_in[1];
    const float* bq = (const float*)d_in[2];
    const float* Wk = (const float*)d_in[3];
    const float* bk = (const float*)d_in[4];
    const float* Wv = (const float*)d_in[5];
    const float* bv = (const float*)d_in[6];
    const float* Wo = (const float*)d_in[7];
    const float* bo = (const float*)d_in[8];
    float* out = (float*)d_out;

    // workspace: q, k, v in [B,H,S,DH], ctx in [B,S,DM] — 16 MiB each, 64 MiB total
    constexpr size_t TSZ = (size_t)BATCH * NH * SEQ * DH;  // 4194304 floats
    float* q   = (float*)d_ws;
    float* k   = q + TSZ;
    float* v   = k + TSZ;
    float* ctx = v + TSZ;

    // 1) QKV projections (+bias, head layout)
    qkv_gemm<<<dim3(DM / GTILE, MROWS / GTILE, 3), 256, 0, stream>>>(
        x, Wq, Wk, Wv, bq, bk, bv, q, k, v);

    // 2) partial RoPE on q and k
    const int rope_items = 2 * BATCH * NH * SEQ * 8;      // 1048576
    rope_kernel<<<rope_items / 256, 256, 0, stream>>>(q, k);

    // 3) causal attention -> ctx [B,S,DM]
    attn_kernel<<<dim3(SEQ / QBLK, BATCH * NH), 256, 0, stream>>>(q, k, v, ctx);

    // 4) output projection
    out_gemm<<<dim3(DM / GTILE, MROWS / GTILE), 256, 0, stream>>>(ctx, Wo, bo, out);
}

// Round 2
// 656.022 us; speedup vs baseline: 3.0780x; 3.0780x over previous
//
#include <hip/hip_runtime.h>
#include <hip/hip_bf16.h>
#include <math.h>

// Problem constants
constexpr int DM = 1024;   // d_model
constexpr int SEQ = 2048;  // sequence length
constexpr int BATCH = 2;
constexpr int NH = 16;     // heads
constexpr int DH = 64;     // head dim
constexpr int MROWS = BATCH * SEQ;  // 4096
constexpr float SCALE = 0.125f;     // 1/sqrt(64)

typedef __attribute__((ext_vector_type(8))) short short8;
typedef __attribute__((ext_vector_type(4))) float f32x4;

__device__ __forceinline__ unsigned short f2b(float f) {
    __hip_bfloat16 h = __float2bfloat16(f);
    return __builtin_bit_cast(unsigned short, h);
}
__device__ __forceinline__ float b2f(unsigned short u) {
    unsigned int t = ((unsigned int)u) << 16;
    return __builtin_bit_cast(float, t);
}

// ---------------- Tiled fp32 GEMM core: 64x64 tile, BK=16 -------------------
#define GTILE 64
#define GBK   16
#define GLDSP 68

__device__ __forceinline__ void gemm_tile_compute(const float* __restrict__ A,
                                                  const float* __restrict__ W,
                                                  int row0, int col0,
                                                  float (&acc)[4][4]) {
    __shared__ float As[GBK][GLDSP];
    __shared__ float Ws[GBK][GLDSP];
    const int tid = threadIdx.x;
    const int tx = tid & 15;
    const int ty = tid >> 4;
    const int ac = tid & 15;
    const int ar = tid >> 4;
    const int wn = tid & 63;
    const int wc = tid >> 6;

#pragma unroll
    for (int i = 0; i < 4; i++)
#pragma unroll
        for (int j = 0; j < 4; j++) acc[i][j] = 0.f;

    for (int kk = 0; kk < DM; kk += GBK) {
        __syncthreads();
#pragma unroll
        for (int q = 0; q < 4; q++) {
            int r = ar + 16 * q;
            As[ac][r] = A[(size_t)(row0 + r) * DM + kk + ac];
        }
#pragma unroll
        for (int q = 0; q < 4; q++) {
            int c = wc + 4 * q;
            Ws[c][wn] = W[(size_t)(kk + c) * DM + col0 + wn];
        }
        __syncthreads();
#pragma unroll
        for (int c = 0; c < GBK; c++) {
            float4 av = *(const float4*)&As[c][ty * 4];
            float4 wv = *(const float4*)&Ws[c][tx * 4];
            float a_[4] = {av.x, av.y, av.z, av.w};
            float w_[4] = {wv.x, wv.y, wv.z, wv.w};
#pragma unroll
            for (int i = 0; i < 4; i++)
#pragma unroll
                for (int j = 0; j < 4; j++)
                    acc[i][j] = fmaf(a_[i], w_[j], acc[i][j]);
        }
    }
}

// QKV projection. z=0: q -> bf16 [B,H,S,DH]; z=1: k -> bf16 [B,H,S,DH];
// z=2: v -> bf16 TRANSPOSED [B,H,DH,S] so attention's V reads are contiguous.
__global__ __launch_bounds__(256) void qkv_gemm(
    const float* __restrict__ x,
    const float* __restrict__ Wq, const float* __restrict__ Wk, const float* __restrict__ Wv,
    const float* __restrict__ bq, const float* __restrict__ bk, const float* __restrict__ bv,
    unsigned short* __restrict__ qb, unsigned short* __restrict__ kb,
    unsigned short* __restrict__ vtb) {
    const float* W; const float* bias;
    if (blockIdx.z == 0)      { W = Wq; bias = bq; }
    else if (blockIdx.z == 1) { W = Wk; bias = bk; }
    else                      { W = Wv; bias = bv; }

    const int row0 = blockIdx.y * GTILE;
    const int col0 = blockIdx.x * GTILE;
    float acc[4][4];
    gemm_tile_compute(x, W, row0, col0, acc);

    const int tx = threadIdx.x & 15, ty = threadIdx.x >> 4;
    const int h = col0 >> 6;            // one head per 64-wide tile
    const int d0 = tx * 4;

    if (blockIdx.z < 2) {
        unsigned short* out = (blockIdx.z == 0) ? qb : kb;
#pragma unroll
        for (int i = 0; i < 4; i++) {
            int m = row0 + ty * 4 + i;
            int b = m >> 11;
            int s = m & (SEQ - 1);
            ushort4 val;
            val.x = f2b(acc[i][0] + bias[col0 + d0 + 0]);
            val.y = f2b(acc[i][1] + bias[col0 + d0 + 1]);
            val.z = f2b(acc[i][2] + bias[col0 + d0 + 2]);
            val.w = f2b(acc[i][3] + bias[col0 + d0 + 3]);
            *(ushort4*)&out[((size_t)((b * NH + h) * SEQ + s)) * DH + d0] = val;
        }
    } else {
        // v transposed: vt[((b*NH+h)*DH + d)*SEQ + s]
        const int b = row0 >> 11;             // 2048 % 64 == 0, constant per tile
        const int s0 = (row0 & (SEQ - 1)) + ty * 4;
#pragma unroll
        for (int j = 0; j < 4; j++) {
            int d = d0 + j;
            float bi = bias[col0 + d];
            ushort4 val;
            val.x = f2b(acc[0][j] + bi);
            val.y = f2b(acc[1][j] + bi);
            val.z = f2b(acc[2][j] + bi);
            val.w = f2b(acc[3][j] + bi);
            *(ushort4*)&vtb[((size_t)((b * NH + h) * DH + d)) * SEQ + s0] = val;
        }
    }
}

// Output projection: fp32, plain [M, DM] output with bias.
__global__ __launch_bounds__(256) void out_gemm(
    const float* __restrict__ ctx, const float* __restrict__ Wo,
    const float* __restrict__ bo, float* __restrict__ out) {
    const int row0 = blockIdx.y * GTILE;
    const int col0 = blockIdx.x * GTILE;
    float acc[4][4];
    gemm_tile_compute(ctx, Wo, row0, col0, acc);

    const int tx = threadIdx.x & 15, ty = threadIdx.x >> 4;
    const int n0 = col0 + tx * 4;
#pragma unroll
    for (int i = 0; i < 4; i++) {
        int m = row0 + ty * 4 + i;
        float4 val;
        val.x = acc[i][0] + bo[n0 + 0];
        val.y = acc[i][1] + bo[n0 + 1];
        val.z = acc[i][2] + bo[n0 + 2];
        val.w = acc[i][3] + bo[n0 + 3];
        *(float4*)&out[(size_t)m * DM + n0] = val;
    }
}

// ---------------- Partial RoPE on bf16 q and k, in place --------------------
__global__ __launch_bounds__(256) void rope_kernel(unsigned short* __restrict__ qb,
                                                   unsigned short* __restrict__ kb) {
    const int idx = blockIdx.x * 256 + threadIdx.x;
    const int d = idx & 7;
    const int row = idx >> 3;
    constexpr int NROWS = BATCH * NH * SEQ;            // 65536
    unsigned short* t = (row < NROWS) ? qb : kb;
    const int r = row & (NROWS - 1);
    const int s = r & (SEQ - 1);
    const float inv_freq = __expf(-(float)d * (logf(10000.f) / 8.f));
    const float ang = (float)s * inv_freq;
    float c, si;
    __sincosf(ang, &si, &c);
    unsigned short* base = t + (size_t)r * DH;
    const float t1 = b2f(base[d]);
    const float t2 = b2f(base[d + 8]);
    base[d]     = f2b(t1 * c - t2 * si);
    base[d + 8] = f2b(t1 * si + t2 * c);
}

// ---------------- Causal flash attention, bf16 MFMA --------------------------
// Block: 256 threads = 4 waves; wave w owns q rows [q0+16w, q0+16w+16).
// K tile [64key][64d] and V^T tile [64d][64key] in XOR-swizzled LDS.
// Swizzle: 16B chunk c of row r lives at byte r*128 + (c ^ (r&7))*16.
#define AQT 64
#define AKT 64

__global__ __launch_bounds__(256) void attn_mfma(
    const unsigned short* __restrict__ qb, const unsigned short* __restrict__ kb,
    const unsigned short* __restrict__ vtb, float* __restrict__ ctx) {
    const int bh = blockIdx.y;
    const int q0 = blockIdx.x * AQT;
    const int tid = threadIdx.x;
    const int wave = tid >> 6;
    const int lane = tid & 63;
    const int lg = lane >> 4;     // lane group 0..3
    const int ln = lane & 15;

    __shared__ unsigned short KT[64 * 64];   // swizzled [key][d]
    __shared__ unsigned short VT[64 * 64];   // swizzled [d][key]
    __shared__ unsigned short PT[4][16 * 64];// per-wave swizzled [q][key]

    // Q fragments: lane ln = q row, element b of frag f => d = f*32 + lg*8 + b
    const unsigned short* qrow = qb + ((size_t)bh * SEQ + q0 + wave * 16 + ln) * DH;
    short8 qf0 = *(const short8*)&qrow[lg * 8];
    short8 qf1 = *(const short8*)&qrow[32 + lg * 8];

    f32x4 o[4];
#pragma unroll
    for (int nt = 0; nt < 4; nt++) o[nt] = f32x4{0.f, 0.f, 0.f, 0.f};
    float m[4], l[4];
#pragma unroll
    for (int r = 0; r < 4; r++) { m[r] = -1e30f; l[r] = 0.f; }

    const unsigned short* kbase = kb + (size_t)bh * SEQ * DH;
    const unsigned short* vbase = vtb + (size_t)bh * DH * SEQ;

    const int ktiles = blockIdx.x + 1;
    for (int t = 0; t < ktiles; ++t) {
        const int kb0 = t * AKT;
        __syncthreads();
#pragma unroll
        for (int i = 0; i < 2; i++) {
            int e = tid + i * 256;            // 0..511
            int r = e >> 3, c = e & 7;
            *(short8*)&KT[r * 64 + ((c ^ (r & 7)) * 8)] =
                *(const short8*)&kbase[(size_t)(kb0 + r) * DH + c * 8];
            *(short8*)&VT[r * 64 + ((c ^ (r & 7)) * 8)] =
                *(const short8*)&vbase[(size_t)r * SEQ + kb0 + c * 8];
        }
        __syncthreads();

        // ---- QK^T: 4 key subtiles of 16
        float s[4][4];
#pragma unroll
        for (int kt = 0; kt < 4; kt++) {
            f32x4 acc = f32x4{0.f, 0.f, 0.f, 0.f};
            int krow = kt * 16 + ln;
            short8 b0 = *(const short8*)&KT[krow * 64 + ((lg ^ (krow & 7)) * 8)];
            short8 b1 = *(const short8*)&KT[krow * 64 + (((4 + lg) ^ (krow & 7)) * 8)];
            acc = __builtin_amdgcn_mfma_f32_16x16x32_bf16(qf0, b0, acc, 0, 0, 0);
            acc = __builtin_amdgcn_mfma_f32_16x16x32_bf16(qf1, b1, acc, 0, 0, 0);
#pragma unroll
            for (int r = 0; r < 4; r++) {
                int qg = q0 + wave * 16 + lg * 4 + r;
                int kg = kb0 + kt * 16 + ln;
                s[kt][r] = (kg <= qg) ? acc[r] * SCALE : -1e30f;
            }
        }

        // ---- online softmax (per q-row stats; rows live on reg r of each group)
        float corr[4];
#pragma unroll
        for (int r = 0; r < 4; r++) {
            float v = fmaxf(fmaxf(s[0][r], s[1][r]), fmaxf(s[2][r], s[3][r]));
            v = fmaxf(v, __shfl_xor(v, 1));
            v = fmaxf(v, __shfl_xor(v, 2));
            v = fmaxf(v, __shfl_xor(v, 4));
            v = fmaxf(v, __shfl_xor(v, 8));
            float mn = fmaxf(m[r], v);
            corr[r] = __expf(m[r] - mn);
            m[r] = mn;
        }
        float rsum[4] = {0.f, 0.f, 0.f, 0.f};
#pragma unroll
        for (int kt = 0; kt < 4; kt++) {
#pragma unroll
            for (int r = 0; r < 4; r++) {
                float p = __expf(s[kt][r] - m[r]);
                rsum[r] += p;
                int qr = lg * 4 + r;
                int kc = kt * 16 + ln;
                PT[wave][qr * 64 + ((((kc >> 3) ^ (qr & 7)) * 8) | (kc & 7))] = f2b(p);
            }
        }
#pragma unroll
        for (int r = 0; r < 4; r++) {
            float v = rsum[r];
            v += __shfl_xor(v, 1);
            v += __shfl_xor(v, 2);
            v += __shfl_xor(v, 4);
            v += __shfl_xor(v, 8);
            l[r] = l[r] * corr[r] + v;
#pragma unroll
            for (int nt = 0; nt < 4; nt++) o[nt][r] *= corr[r];
        }

        // ---- PV: A = P (row ln, k = lg*8+b / 32+lg*8+b), B = V^T rows = d
        short8 pa0 = *(const short8*)&PT[wave][ln * 64 + ((lg ^ (ln & 7)) * 8)];
        short8 pa1 = *(const short8*)&PT[wave][ln * 64 + (((4 + lg) ^ (ln & 7)) * 8)];
#pragma unroll
        for (int nt = 0; nt < 4; nt++) {
            int vrow = nt * 16 + ln;
            short8 vb0 = *(const short8*)&VT[vrow * 64 + ((lg ^ (vrow & 7)) * 8)];
            short8 vb1 = *(const short8*)&VT[vrow * 64 + (((4 + lg) ^ (vrow & 7)) * 8)];
            o[nt] = __builtin_amdgcn_mfma_f32_16x16x32_bf16(pa0, vb0, o[nt], 0, 0, 0);
            o[nt] = __builtin_amdgcn_mfma_f32_16x16x32_bf16(pa1, vb1, o[nt], 0, 0, 0);
        }
    }

    // ---- epilogue: ctx[b][s][h*64+d], C layout row=lg*4+r, col=ln
    const int b = bh >> 4, h = bh & 15;
#pragma unroll
    for (int r = 0; r < 4; r++) {
        float invl = 1.f / l[r];
        int qg = q0 + wave * 16 + lg * 4 + r;
        float* op = ctx + ((size_t)(b * SEQ + qg)) * DM + h * DH;
#pragma unroll
        for (int nt = 0; nt < 4; nt++)
            op[nt * 16 + ln] = o[nt][r] * invl;
    }
}

// ---------------- launch ------------------------------------------------------
extern "C" void kernel_launch(void* const* d_in, const int* in_sizes, int n_in,
                              void* d_out, int out_size, void* d_ws, size_t ws_size,
                              hipStream_t stream) {
    const float* x  = (const float*)d_in[0];
    const float* Wq = (const float*)d_in[1];
    const float* bq = (const float*)d_in[2];
    const float* Wk = (const float*)d_in[3];
    const float* bk = (const float*)d_in[4];
    const float* Wv = (const float*)d_in[5];
    const float* bv = (const float*)d_in[6];
    const float* Wo = (const float*)d_in[7];
    const float* bo = (const float*)d_in[8];
    float* out = (float*)d_out;

    // workspace: qb, kb (bf16 [B,H,S,DH]) + vtb (bf16 [B,H,DH,S]) + ctx fp32
    constexpr size_t TSZ = (size_t)BATCH * NH * SEQ * DH;  // 4194304 elements
    unsigned short* qbp = (unsigned short*)d_ws;
    unsigned short* kbp = qbp + TSZ;
    unsigned short* vtp = kbp + TSZ;
    float* ctx = (float*)(vtp + TSZ);

    // 1) QKV projections (+bias, bf16 head layout, V transposed)
    qkv_gemm<<<dim3(DM / GTILE, MROWS / GTILE, 3), 256, 0, stream>>>(
        x, Wq, Wk, Wv, bq, bk, bv, qbp, kbp, vtp);

    // 2) partial RoPE on q and k (in place, bf16)
    const int rope_items = 2 * BATCH * NH * SEQ * 8;      // 1048576
    rope_kernel<<<rope_items / 256, 256, 0, stream>>>(qbp, kbp);

    // 3) causal MFMA attention -> ctx [B,S,DM] fp32
    attn_mfma<<<dim3(SEQ / AQT, BATCH * NH), 256, 0, stream>>>(qbp, kbp, vtp, ctx);

    // 4) output projection (fp32)
    out_gemm<<<dim3(DM / GTILE, MROWS / GTILE), 256, 0, stream>>>(ctx, Wo, bo, out);
}

// Round 3
// 268.510 us; speedup vs baseline: 7.5202x; 2.4432x over previous
//
#include <hip/hip_runtime.h>
#include <hip/hip_bf16.h>
#include <math.h>

// Problem constants
constexpr int DM = 1024;
constexpr int SEQ = 2048;
constexpr int BATCH = 2;
constexpr int NH = 16;
constexpr int DH = 64;
constexpr int MROWS = BATCH * SEQ;  // 4096
constexpr float SCALE = 0.125f;

typedef __attribute__((ext_vector_type(8))) short short8;
typedef __attribute__((ext_vector_type(4))) float f32x4;
typedef unsigned short ushort_t;

__device__ __forceinline__ unsigned short f2b(float f) {
    __hip_bfloat16 h = __float2bfloat16(f);
    return __builtin_bit_cast(unsigned short, h);
}
__device__ __forceinline__ float b2f(unsigned short u) {
    unsigned int t = ((unsigned int)u) << 16;
    return __builtin_bit_cast(float, t);
}

__device__ __forceinline__ void gload16(const ushort_t* g, ushort_t* l) {
    __builtin_amdgcn_global_load_lds(
        (const __attribute__((address_space(1))) void*)g,
        (__attribute__((address_space(3))) void*)l, 16, 0, 0);
}

// ---------------- converters --------------------------------------------------
__global__ __launch_bounds__(256) void conv_x(const float* __restrict__ x,
                                              ushort_t* __restrict__ xb) {
    const size_t idx = (size_t)blockIdx.x * 256 + threadIdx.x;  // 524288 threads
    const float4* src = (const float4*)(x + idx * 8);
    float4 a = src[0], b = src[1];
    short8 v;
    v[0] = (short)f2b(a.x); v[1] = (short)f2b(a.y);
    v[2] = (short)f2b(a.z); v[3] = (short)f2b(a.w);
    v[4] = (short)f2b(b.x); v[5] = (short)f2b(b.y);
    v[6] = (short)f2b(b.z); v[7] = (short)f2b(b.w);
    *(short8*)(xb + idx * 8) = v;
}

// Transpose + convert weights: W [K][N] fp32 -> Wt [N][K] bf16
__global__ __launch_bounds__(256) void conv_w(
    const float* __restrict__ Wq, const float* __restrict__ Wk,
    const float* __restrict__ Wv, const float* __restrict__ Wo,
    ushort_t* __restrict__ Wqt, ushort_t* __restrict__ Wkt,
    ushort_t* __restrict__ Wvt, ushort_t* __restrict__ Wot) {
    const float* W; ushort_t* Wt;
    switch (blockIdx.z) {
        case 0:  W = Wq; Wt = Wqt; break;
        case 1:  W = Wk; Wt = Wkt; break;
        case 2:  W = Wv; Wt = Wvt; break;
        default: W = Wo; Wt = Wot; break;
    }
    __shared__ float L[64][65];
    const int n0 = blockIdx.x * 64, k0 = blockIdx.y * 64;
    const int t = threadIdx.x;
    const int tr = t >> 4, tc4 = (t & 15) * 4;
#pragma unroll
    for (int i = 0; i < 4; ++i) {
        int kk = tr + i * 16;
        float4 v = *(const float4*)&W[(size_t)(k0 + kk) * DM + n0 + tc4];
        L[kk][tc4 + 0] = v.x; L[kk][tc4 + 1] = v.y;
        L[kk][tc4 + 2] = v.z; L[kk][tc4 + 3] = v.w;
    }
    __syncthreads();
#pragma unroll
    for (int i = 0; i < 4; ++i) {
        int nn = tr + i * 16;
        ushort4 u;
        u.x = f2b(L[tc4 + 0][nn]); u.y = f2b(L[tc4 + 1][nn]);
        u.z = f2b(L[tc4 + 2][nn]); u.w = f2b(L[tc4 + 3][nn]);
        *(ushort4*)&Wt[(size_t)(n0 + nn) * DM + k0 + tc4] = u;
    }
}

// ---------------- MFMA GEMM core: 128x128 tile, BK=64, 4 waves ---------------
// A: [M][1024] bf16 row-major; B: [N][1024] bf16 row-major (pre-transposed W).
// LDS swizzle: 16B chunk c of row r stored at position c^(r&7); staged via
// pre-swizzled global source + linear global_load_lds dest.
#define BM 128
#define BN 128
#define BKK 64

__device__ __forceinline__ void mfma_core(const ushort_t* __restrict__ A,
                                          const ushort_t* __restrict__ B,
                                          int row0, int col0,
                                          ushort_t* smem, f32x4 (&acc)[4][4]) {
    const int tid = threadIdx.x;
    const int wave = tid >> 6, lane = tid & 63;
    const int lg = lane >> 4, ln = lane & 15;
    const int wr = wave >> 1, wc = wave & 1;
    ushort_t* As = smem;          // 8192 ushorts: [128 r][64 k] swizzled
    ushort_t* Bs = smem + 8192;

    for (int kt = 0; kt < DM / BKK; ++kt) {
        __syncthreads();
#pragma unroll
        for (int i = 0; i < 4; ++i) {
            int f = i * 256 + tid;                 // [0,1024)
            int r = f >> 3, p = f & 7, c = p ^ (r & 7);
            gload16(&A[(size_t)(row0 + r) * DM + kt * BKK + c * 8], &As[f * 8]);
            gload16(&B[(size_t)(col0 + r) * DM + kt * BKK + c * 8], &Bs[f * 8]);
        }
        __syncthreads();

        short8 af[4][2], bf[4][2];
#pragma unroll
        for (int mi = 0; mi < 4; ++mi) {
            int r = wr * 64 + mi * 16 + ln;
#pragma unroll
            for (int ks = 0; ks < 2; ++ks) {
                int c = ks * 4 + lg;
                af[mi][ks] = *(const short8*)&As[r * 64 + ((c ^ (r & 7)) * 8)];
            }
        }
#pragma unroll
        for (int ni = 0; ni < 4; ++ni) {
            int r = wc * 64 + ni * 16 + ln;
#pragma unroll
            for (int ks = 0; ks < 2; ++ks) {
                int c = ks * 4 + lg;
                bf[ni][ks] = *(const short8*)&Bs[r * 64 + ((c ^ (r & 7)) * 8)];
            }
        }
#pragma unroll
        for (int ks = 0; ks < 2; ++ks)
#pragma unroll
            for (int mi = 0; mi < 4; ++mi)
#pragma unroll
                for (int ni = 0; ni < 4; ++ni)
                    acc[mi][ni] = __builtin_amdgcn_mfma_f32_16x16x32_bf16(
                        af[mi][ks], bf[ni][ks], acc[mi][ni], 0, 0, 0);
    }
}

// QKV: z=0 -> qb [B,H,S,DH]; z=1 -> kb; z=2 -> vtb [B,H,DH,S]; all bf16 +bias.
__global__ __launch_bounds__(256) void mfma_gemm_qkv(
    const ushort_t* __restrict__ xb,
    const ushort_t* __restrict__ Wqt, const ushort_t* __restrict__ Wkt,
    const ushort_t* __restrict__ Wvt,
    const float* __restrict__ bq, const float* __restrict__ bk,
    const float* __restrict__ bv,
    ushort_t* __restrict__ qb, ushort_t* __restrict__ kb,
    ushort_t* __restrict__ vtb) {
    const ushort_t* W; const float* bias;
    if (blockIdx.z == 0)      { W = Wqt; bias = bq; }
    else if (blockIdx.z == 1) { W = Wkt; bias = bk; }
    else                      { W = Wvt; bias = bv; }

    const int row0 = blockIdx.y * BM;
    const int col0 = blockIdx.x * BN;
    __shared__ ushort_t smem[16384];
    f32x4 acc[4][4] = {};
    mfma_core(xb, W, row0, col0, smem, acc);

    const int tid = threadIdx.x;
    const int wave = tid >> 6, lane = tid & 63;
    const int lg = lane >> 4, ln = lane & 15;
    const int wr = wave >> 1, wc = wave & 1;
    const bool isV = (blockIdx.z == 2);

    __syncthreads();
    ushort_t* Cs = smem;  // 128x128 bf16 = 32 KB (aliases A/B buffers)
#pragma unroll
    for (int mi = 0; mi < 4; ++mi)
#pragma unroll
        for (int ni = 0; ni < 4; ++ni)
#pragma unroll
            for (int r = 0; r < 4; ++r) {
                int mrel = wr * 64 + mi * 16 + lg * 4 + r;
                int nrel = wc * 64 + ni * 16 + ln;
                float v = acc[mi][ni][r] + bias[col0 + nrel];
                Cs[isV ? (nrel * 128 + mrel) : (mrel * 128 + nrel)] = f2b(v);
            }
    __syncthreads();

    if (!isV) {
        ushort_t* out = (blockIdx.z == 0) ? qb : kb;
#pragma unroll
        for (int i = 0; i < 8; ++i) {
            int f = i * 256 + tid;              // [0,2048)
            int rrow = f >> 4, c8 = f & 15;
            int m = row0 + rrow;
            int b = m >> 11, s = m & (SEQ - 1);
            int n = col0 + c8 * 8;
            int h = n >> 6, d = n & 63;
            *(short8*)&out[((size_t)((b * NH + h) * SEQ) + s) * DH + d] =
                *(const short8*)&Cs[rrow * 128 + c8 * 8];
        }
    } else {
#pragma unroll
        for (int i = 0; i < 8; ++i) {
            int f = i * 256 + tid;
            int nrow = f >> 4, c8 = f & 15;
            int n = col0 + nrow;
            int h = n >> 6, d = n & 63;
            int m = row0 + c8 * 8;
            int b = m >> 11, s = m & (SEQ - 1);
            *(short8*)&vtb[((size_t)((b * NH + h) * DH) + d) * SEQ + s] =
                *(const short8*)&Cs[nrow * 128 + c8 * 8];
        }
    }
}

// Output projection: A = ctxb bf16 [M][DM], B = Wot, out fp32 [M][DM] + bo.
__global__ __launch_bounds__(256) void mfma_gemm_out(
    const ushort_t* __restrict__ ctxb, const ushort_t* __restrict__ Wot,
    const float* __restrict__ bo, float* __restrict__ out) {
    const int row0 = blockIdx.y * BM;
    const int col0 = blockIdx.x * BN;
    __shared__ ushort_t smem[16384];
    f32x4 acc[4][4] = {};
    mfma_core(ctxb, Wot, row0, col0, smem, acc);

    const int tid = threadIdx.x;
    const int wave = tid >> 6, lane = tid & 63;
    const int lg = lane >> 4, ln = lane & 15;
    const int wr = wave >> 1, wc = wave & 1;
#pragma unroll
    for (int mi = 0; mi < 4; ++mi)
#pragma unroll
        for (int ni = 0; ni < 4; ++ni)
#pragma unroll
            for (int r = 0; r < 4; ++r) {
                int m = row0 + wr * 64 + mi * 16 + lg * 4 + r;
                int n = col0 + wc * 64 + ni * 16 + ln;
                out[(size_t)m * DM + n] = acc[mi][ni][r] + bo[n];
            }
}

// ---------------- Partial RoPE on bf16 q and k, in place --------------------
__global__ __launch_bounds__(256) void rope_kernel(ushort_t* __restrict__ qb,
                                                   ushort_t* __restrict__ kb) {
    const int idx = blockIdx.x * 256 + threadIdx.x;
    const int d = idx & 7;
    const int row = idx >> 3;
    constexpr int NROWS = BATCH * NH * SEQ;
    ushort_t* t = (row < NROWS) ? qb : kb;
    const int r = row & (NROWS - 1);
    const int s = r & (SEQ - 1);
    const float inv_freq = __expf(-(float)d * (logf(10000.f) / 8.f));
    const float ang = (float)s * inv_freq;
    float c, si;
    __sincosf(ang, &si, &c);
    ushort_t* base = t + (size_t)r * DH;
    const float t1 = b2f(base[d]);
    const float t2 = b2f(base[d + 8]);
    base[d]     = f2b(t1 * c - t2 * si);
    base[d + 8] = f2b(t1 * si + t2 * c);
}

// ---------------- Causal flash attention, bf16 MFMA --------------------------
#define AQT 64
#define AKT 64

__global__ __launch_bounds__(256) void attn_mfma(
    const ushort_t* __restrict__ qb, const ushort_t* __restrict__ kb,
    const ushort_t* __restrict__ vtb, ushort_t* __restrict__ ctxb) {
    const int bh = blockIdx.y;
    const int q0 = blockIdx.x * AQT;
    const int tid = threadIdx.x;
    const int wave = tid >> 6;
    const int lane = tid & 63;
    const int lg = lane >> 4;
    const int ln = lane & 15;

    __shared__ ushort_t KT[64 * 64];
    __shared__ ushort_t VT[64 * 64];
    __shared__ ushort_t PT[4][16 * 64];

    const ushort_t* qrow = qb + ((size_t)bh * SEQ + q0 + wave * 16 + ln) * DH;
    short8 qf0 = *(const short8*)&qrow[lg * 8];
    short8 qf1 = *(const short8*)&qrow[32 + lg * 8];

    f32x4 o[4];
#pragma unroll
    for (int nt = 0; nt < 4; nt++) o[nt] = f32x4{0.f, 0.f, 0.f, 0.f};
    float m[4], l[4];
#pragma unroll
    for (int r = 0; r < 4; r++) { m[r] = -1e30f; l[r] = 0.f; }

    const ushort_t* kbase = kb + (size_t)bh * SEQ * DH;
    const ushort_t* vbase = vtb + (size_t)bh * DH * SEQ;

    const int ktiles = blockIdx.x + 1;
    for (int t = 0; t < ktiles; ++t) {
        const int kb0 = t * AKT;
        __syncthreads();
#pragma unroll
        for (int i = 0; i < 2; i++) {
            int e = tid + i * 256;
            int r = e >> 3, c = e & 7;
            *(short8*)&KT[r * 64 + ((c ^ (r & 7)) * 8)] =
                *(const short8*)&kbase[(size_t)(kb0 + r) * DH + c * 8];
            *(short8*)&VT[r * 64 + ((c ^ (r & 7)) * 8)] =
                *(const short8*)&vbase[(size_t)r * SEQ + kb0 + c * 8];
        }
        __syncthreads();

        float s[4][4];
#pragma unroll
        for (int kt = 0; kt < 4; kt++) {
            f32x4 acc = f32x4{0.f, 0.f, 0.f, 0.f};
            int krow = kt * 16 + ln;
            short8 b0 = *(const short8*)&KT[krow * 64 + ((lg ^ (krow & 7)) * 8)];
            short8 b1 = *(const short8*)&KT[krow * 64 + (((4 + lg) ^ (krow & 7)) * 8)];
            acc = __builtin_amdgcn_mfma_f32_16x16x32_bf16(qf0, b0, acc, 0, 0, 0);
            acc = __builtin_amdgcn_mfma_f32_16x16x32_bf16(qf1, b1, acc, 0, 0, 0);
#pragma unroll
            for (int r = 0; r < 4; r++) {
                int qg = q0 + wave * 16 + lg * 4 + r;
                int kg = kb0 + kt * 16 + ln;
                s[kt][r] = (kg <= qg) ? acc[r] * SCALE : -1e30f;
            }
        }

        float corr[4];
#pragma unroll
        for (int r = 0; r < 4; r++) {
            float v = fmaxf(fmaxf(s[0][r], s[1][r]), fmaxf(s[2][r], s[3][r]));
            v = fmaxf(v, __shfl_xor(v, 1));
            v = fmaxf(v, __shfl_xor(v, 2));
            v = fmaxf(v, __shfl_xor(v, 4));
            v = fmaxf(v, __shfl_xor(v, 8));
            float mn = fmaxf(m[r], v);
            corr[r] = __expf(m[r] - mn);
            m[r] = mn;
        }
        float rsum[4] = {0.f, 0.f, 0.f, 0.f};
#pragma unroll
        for (int kt = 0; kt < 4; kt++) {
#pragma unroll
            for (int r = 0; r < 4; r++) {
                float p = __expf(s[kt][r] - m[r]);
                rsum[r] += p;
                int qr = lg * 4 + r;
                int kc = kt * 16 + ln;
                PT[wave][qr * 64 + ((((kc >> 3) ^ (qr & 7)) * 8) | (kc & 7))] = f2b(p);
            }
        }
#pragma unroll
        for (int r = 0; r < 4; r++) {
            float v = rsum[r];
            v += __shfl_xor(v, 1);
            v += __shfl_xor(v, 2);
            v += __shfl_xor(v, 4);
            v += __shfl_xor(v, 8);
            l[r] = l[r] * corr[r] + v;
#pragma unroll
            for (int nt = 0; nt < 4; nt++) o[nt][r] *= corr[r];
        }

        short8 pa0 = *(const short8*)&PT[wave][ln * 64 + ((lg ^ (ln & 7)) * 8)];
        short8 pa1 = *(const short8*)&PT[wave][ln * 64 + (((4 + lg) ^ (ln & 7)) * 8)];
#pragma unroll
        for (int nt = 0; nt < 4; nt++) {
            int vrow = nt * 16 + ln;
            short8 vb0 = *(const short8*)&VT[vrow * 64 + ((lg ^ (vrow & 7)) * 8)];
            short8 vb1 = *(const short8*)&VT[vrow * 64 + (((4 + lg) ^ (vrow & 7)) * 8)];
            o[nt] = __builtin_amdgcn_mfma_f32_16x16x32_bf16(pa0, vb0, o[nt], 0, 0, 0);
            o[nt] = __builtin_amdgcn_mfma_f32_16x16x32_bf16(pa1, vb1, o[nt], 0, 0, 0);
        }
    }

    const int b = bh >> 4, h = bh & 15;
#pragma unroll
    for (int r = 0; r < 4; r++) {
        float invl = 1.f / l[r];
        int qg = q0 + wave * 16 + lg * 4 + r;
        ushort_t* op = ctxb + ((size_t)(b * SEQ + qg)) * DM + h * DH;
#pragma unroll
        for (int nt = 0; nt < 4; nt++)
            op[nt * 16 + ln] = f2b(o[nt][r] * invl);
    }
}

// ---------------- launch ------------------------------------------------------
extern "C" void kernel_launch(void* const* d_in, const int* in_sizes, int n_in,
                              void* d_out, int out_size, void* d_ws, size_t ws_size,
                              hipStream_t stream) {
    const float* x  = (const float*)d_in[0];
    const float* Wq = (const float*)d_in[1];
    const float* bq = (const float*)d_in[2];
    const float* Wk = (const float*)d_in[3];
    const float* bk = (const float*)d_in[4];
    const float* Wv = (const float*)d_in[5];
    const float* bv = (const float*)d_in[6];
    const float* Wo = (const float*)d_in[7];
    const float* bo = (const float*)d_in[8];
    float* out = (float*)d_out;

    // workspace (ushort elements): xb 4M | Wt 4x1M | qb 4M | kb 4M | vt 4M | ctx 4M
    constexpr size_t TSZ = (size_t)MROWS * DM;   // 4194304
    constexpr size_t WSZ = (size_t)DM * DM;      // 1048576
    ushort_t* xb  = (ushort_t*)d_ws;
    ushort_t* Wqt = xb + TSZ;
    ushort_t* Wkt = Wqt + WSZ;
    ushort_t* Wvt = Wkt + WSZ;
    ushort_t* Wot = Wvt + WSZ;
    ushort_t* qbp = Wot + WSZ;
    ushort_t* kbp = qbp + TSZ;
    ushort_t* vtp = kbp + TSZ;
    ushort_t* ctxb = vtp + TSZ;

    // 0) bf16 conversions (x) and weight transpose+convert
    conv_x<<<TSZ / 8 / 256, 256, 0, stream>>>(x, xb);
    conv_w<<<dim3(16, 16, 4), 256, 0, stream>>>(Wq, Wk, Wv, Wo, Wqt, Wkt, Wvt, Wot);

    // 1) QKV projections (MFMA, +bias, head layout, V transposed)
    mfma_gemm_qkv<<<dim3(DM / BN, MROWS / BM, 3), 256, 0, stream>>>(
        xb, Wqt, Wkt, Wvt, bq, bk, bv, qbp, kbp, vtp);

    // 2) partial RoPE on q and k (in place, bf16)
    const int rope_items = 2 * BATCH * NH * SEQ * 8;
    rope_kernel<<<rope_items / 256, 256, 0, stream>>>(qbp, kbp);

    // 3) causal MFMA attention -> ctx bf16 [B,S,DM]
    attn_mfma<<<dim3(SEQ / AQT, BATCH * NH), 256, 0, stream>>>(qbp, kbp, vtp, ctxb);

    // 4) output projection (MFMA, fp32 out)
    mfma_gemm_out<<<dim3(DM / BN, MROWS / BM), 256, 0, stream>>>(ctxb, Wot, bo, out);
}

// Round 4
// 154.588 us; speedup vs baseline: 13.0622x; 1.7369x over previous
//
#include <hip/hip_runtime.h>
#include <hip/hip_bf16.h>
#include <math.h>

// Problem constants
constexpr int DM = 1024;
constexpr int SEQ = 2048;
constexpr int BATCH = 2;
constexpr int NH = 16;
constexpr int DH = 64;
constexpr int MROWS = BATCH * SEQ;  // 4096
constexpr float SCALE = 0.125f;

typedef __attribute__((ext_vector_type(8))) short short8;
typedef __attribute__((ext_vector_type(4))) float f32x4;
typedef unsigned short ushort_t;

__device__ __forceinline__ unsigned short f2b(float f) {
    __hip_bfloat16 h = __float2bfloat16(f);
    return __builtin_bit_cast(unsigned short, h);
}
__device__ __forceinline__ float b2f(unsigned short u) {
    unsigned int t = ((unsigned int)u) << 16;
    return __builtin_bit_cast(float, t);
}

__device__ __forceinline__ void gload16(const ushort_t* g, ushort_t* l) {
    __builtin_amdgcn_global_load_lds(
        (const __attribute__((address_space(1))) void*)g,
        (__attribute__((address_space(3))) void*)l, 16, 0, 0);
}

// DPP row-rotate reductions over 16-lane groups (all-VALU, no ds_bpermute).
template <int CTRL>
__device__ __forceinline__ float dppf(float x) {
    int i = __builtin_bit_cast(int, x);
    int r = __builtin_amdgcn_update_dpp(i, i, CTRL, 0xF, 0xF, false);
    return __builtin_bit_cast(float, r);
}
__device__ __forceinline__ float rmax16(float v) {
    v = fmaxf(v, dppf<0x121>(v));  // row_ror:1
    v = fmaxf(v, dppf<0x122>(v));  // row_ror:2
    v = fmaxf(v, dppf<0x124>(v));  // row_ror:4
    v = fmaxf(v, dppf<0x128>(v));  // row_ror:8
    return v;
}
__device__ __forceinline__ float rsum16(float v) {
    v += dppf<0x121>(v);
    v += dppf<0x122>(v);
    v += dppf<0x124>(v);
    v += dppf<0x128>(v);
    return v;
}

// ---------------- converters --------------------------------------------------
__global__ __launch_bounds__(256) void conv_x(const float* __restrict__ x,
                                              ushort_t* __restrict__ xb) {
    const size_t idx = (size_t)blockIdx.x * 256 + threadIdx.x;
    const float4* src = (const float4*)(x + idx * 8);
    float4 a = src[0], b = src[1];
    short8 v;
    v[0] = (short)f2b(a.x); v[1] = (short)f2b(a.y);
    v[2] = (short)f2b(a.z); v[3] = (short)f2b(a.w);
    v[4] = (short)f2b(b.x); v[5] = (short)f2b(b.y);
    v[6] = (short)f2b(b.z); v[7] = (short)f2b(b.w);
    *(short8*)(xb + idx * 8) = v;
}

// Transpose + convert weights: W [K][N] fp32 -> Wt [N][K] bf16
__global__ __launch_bounds__(256) void conv_w(
    const float* __restrict__ Wq, const float* __restrict__ Wk,
    const float* __restrict__ Wv, const float* __restrict__ Wo,
    ushort_t* __restrict__ Wqt, ushort_t* __restrict__ Wkt,
    ushort_t* __restrict__ Wvt, ushort_t* __restrict__ Wot) {
    const float* W; ushort_t* Wt;
    switch (blockIdx.z) {
        case 0:  W = Wq; Wt = Wqt; break;
        case 1:  W = Wk; Wt = Wkt; break;
        case 2:  W = Wv; Wt = Wvt; break;
        default: W = Wo; Wt = Wot; break;
    }
    __shared__ float L[64][65];
    const int n0 = blockIdx.x * 64, k0 = blockIdx.y * 64;
    const int t = threadIdx.x;
    const int tr = t >> 4, tc4 = (t & 15) * 4;
#pragma unroll
    for (int i = 0; i < 4; ++i) {
        int kk = tr + i * 16;
        float4 v = *(const float4*)&W[(size_t)(k0 + kk) * DM + n0 + tc4];
        L[kk][tc4 + 0] = v.x; L[kk][tc4 + 1] = v.y;
        L[kk][tc4 + 2] = v.z; L[kk][tc4 + 3] = v.w;
    }
    __syncthreads();
#pragma unroll
    for (int i = 0; i < 4; ++i) {
        int nn = tr + i * 16;
        ushort4 u;
        u.x = f2b(L[tc4 + 0][nn]); u.y = f2b(L[tc4 + 1][nn]);
        u.z = f2b(L[tc4 + 2][nn]); u.w = f2b(L[tc4 + 3][nn]);
        *(ushort4*)&Wt[(size_t)(n0 + nn) * DM + k0 + tc4] = u;
    }
}

// ---------------- MFMA GEMM core: 128x128 tile, BK=64, 4 waves ---------------
#define BM 128
#define BN 128
#define BKK 64

__device__ __forceinline__ void mfma_core(const ushort_t* __restrict__ A,
                                          const ushort_t* __restrict__ B,
                                          int row0, int col0,
                                          ushort_t* smem, f32x4 (&acc)[4][4]) {
    const int tid = threadIdx.x;
    const int wave = tid >> 6, lane = tid & 63;
    const int lg = lane >> 4, ln = lane & 15;
    const int wr = wave >> 1, wc = wave & 1;
    ushort_t* As = smem;
    ushort_t* Bs = smem + 8192;

    for (int kt = 0; kt < DM / BKK; ++kt) {
        __syncthreads();
#pragma unroll
        for (int i = 0; i < 4; ++i) {
            int f = i * 256 + tid;
            int r = f >> 3, p = f & 7, c = p ^ (r & 7);
            gload16(&A[(size_t)(row0 + r) * DM + kt * BKK + c * 8], &As[f * 8]);
            gload16(&B[(size_t)(col0 + r) * DM + kt * BKK + c * 8], &Bs[f * 8]);
        }
        __syncthreads();

        short8 af[4][2], bf[4][2];
#pragma unroll
        for (int mi = 0; mi < 4; ++mi) {
            int r = wr * 64 + mi * 16 + ln;
#pragma unroll
            for (int ks = 0; ks < 2; ++ks) {
                int c = ks * 4 + lg;
                af[mi][ks] = *(const short8*)&As[r * 64 + ((c ^ (r & 7)) * 8)];
            }
        }
#pragma unroll
        for (int ni = 0; ni < 4; ++ni) {
            int r = wc * 64 + ni * 16 + ln;
#pragma unroll
            for (int ks = 0; ks < 2; ++ks) {
                int c = ks * 4 + lg;
                bf[ni][ks] = *(const short8*)&Bs[r * 64 + ((c ^ (r & 7)) * 8)];
            }
        }
#pragma unroll
        for (int ks = 0; ks < 2; ++ks)
#pragma unroll
            for (int mi = 0; mi < 4; ++mi)
#pragma unroll
                for (int ni = 0; ni < 4; ++ni)
                    acc[mi][ni] = __builtin_amdgcn_mfma_f32_16x16x32_bf16(
                        af[mi][ks], bf[ni][ks], acc[mi][ni], 0, 0, 0);
    }
}

// QKV: z=0 -> qb [B,H,S,DH]; z=1 -> kb; z=2 -> vtb [B,H,DH,S]; all bf16 +bias.
__global__ __launch_bounds__(256) void mfma_gemm_qkv(
    const ushort_t* __restrict__ xb,
    const ushort_t* __restrict__ Wqt, const ushort_t* __restrict__ Wkt,
    const ushort_t* __restrict__ Wvt,
    const float* __restrict__ bq, const float* __restrict__ bk,
    const float* __restrict__ bv,
    ushort_t* __restrict__ qb, ushort_t* __restrict__ kb,
    ushort_t* __restrict__ vtb) {
    const ushort_t* W; const float* bias;
    if (blockIdx.z == 0)      { W = Wqt; bias = bq; }
    else if (blockIdx.z == 1) { W = Wkt; bias = bk; }
    else                      { W = Wvt; bias = bv; }

    const int row0 = blockIdx.y * BM;
    const int col0 = blockIdx.x * BN;
    __shared__ ushort_t smem[16384];
    f32x4 acc[4][4] = {};
    mfma_core(xb, W, row0, col0, smem, acc);

    const int tid = threadIdx.x;
    const int wave = tid >> 6, lane = tid & 63;
    const int lg = lane >> 4, ln = lane & 15;
    const int wr = wave >> 1, wc = wave & 1;
    const bool isV = (blockIdx.z == 2);

    __syncthreads();
    ushort_t* Cs = smem;
#pragma unroll
    for (int mi = 0; mi < 4; ++mi)
#pragma unroll
        for (int ni = 0; ni < 4; ++ni)
#pragma unroll
            for (int r = 0; r < 4; ++r) {
                int mrel = wr * 64 + mi * 16 + lg * 4 + r;
                int nrel = wc * 64 + ni * 16 + ln;
                float v = acc[mi][ni][r] + bias[col0 + nrel];
                Cs[isV ? (nrel * 128 + mrel) : (mrel * 128 + nrel)] = f2b(v);
            }
    __syncthreads();

    if (!isV) {
        ushort_t* out = (blockIdx.z == 0) ? qb : kb;
#pragma unroll
        for (int i = 0; i < 8; ++i) {
            int f = i * 256 + tid;
            int rrow = f >> 4, c8 = f & 15;
            int m = row0 + rrow;
            int b = m >> 11, s = m & (SEQ - 1);
            int n = col0 + c8 * 8;
            int h = n >> 6, d = n & 63;
            *(short8*)&out[((size_t)((b * NH + h) * SEQ) + s) * DH + d] =
                *(const short8*)&Cs[rrow * 128 + c8 * 8];
        }
    } else {
#pragma unroll
        for (int i = 0; i < 8; ++i) {
            int f = i * 256 + tid;
            int nrow = f >> 4, c8 = f & 15;
            int n = col0 + nrow;
            int h = n >> 6, d = n & 63;
            int m = row0 + c8 * 8;
            int b = m >> 11, s = m & (SEQ - 1);
            *(short8*)&vtb[((size_t)((b * NH + h) * DH) + d) * SEQ + s] =
                *(const short8*)&Cs[nrow * 128 + c8 * 8];
        }
    }
}

// Output projection: A = ctxb bf16 [M][DM], B = Wot, out fp32 [M][DM] + bo.
__global__ __launch_bounds__(256) void mfma_gemm_out(
    const ushort_t* __restrict__ ctxb, const ushort_t* __restrict__ Wot,
    const float* __restrict__ bo, float* __restrict__ out) {
    const int row0 = blockIdx.y * BM;
    const int col0 = blockIdx.x * BN;
    __shared__ ushort_t smem[16384];
    f32x4 acc[4][4] = {};
    mfma_core(ctxb, Wot, row0, col0, smem, acc);

    const int tid = threadIdx.x;
    const int wave = tid >> 6, lane = tid & 63;
    const int lg = lane >> 4, ln = lane & 15;
    const int wr = wave >> 1, wc = wave & 1;
#pragma unroll
    for (int mi = 0; mi < 4; ++mi)
#pragma unroll
        for (int ni = 0; ni < 4; ++ni)
#pragma unroll
            for (int r = 0; r < 4; ++r) {
                int m = row0 + wr * 64 + mi * 16 + lg * 4 + r;
                int n = col0 + wc * 64 + ni * 16 + ln;
                out[(size_t)m * DM + n] = acc[mi][ni][r] + bo[n];
            }
}

// ---------------- Partial RoPE on bf16 q and k, in place --------------------
__global__ __launch_bounds__(256) void rope_kernel(ushort_t* __restrict__ qb,
                                                   ushort_t* __restrict__ kb) {
    const int idx = blockIdx.x * 256 + threadIdx.x;
    const int d = idx & 7;
    const int row = idx >> 3;
    constexpr int NROWS = BATCH * NH * SEQ;
    ushort_t* t = (row < NROWS) ? qb : kb;
    const int r = row & (NROWS - 1);
    const int s = r & (SEQ - 1);
    const float inv_freq = __expf(-(float)d * (logf(10000.f) / 8.f));
    const float ang = (float)s * inv_freq;
    float c, si;
    __sincosf(ang, &si, &c);
    ushort_t* base = t + (size_t)r * DH;
    const float t1 = b2f(base[d]);
    const float t2 = b2f(base[d + 8]);
    base[d]     = f2b(t1 * c - t2 * si);
    base[d + 8] = f2b(t1 * si + t2 * c);
}

// ---------------- Causal flash attention, bf16 MFMA --------------------------
// Grid: (16 strip-pairs, 32 bh). Block = 4 waves; wave w owns 16 q-rows.
// Each block processes q-tiles {x, 31-x} -> constant 33 tile-steps (balance).
// K/V double-buffered in swizzled LDS via global_load_lds prefetch.
#define AQT 64
#define AKT 64
#define NQT (SEQ / AQT)   // 32

__global__ __launch_bounds__(256) void attn_mfma(
    const ushort_t* __restrict__ qb, const ushort_t* __restrict__ kb,
    const ushort_t* __restrict__ vtb, ushort_t* __restrict__ ctxb) {
    const int bh = blockIdx.y;
    const int tid = threadIdx.x;
    const int wave = tid >> 6;
    const int lane = tid & 63;
    const int lg = lane >> 4;
    const int ln = lane & 15;

    __shared__ ushort_t KT[2][64 * 64];
    __shared__ ushort_t VT[2][64 * 64];
    __shared__ ushort_t PT[4][16 * 64];

    const ushort_t* kbase = kb + (size_t)bh * SEQ * DH;
    const ushort_t* vbase = vtb + (size_t)bh * DH * SEQ;
    const int b = bh >> 4, h = bh & 15;

    for (int strip = 0; strip < 2; ++strip) {
        const int qt = strip ? (NQT - 1 - blockIdx.x) : blockIdx.x;
        const int q0 = qt * AQT;

        const ushort_t* qrow = qb + ((size_t)bh * SEQ + q0 + wave * 16 + ln) * DH;
        short8 qf0 = *(const short8*)&qrow[lg * 8];
        short8 qf1 = *(const short8*)&qrow[32 + lg * 8];

        f32x4 o[4];
#pragma unroll
        for (int nt = 0; nt < 4; nt++) o[nt] = f32x4{0.f, 0.f, 0.f, 0.f};
        float m[4], l[4];
#pragma unroll
        for (int r = 0; r < 4; r++) { m[r] = -1e30f; l[r] = 0.f; }

        const int ntiles = qt + 1;

        // prologue: stage tile 0 into buffer 0
        {
#pragma unroll
            for (int i = 0; i < 2; i++) {
                int f = i * 256 + tid;
                int r = f >> 3, p = f & 7, c = p ^ (r & 7);
                gload16(&kbase[(size_t)r * DH + c * 8], &KT[0][f * 8]);
                gload16(&vbase[(size_t)r * SEQ + c * 8], &VT[0][f * 8]);
            }
        }

        int cur = 0;
        for (int t = 0; t < ntiles; ++t) {
            __syncthreads();   // staged data for tile t is now visible

            // prefetch tile t+1 into the other buffer
            if (t + 1 < ntiles) {
                const int nb0 = (t + 1) * AKT;
                const int nxt = cur ^ 1;
#pragma unroll
                for (int i = 0; i < 2; i++) {
                    int f = i * 256 + tid;
                    int r = f >> 3, p = f & 7, c = p ^ (r & 7);
                    gload16(&kbase[(size_t)(nb0 + r) * DH + c * 8], &KT[nxt][f * 8]);
                    gload16(&vbase[(size_t)r * SEQ + nb0 + c * 8], &VT[nxt][f * 8]);
                }
            }

            // ---- QK^T
            float s[4][4];
            __builtin_amdgcn_s_setprio(1);
#pragma unroll
            for (int kt = 0; kt < 4; kt++) {
                f32x4 acc = f32x4{0.f, 0.f, 0.f, 0.f};
                int krow = kt * 16 + ln;
                short8 b0 = *(const short8*)&KT[cur][krow * 64 + ((lg ^ (krow & 7)) * 8)];
                short8 b1 = *(const short8*)&KT[cur][krow * 64 + (((4 + lg) ^ (krow & 7)) * 8)];
                acc = __builtin_amdgcn_mfma_f32_16x16x32_bf16(qf0, b0, acc, 0, 0, 0);
                acc = __builtin_amdgcn_mfma_f32_16x16x32_bf16(qf1, b1, acc, 0, 0, 0);
#pragma unroll
                for (int r = 0; r < 4; r++) s[kt][r] = acc[r] * SCALE;
            }
            __builtin_amdgcn_s_setprio(0);

            // causal mask only on the diagonal (last) tile
            if (t == ntiles - 1) {
#pragma unroll
                for (int kt = 0; kt < 4; kt++)
#pragma unroll
                    for (int r = 0; r < 4; r++) {
                        int qrel = wave * 16 + lg * 4 + r;
                        int krel = kt * 16 + ln;
                        if (krel > qrel) s[kt][r] = -1e30f;
                    }
            }

            // ---- online softmax with defer-max (THR=8)
            float pmax[4];
#pragma unroll
            for (int r = 0; r < 4; r++) {
                float v = fmaxf(fmaxf(s[0][r], s[1][r]), fmaxf(s[2][r], s[3][r]));
                pmax[r] = rmax16(v);
            }
            bool ok = true;
#pragma unroll
            for (int r = 0; r < 4; r++) ok = ok && (pmax[r] <= m[r] + 8.f);
            if (!__all(ok)) {
#pragma unroll
                for (int r = 0; r < 4; r++) {
                    float mn = fmaxf(m[r], pmax[r]);
                    float corr = __expf(m[r] - mn);
                    m[r] = mn;
                    l[r] *= corr;
#pragma unroll
                    for (int nt = 0; nt < 4; nt++) o[nt][r] *= corr;
                }
            }

            float rsum[4] = {0.f, 0.f, 0.f, 0.f};
#pragma unroll
            for (int kt = 0; kt < 4; kt++) {
#pragma unroll
                for (int r = 0; r < 4; r++) {
                    float p = __expf(s[kt][r] - m[r]);
                    rsum[r] += p;
                    int qr = lg * 4 + r;
                    int kc = kt * 16 + ln;
                    PT[wave][qr * 64 + ((((kc >> 3) ^ (qr & 7)) * 8) | (kc & 7))] = f2b(p);
                }
            }
#pragma unroll
            for (int r = 0; r < 4; r++) l[r] += rsum16(rsum[r]);

            // ---- PV
            short8 pa0 = *(const short8*)&PT[wave][ln * 64 + ((lg ^ (ln & 7)) * 8)];
            short8 pa1 = *(const short8*)&PT[wave][ln * 64 + (((4 + lg) ^ (ln & 7)) * 8)];
            __builtin_amdgcn_s_setprio(1);
#pragma unroll
            for (int nt = 0; nt < 4; nt++) {
                int vrow = nt * 16 + ln;
                short8 vb0 = *(const short8*)&VT[cur][vrow * 64 + ((lg ^ (vrow & 7)) * 8)];
                short8 vb1 = *(const short8*)&VT[cur][vrow * 64 + (((4 + lg) ^ (vrow & 7)) * 8)];
                o[nt] = __builtin_amdgcn_mfma_f32_16x16x32_bf16(pa0, vb0, o[nt], 0, 0, 0);
                o[nt] = __builtin_amdgcn_mfma_f32_16x16x32_bf16(pa1, vb1, o[nt], 0, 0, 0);
            }
            __builtin_amdgcn_s_setprio(0);

            cur ^= 1;
        }

        // ---- epilogue: bf16 ctx write
#pragma unroll
        for (int r = 0; r < 4; r++) {
            float invl = 1.f / l[r];
            int qg = q0 + wave * 16 + lg * 4 + r;
            ushort_t* op = ctxb + ((size_t)(b * SEQ + qg)) * DM + h * DH;
#pragma unroll
            for (int nt = 0; nt < 4; nt++)
                op[nt * 16 + ln] = f2b(o[nt][r] * invl);
        }
        __syncthreads();   // protect LDS before next strip's prologue staging
    }
}

// ---------------- launch ------------------------------------------------------
extern "C" void kernel_launch(void* const* d_in, const int* in_sizes, int n_in,
                              void* d_out, int out_size, void* d_ws, size_t ws_size,
                              hipStream_t stream) {
    const float* x  = (const float*)d_in[0];
    const float* Wq = (const float*)d_in[1];
    const float* bq = (const float*)d_in[2];
    const float* Wk = (const float*)d_in[3];
    const float* bk = (const float*)d_in[4];
    const float* Wv = (const float*)d_in[5];
    const float* bv = (const float*)d_in[6];
    const float* Wo = (const float*)d_in[7];
    const float* bo = (const float*)d_in[8];
    float* out = (float*)d_out;

    constexpr size_t TSZ = (size_t)MROWS * DM;   // 4194304
    constexpr size_t WSZ = (size_t)DM * DM;      // 1048576
    ushort_t* xb  = (ushort_t*)d_ws;
    ushort_t* Wqt = xb + TSZ;
    ushort_t* Wkt = Wqt + WSZ;
    ushort_t* Wvt = Wkt + WSZ;
    ushort_t* Wot = Wvt + WSZ;
    ushort_t* qbp = Wot + WSZ;
    ushort_t* kbp = qbp + TSZ;
    ushort_t* vtp = kbp + TSZ;
    ushort_t* ctxb = vtp + TSZ;

    conv_x<<<TSZ / 8 / 256, 256, 0, stream>>>(x, xb);
    conv_w<<<dim3(16, 16, 4), 256, 0, stream>>>(Wq, Wk, Wv, Wo, Wqt, Wkt, Wvt, Wot);

    mfma_gemm_qkv<<<dim3(DM / BN, MROWS / BM, 3), 256, 0, stream>>>(
        xb, Wqt, Wkt, Wvt, bq, bk, bv, qbp, kbp, vtp);

    const int rope_items = 2 * BATCH * NH * SEQ * 8;
    rope_kernel<<<rope_items / 256, 256, 0, stream>>>(qbp, kbp);

    attn_mfma<<<dim3(NQT / 2, BATCH * NH), 256, 0, stream>>>(qbp, kbp, vtp, ctxb);

    mfma_gemm_out<<<dim3(DM / BN, MROWS / BM), 256, 0, stream>>>(ctxb, Wot, bo, out);
}

// Round 5
// 147.557 us; speedup vs baseline: 13.6846x; 1.0476x over previous
//
#include <hip/hip_runtime.h>
#include <hip/hip_bf16.h>
#include <math.h>

// Problem constants
constexpr int DM = 1024;
constexpr int SEQ = 2048;
constexpr int BATCH = 2;
constexpr int NH = 16;
constexpr int DH = 64;
constexpr int MROWS = BATCH * SEQ;  // 4096
constexpr float SCALE = 0.125f;

typedef __attribute__((ext_vector_type(8))) short short8;
typedef __attribute__((ext_vector_type(4))) float f32x4;
typedef unsigned short ushort_t;

__device__ __forceinline__ unsigned short f2b(float f) {
    __hip_bfloat16 h = __float2bfloat16(f);
    return __builtin_bit_cast(unsigned short, h);
}
__device__ __forceinline__ float b2f(unsigned short u) {
    unsigned int t = ((unsigned int)u) << 16;
    return __builtin_bit_cast(float, t);
}
// v_cvt_pk_bf16_f32: D = {bf16(hi) : bf16(lo)} (no builtin on gfx950 -> asm)
__device__ __forceinline__ unsigned int cvtpk_bf16(float lo, float hi) {
    unsigned int r;
    asm("v_cvt_pk_bf16_f32 %0, %1, %2" : "=v"(r) : "v"(lo), "v"(hi));
    return r;
}

__device__ __forceinline__ void gload16(const ushort_t* g, ushort_t* l) {
    __builtin_amdgcn_global_load_lds(
        (const __attribute__((address_space(1))) void*)g,
        (__attribute__((address_space(3))) void*)l, 16, 0, 0);
}

// ---------------- converters --------------------------------------------------
__global__ __launch_bounds__(256) void conv_x(const float* __restrict__ x,
                                              ushort_t* __restrict__ xb) {
    const size_t idx = (size_t)blockIdx.x * 256 + threadIdx.x;
    const float4* src = (const float4*)(x + idx * 8);
    float4 a = src[0], b = src[1];
    short8 v;
    v[0] = (short)f2b(a.x); v[1] = (short)f2b(a.y);
    v[2] = (short)f2b(a.z); v[3] = (short)f2b(a.w);
    v[4] = (short)f2b(b.x); v[5] = (short)f2b(b.y);
    v[6] = (short)f2b(b.z); v[7] = (short)f2b(b.w);
    *(short8*)(xb + idx * 8) = v;
}

// Transpose + convert weights: W [K][N] fp32 -> Wt [N][K] bf16
__global__ __launch_bounds__(256) void conv_w(
    const float* __restrict__ Wq, const float* __restrict__ Wk,
    const float* __restrict__ Wv, const float* __restrict__ Wo,
    ushort_t* __restrict__ Wqt, ushort_t* __restrict__ Wkt,
    ushort_t* __restrict__ Wvt, ushort_t* __restrict__ Wot) {
    const float* W; ushort_t* Wt;
    switch (blockIdx.z) {
        case 0:  W = Wq; Wt = Wqt; break;
        case 1:  W = Wk; Wt = Wkt; break;
        case 2:  W = Wv; Wt = Wvt; break;
        default: W = Wo; Wt = Wot; break;
    }
    __shared__ float L[64][65];
    const int n0 = blockIdx.x * 64, k0 = blockIdx.y * 64;
    const int t = threadIdx.x;
    const int tr = t >> 4, tc4 = (t & 15) * 4;
#pragma unroll
    for (int i = 0; i < 4; ++i) {
        int kk = tr + i * 16;
        float4 v = *(const float4*)&W[(size_t)(k0 + kk) * DM + n0 + tc4];
        L[kk][tc4 + 0] = v.x; L[kk][tc4 + 1] = v.y;
        L[kk][tc4 + 2] = v.z; L[kk][tc4 + 3] = v.w;
    }
    __syncthreads();
#pragma unroll
    for (int i = 0; i < 4; ++i) {
        int nn = tr + i * 16;
        ushort4 u;
        u.x = f2b(L[tc4 + 0][nn]); u.y = f2b(L[tc4 + 1][nn]);
        u.z = f2b(L[tc4 + 2][nn]); u.w = f2b(L[tc4 + 3][nn]);
        *(ushort4*)&Wt[(size_t)(n0 + nn) * DM + k0 + tc4] = u;
    }
}

// ---------------- MFMA GEMM core: 128x128 tile, BK=64, 4 waves ---------------
#define BM 128
#define BN 128
#define BKK 64

__device__ __forceinline__ void mfma_core(const ushort_t* __restrict__ A,
                                          const ushort_t* __restrict__ B,
                                          int row0, int col0,
                                          ushort_t* smem, f32x4 (&acc)[4][4]) {
    const int tid = threadIdx.x;
    const int wave = tid >> 6, lane = tid & 63;
    const int lg = lane >> 4, ln = lane & 15;
    const int wr = wave >> 1, wc = wave & 1;
    ushort_t* As = smem;
    ushort_t* Bs = smem + 8192;

    for (int kt = 0; kt < DM / BKK; ++kt) {
        __syncthreads();
#pragma unroll
        for (int i = 0; i < 4; ++i) {
            int f = i * 256 + tid;
            int r = f >> 3, p = f & 7, c = p ^ (r & 7);
            gload16(&A[(size_t)(row0 + r) * DM + kt * BKK + c * 8], &As[f * 8]);
            gload16(&B[(size_t)(col0 + r) * DM + kt * BKK + c * 8], &Bs[f * 8]);
        }
        __syncthreads();

        short8 af[4][2], bf[4][2];
#pragma unroll
        for (int mi = 0; mi < 4; ++mi) {
            int r = wr * 64 + mi * 16 + ln;
#pragma unroll
            for (int ks = 0; ks < 2; ++ks) {
                int c = ks * 4 + lg;
                af[mi][ks] = *(const short8*)&As[r * 64 + ((c ^ (r & 7)) * 8)];
            }
        }
#pragma unroll
        for (int ni = 0; ni < 4; ++ni) {
            int r = wc * 64 + ni * 16 + ln;
#pragma unroll
            for (int ks = 0; ks < 2; ++ks) {
                int c = ks * 4 + lg;
                bf[ni][ks] = *(const short8*)&Bs[r * 64 + ((c ^ (r & 7)) * 8)];
            }
        }
#pragma unroll
        for (int ks = 0; ks < 2; ++ks)
#pragma unroll
            for (int mi = 0; mi < 4; ++mi)
#pragma unroll
                for (int ni = 0; ni < 4; ++ni)
                    acc[mi][ni] = __builtin_amdgcn_mfma_f32_16x16x32_bf16(
                        af[mi][ks], bf[ni][ks], acc[mi][ni], 0, 0, 0);
    }
}

// QKV: z=0 -> qb [B,H,S,DH]; z=1 -> kb; z=2 -> vtb [B,H,DH,S]; all bf16 +bias.
__global__ __launch_bounds__(256) void mfma_gemm_qkv(
    const ushort_t* __restrict__ xb,
    const ushort_t* __restrict__ Wqt, const ushort_t* __restrict__ Wkt,
    const ushort_t* __restrict__ Wvt,
    const float* __restrict__ bq, const float* __restrict__ bk,
    const float* __restrict__ bv,
    ushort_t* __restrict__ qb, ushort_t* __restrict__ kb,
    ushort_t* __restrict__ vtb) {
    const ushort_t* W; const float* bias;
    if (blockIdx.z == 0)      { W = Wqt; bias = bq; }
    else if (blockIdx.z == 1) { W = Wkt; bias = bk; }
    else                      { W = Wvt; bias = bv; }

    const int row0 = blockIdx.y * BM;
    const int col0 = blockIdx.x * BN;
    __shared__ ushort_t smem[16384];
    f32x4 acc[4][4] = {};
    mfma_core(xb, W, row0, col0, smem, acc);

    const int tid = threadIdx.x;
    const int wave = tid >> 6, lane = tid & 63;
    const int lg = lane >> 4, ln = lane & 15;
    const int wr = wave >> 1, wc = wave & 1;
    const bool isV = (blockIdx.z == 2);

    __syncthreads();
    ushort_t* Cs = smem;
#pragma unroll
    for (int mi = 0; mi < 4; ++mi)
#pragma unroll
        for (int ni = 0; ni < 4; ++ni)
#pragma unroll
            for (int r = 0; r < 4; ++r) {
                int mrel = wr * 64 + mi * 16 + lg * 4 + r;
                int nrel = wc * 64 + ni * 16 + ln;
                float v = acc[mi][ni][r] + bias[col0 + nrel];
                Cs[isV ? (nrel * 128 + mrel) : (mrel * 128 + nrel)] = f2b(v);
            }
    __syncthreads();

    if (!isV) {
        ushort_t* out = (blockIdx.z == 0) ? qb : kb;
#pragma unroll
        for (int i = 0; i < 8; ++i) {
            int f = i * 256 + tid;
            int rrow = f >> 4, c8 = f & 15;
            int m = row0 + rrow;
            int b = m >> 11, s = m & (SEQ - 1);
            int n = col0 + c8 * 8;
            int h = n >> 6, d = n & 63;
            *(short8*)&out[((size_t)((b * NH + h) * SEQ) + s) * DH + d] =
                *(const short8*)&Cs[rrow * 128 + c8 * 8];
        }
    } else {
#pragma unroll
        for (int i = 0; i < 8; ++i) {
            int f = i * 256 + tid;
            int nrow = f >> 4, c8 = f & 15;
            int n = col0 + nrow;
            int h = n >> 6, d = n & 63;
            int m = row0 + c8 * 8;
            int b = m >> 11, s = m & (SEQ - 1);
            *(short8*)&vtb[((size_t)((b * NH + h) * DH) + d) * SEQ + s] =
                *(const short8*)&Cs[nrow * 128 + c8 * 8];
        }
    }
}

// Output projection: A = ctxb bf16 [M][DM], B = Wot, out fp32 [M][DM] + bo.
__global__ __launch_bounds__(256) void mfma_gemm_out(
    const ushort_t* __restrict__ ctxb, const ushort_t* __restrict__ Wot,
    const float* __restrict__ bo, float* __restrict__ out) {
    const int row0 = blockIdx.y * BM;
    const int col0 = blockIdx.x * BN;
    __shared__ ushort_t smem[16384];
    f32x4 acc[4][4] = {};
    mfma_core(ctxb, Wot, row0, col0, smem, acc);

    const int tid = threadIdx.x;
    const int wave = tid >> 6, lane = tid & 63;
    const int lg = lane >> 4, ln = lane & 15;
    const int wr = wave >> 1, wc = wave & 1;
#pragma unroll
    for (int mi = 0; mi < 4; ++mi)
#pragma unroll
        for (int ni = 0; ni < 4; ++ni)
#pragma unroll
            for (int r = 0; r < 4; ++r) {
                int m = row0 + wr * 64 + mi * 16 + lg * 4 + r;
                int n = col0 + wc * 64 + ni * 16 + ln;
                out[(size_t)m * DM + n] = acc[mi][ni][r] + bo[n];
            }
}

// ---------------- Partial RoPE on bf16 q and k, in place --------------------
__global__ __launch_bounds__(256) void rope_kernel(ushort_t* __restrict__ qb,
                                                   ushort_t* __restrict__ kb) {
    const int idx = blockIdx.x * 256 + threadIdx.x;
    const int d = idx & 7;
    const int row = idx >> 3;
    constexpr int NROWS = BATCH * NH * SEQ;
    ushort_t* t = (row < NROWS) ? qb : kb;
    const int r = row & (NROWS - 1);
    const int s = r & (SEQ - 1);
    const float inv_freq = __expf(-(float)d * (logf(10000.f) / 8.f));
    const float ang = (float)s * inv_freq;
    float c, si;
    __sincosf(ang, &si, &c);
    ushort_t* base = t + (size_t)r * DH;
    const float t1 = b2f(base[d]);
    const float t2 = b2f(base[d + 8]);
    base[d]     = f2b(t1 * c - t2 * si);
    base[d + 8] = f2b(t1 * si + t2 * c);
}

// ---------------- Causal flash attention, bf16 MFMA, swapped QK^T -----------
// Grid: (16 strip-pairs, 32 bh). Block = 4 waves; wave w owns 16 q-rows.
// Swapped QK^T (mfma(K,Q) -> S^T): lane ln owns q-row ln's full softmax state.
// exp2-domain online softmax with defer-max; P packed via v_cvt_pk_bf16_f32.
#define AQT 64
#define AKT 64
#define NQT (SEQ / AQT)   // 32

__global__ __launch_bounds__(256) void attn_mfma(
    const ushort_t* __restrict__ qb, const ushort_t* __restrict__ kb,
    const ushort_t* __restrict__ vtb, ushort_t* __restrict__ ctxb) {
    constexpr float C1 = 0.18033688f;        // SCALE * log2(e)
    constexpr float THR2 = 11.5415603f;      // 8 * log2(e)
    const int bh = blockIdx.y;
    const int tid = threadIdx.x;
    const int wave = tid >> 6;
    const int lane = tid & 63;
    const int lg = lane >> 4;
    const int ln = lane & 15;

    __shared__ ushort_t KT[2][64 * 64];
    __shared__ ushort_t VT[2][64 * 64];
    __shared__ ushort_t PT[4][16 * 64];

    const ushort_t* kbase = kb + (size_t)bh * SEQ * DH;
    const ushort_t* vbase = vtb + (size_t)bh * DH * SEQ;
    const int b = bh >> 4, h = bh & 15;

    for (int strip = 0; strip < 2; ++strip) {
        const int qt = strip ? (NQT - 1 - blockIdx.x) : blockIdx.x;
        const int q0 = qt * AQT;

        const ushort_t* qrow = qb + ((size_t)bh * SEQ + q0 + wave * 16 + ln) * DH;
        short8 qf0 = *(const short8*)&qrow[lg * 8];
        short8 qf1 = *(const short8*)&qrow[32 + lg * 8];

        f32x4 o[4];
#pragma unroll
        for (int nt = 0; nt < 4; nt++) o[nt] = f32x4{0.f, 0.f, 0.f, 0.f};
        float m2 = -1e30f, l = 0.f;          // per-lane stats for q-row = ln

        const int ntiles = qt + 1;

        // prologue: stage tile 0 into buffer 0
#pragma unroll
        for (int i = 0; i < 2; i++) {
            int f = i * 256 + tid;
            int r = f >> 3, p = f & 7, c = p ^ (r & 7);
            gload16(&kbase[(size_t)r * DH + c * 8], &KT[0][f * 8]);
            gload16(&vbase[(size_t)r * SEQ + c * 8], &VT[0][f * 8]);
        }

        int cur = 0;
        for (int t = 0; t < ntiles; ++t) {
            __syncthreads();   // staged data for tile t visible

            // prefetch tile t+1 into the other buffer
            if (t + 1 < ntiles) {
                const int nb0 = (t + 1) * AKT;
                const int nxt = cur ^ 1;
#pragma unroll
                for (int i = 0; i < 2; i++) {
                    int f = i * 256 + tid;
                    int r = f >> 3, p = f & 7, c = p ^ (r & 7);
                    gload16(&kbase[(size_t)(nb0 + r) * DH + c * 8], &KT[nxt][f * 8]);
                    gload16(&vbase[(size_t)r * SEQ + nb0 + c * 8], &VT[nxt][f * 8]);
                }
            }

            // ---- swapped QK^T: S^T tile, lane holds q=ln, keys kt*16+lg*4+r
            float st[4][4];
            __builtin_amdgcn_s_setprio(1);
#pragma unroll
            for (int kt = 0; kt < 4; kt++) {
                f32x4 acc = f32x4{0.f, 0.f, 0.f, 0.f};
                int krow = kt * 16 + ln;
                short8 b0 = *(const short8*)&KT[cur][krow * 64 + ((lg ^ (krow & 7)) * 8)];
                short8 b1 = *(const short8*)&KT[cur][krow * 64 + (((4 + lg) ^ (krow & 7)) * 8)];
                acc = __builtin_amdgcn_mfma_f32_16x16x32_bf16(b0, qf0, acc, 0, 0, 0);
                acc = __builtin_amdgcn_mfma_f32_16x16x32_bf16(b1, qf1, acc, 0, 0, 0);
#pragma unroll
                for (int r = 0; r < 4; r++) st[kt][r] = acc[r];
            }
            __builtin_amdgcn_s_setprio(0);

            // causal mask only on the diagonal (last) tile: key > q
            if (t == ntiles - 1) {
                const int qrel = wave * 16 + ln;
#pragma unroll
                for (int kt = 0; kt < 4; kt++)
#pragma unroll
                    for (int r = 0; r < 4; r++)
                        if (kt * 16 + lg * 4 + r > qrel) st[kt][r] = -1e30f;
            }

            // ---- online softmax (exp2 domain), defer-max THR=8
            float smax = st[0][0];
#pragma unroll
            for (int kt = 0; kt < 4; kt++)
#pragma unroll
                for (int r = 0; r < 4; r++) smax = fmaxf(smax, st[kt][r]);
            smax = fmaxf(smax, __shfl_xor(smax, 16));
            smax = fmaxf(smax, __shfl_xor(smax, 32));
            const float m2c = C1 * smax;

            if (!__all(m2c <= m2 + THR2)) {
                float m2n = fmaxf(m2, m2c);
                float corr = exp2f(m2 - m2n);
                m2 = m2n;
                l *= corr;
#pragma unroll
                for (int r = 0; r < 4; r++) {
                    float c_o = __shfl(corr, (lane & 48) | (lg * 4 + r));
#pragma unroll
                    for (int nt = 0; nt < 4; nt++) o[nt][r] *= c_o;
                }
            }

            float lsum = 0.f;
#pragma unroll
            for (int kt = 0; kt < 4; kt++) {
                float pv[4];
#pragma unroll
                for (int r = 0; r < 4; r++) {
                    pv[r] = exp2f(fmaf(C1, st[kt][r], -m2));
                    lsum += pv[r];
                }
                uint2 pk;
                pk.x = cvtpk_bf16(pv[0], pv[1]);
                pk.y = cvtpk_bf16(pv[2], pv[3]);
                // PT[q=ln][k=kt*16+lg*4 ..+3], 16B-chunk XOR swizzle
                int addr = ln * 64 + (((kt * 2 + (lg >> 1)) ^ (ln & 7)) * 8) + (lg & 1) * 4;
                *(uint2*)&PT[wave][addr] = pk;
            }
            lsum += __shfl_xor(lsum, 16);
            lsum += __shfl_xor(lsum, 32);
            l += lsum;

            // ---- PV (unchanged layout: A=P[q][k], B=V^T[d][k])
            short8 pa0 = *(const short8*)&PT[wave][ln * 64 + ((lg ^ (ln & 7)) * 8)];
            short8 pa1 = *(const short8*)&PT[wave][ln * 64 + (((4 + lg) ^ (ln & 7)) * 8)];
            __builtin_amdgcn_s_setprio(1);
#pragma unroll
            for (int nt = 0; nt < 4; nt++) {
                int vrow = nt * 16 + ln;
                short8 vb0 = *(const short8*)&VT[cur][vrow * 64 + ((lg ^ (vrow & 7)) * 8)];
                short8 vb1 = *(const short8*)&VT[cur][vrow * 64 + (((4 + lg) ^ (vrow & 7)) * 8)];
                o[nt] = __builtin_amdgcn_mfma_f32_16x16x32_bf16(pa0, vb0, o[nt], 0, 0, 0);
                o[nt] = __builtin_amdgcn_mfma_f32_16x16x32_bf16(pa1, vb1, o[nt], 0, 0, 0);
            }
            __builtin_amdgcn_s_setprio(0);

            cur ^= 1;
        }

        // ---- epilogue: gather 1/l for q=lg*4+r, bf16 ctx write
        const float rcp = 1.f / l;
#pragma unroll
        for (int r = 0; r < 4; r++) {
            float invl = __shfl(rcp, (lane & 48) | (lg * 4 + r));
            int qg = q0 + wave * 16 + lg * 4 + r;
            ushort_t* op = ctxb + ((size_t)(b * SEQ + qg)) * DM + h * DH;
#pragma unroll
            for (int nt = 0; nt < 4; nt++)
                op[nt * 16 + ln] = f2b(o[nt][r] * invl);
        }
        __syncthreads();   // protect LDS before next strip's prologue staging
    }
}

// ---------------- launch ------------------------------------------------------
extern "C" void kernel_launch(void* const* d_in, const int* in_sizes, int n_in,
                              void* d_out, int out_size, void* d_ws, size_t ws_size,
                              hipStream_t stream) {
    const float* x  = (const float*)d_in[0];
    const float* Wq = (const float*)d_in[1];
    const float* bq = (const float*)d_in[2];
    const float* Wk = (const float*)d_in[3];
    const float* bk = (const float*)d_in[4];
    const float* Wv = (const float*)d_in[5];
    const float* bv = (const float*)d_in[6];
    const float* Wo = (const float*)d_in[7];
    const float* bo = (const float*)d_in[8];
    float* out = (float*)d_out;

    constexpr size_t TSZ = (size_t)MROWS * DM;   // 4194304
    constexpr size_t WSZ = (size_t)DM * DM;      // 1048576
    ushort_t* xb  = (ushort_t*)d_ws;
    ushort_t* Wqt = xb + TSZ;
    ushort_t* Wkt = Wqt + WSZ;
    ushort_t* Wvt = Wkt + WSZ;
    ushort_t* Wot = Wvt + WSZ;
    ushort_t* qbp = Wot + WSZ;
    ushort_t* kbp = qbp + TSZ;
    ushort_t* vtp = kbp + TSZ;
    ushort_t* ctxb = vtp + TSZ;

    conv_x<<<TSZ / 8 / 256, 256, 0, stream>>>(x, xb);
    conv_w<<<dim3(16, 16, 4), 256, 0, stream>>>(Wq, Wk, Wv, Wo, Wqt, Wkt, Wvt, Wot);

    mfma_gemm_qkv<<<dim3(DM / BN, MROWS / BM, 3), 256, 0, stream>>>(
        xb, Wqt, Wkt, Wvt, bq, bk, bv, qbp, kbp, vtp);

    const int rope_items = 2 * BATCH * NH * SEQ * 8;
    rope_kernel<<<rope_items / 256, 256, 0, stream>>>(qbp, kbp);

    attn_mfma<<<dim3(NQT / 2, BATCH * NH), 256, 0, stream>>>(qbp, kbp, vtp, ctxb);

    mfma_gemm_out<<<dim3(DM / BN, MROWS / BM), 256, 0, stream>>>(ctxb, Wot, bo, out);
}

// Round 6
// 137.566 us; speedup vs baseline: 14.6784x; 1.0726x over previous
//
#include <hip/hip_runtime.h>
#include <hip/hip_bf16.h>
#include <math.h>

// Problem constants
constexpr int DM = 1024;
constexpr int SEQ = 2048;
constexpr int BATCH = 2;
constexpr int NH = 16;
constexpr int DH = 64;
constexpr int MROWS = BATCH * SEQ;  // 4096
constexpr float SCALE = 0.125f;

typedef __attribute__((ext_vector_type(8))) short short8;
typedef __attribute__((ext_vector_type(4))) float f32x4;
typedef unsigned short ushort_t;

__device__ __forceinline__ unsigned short f2b(float f) {
    __hip_bfloat16 h = __float2bfloat16(f);
    return __builtin_bit_cast(unsigned short, h);
}
__device__ __forceinline__ float b2f(unsigned short u) {
    unsigned int t = ((unsigned int)u) << 16;
    return __builtin_bit_cast(float, t);
}
// v_cvt_pk_bf16_f32: D = {bf16(hi) : bf16(lo)} (no builtin on gfx950 -> asm)
__device__ __forceinline__ unsigned int cvtpk_bf16(float lo, float hi) {
    unsigned int r;
    asm("v_cvt_pk_bf16_f32 %0, %1, %2" : "=v"(r) : "v"(lo), "v"(hi));
    return r;
}

__device__ __forceinline__ void gload16(const ushort_t* g, ushort_t* l) {
    __builtin_amdgcn_global_load_lds(
        (const __attribute__((address_space(1))) void*)g,
        (__attribute__((address_space(3))) void*)l, 16, 0, 0);
}

// ---------------- converters --------------------------------------------------
__global__ __launch_bounds__(256) void conv_x(const float* __restrict__ x,
                                              ushort_t* __restrict__ xb) {
    const size_t idx = (size_t)blockIdx.x * 256 + threadIdx.x;
    const float4* src = (const float4*)(x + idx * 8);
    float4 a = src[0], b = src[1];
    short8 v;
    v[0] = (short)f2b(a.x); v[1] = (short)f2b(a.y);
    v[2] = (short)f2b(a.z); v[3] = (short)f2b(a.w);
    v[4] = (short)f2b(b.x); v[5] = (short)f2b(b.y);
    v[6] = (short)f2b(b.z); v[7] = (short)f2b(b.w);
    *(short8*)(xb + idx * 8) = v;
}

// Transpose + convert weights: W [K][N] fp32 -> Wt [N][K] bf16
__global__ __launch_bounds__(256) void conv_w(
    const float* __restrict__ Wq, const float* __restrict__ Wk,
    const float* __restrict__ Wv, const float* __restrict__ Wo,
    ushort_t* __restrict__ Wqt, ushort_t* __restrict__ Wkt,
    ushort_t* __restrict__ Wvt, ushort_t* __restrict__ Wot) {
    const float* W; ushort_t* Wt;
    switch (blockIdx.z) {
        case 0:  W = Wq; Wt = Wqt; break;
        case 1:  W = Wk; Wt = Wkt; break;
        case 2:  W = Wv; Wt = Wvt; break;
        default: W = Wo; Wt = Wot; break;
    }
    __shared__ float L[64][65];
    const int n0 = blockIdx.x * 64, k0 = blockIdx.y * 64;
    const int t = threadIdx.x;
    const int tr = t >> 4, tc4 = (t & 15) * 4;
#pragma unroll
    for (int i = 0; i < 4; ++i) {
        int kk = tr + i * 16;
        float4 v = *(const float4*)&W[(size_t)(k0 + kk) * DM + n0 + tc4];
        L[kk][tc4 + 0] = v.x; L[kk][tc4 + 1] = v.y;
        L[kk][tc4 + 2] = v.z; L[kk][tc4 + 3] = v.w;
    }
    __syncthreads();
#pragma unroll
    for (int i = 0; i < 4; ++i) {
        int nn = tr + i * 16;
        ushort4 u;
        u.x = f2b(L[tc4 + 0][nn]); u.y = f2b(L[tc4 + 1][nn]);
        u.z = f2b(L[tc4 + 2][nn]); u.w = f2b(L[tc4 + 3][nn]);
        *(ushort4*)&Wt[(size_t)(n0 + nn) * DM + k0 + tc4] = u;
    }
}

// ---------------- MFMA GEMM core: 128x128 tile, BK=64, 4 waves ---------------
#define BM 128
#define BN 128
#define BKK 64

__device__ __forceinline__ void mfma_core(const ushort_t* __restrict__ A,
                                          const ushort_t* __restrict__ B,
                                          int row0, int col0,
                                          ushort_t* smem, f32x4 (&acc)[4][4]) {
    const int tid = threadIdx.x;
    const int wave = tid >> 6, lane = tid & 63;
    const int lg = lane >> 4, ln = lane & 15;
    const int wr = wave >> 1, wc = wave & 1;
    ushort_t* As = smem;
    ushort_t* Bs = smem + 8192;

    for (int kt = 0; kt < DM / BKK; ++kt) {
        __syncthreads();
#pragma unroll
        for (int i = 0; i < 4; ++i) {
            int f = i * 256 + tid;
            int r = f >> 3, p = f & 7, c = p ^ (r & 7);
            gload16(&A[(size_t)(row0 + r) * DM + kt * BKK + c * 8], &As[f * 8]);
            gload16(&B[(size_t)(col0 + r) * DM + kt * BKK + c * 8], &Bs[f * 8]);
        }
        __syncthreads();

        short8 af[4][2], bf[4][2];
#pragma unroll
        for (int mi = 0; mi < 4; ++mi) {
            int r = wr * 64 + mi * 16 + ln;
#pragma unroll
            for (int ks = 0; ks < 2; ++ks) {
                int c = ks * 4 + lg;
                af[mi][ks] = *(const short8*)&As[r * 64 + ((c ^ (r & 7)) * 8)];
            }
        }
#pragma unroll
        for (int ni = 0; ni < 4; ++ni) {
            int r = wc * 64 + ni * 16 + ln;
#pragma unroll
            for (int ks = 0; ks < 2; ++ks) {
                int c = ks * 4 + lg;
                bf[ni][ks] = *(const short8*)&Bs[r * 64 + ((c ^ (r & 7)) * 8)];
            }
        }
#pragma unroll
        for (int ks = 0; ks < 2; ++ks)
#pragma unroll
            for (int mi = 0; mi < 4; ++mi)
#pragma unroll
                for (int ni = 0; ni < 4; ++ni)
                    acc[mi][ni] = __builtin_amdgcn_mfma_f32_16x16x32_bf16(
                        af[mi][ks], bf[ni][ks], acc[mi][ni], 0, 0, 0);
    }
}

// QKV: z=0 -> qb [B,H,S,DH]; z=1 -> kb; z=2 -> vtb [B,H,DH,S]; all bf16 +bias.
// Partial RoPE (rot dim 16) is fused into the q/k scatter: the d<8 chunk and
// its d+8 partner are adjacent in the Cs tile.
__global__ __launch_bounds__(256) void mfma_gemm_qkv(
    const ushort_t* __restrict__ xb,
    const ushort_t* __restrict__ Wqt, const ushort_t* __restrict__ Wkt,
    const ushort_t* __restrict__ Wvt,
    const float* __restrict__ bq, const float* __restrict__ bk,
    const float* __restrict__ bv,
    ushort_t* __restrict__ qb, ushort_t* __restrict__ kb,
    ushort_t* __restrict__ vtb) {
    const ushort_t* W; const float* bias;
    if (blockIdx.z == 0)      { W = Wqt; bias = bq; }
    else if (blockIdx.z == 1) { W = Wkt; bias = bk; }
    else                      { W = Wvt; bias = bv; }

    const int row0 = blockIdx.y * BM;
    const int col0 = blockIdx.x * BN;
    __shared__ ushort_t smem[16384];
    f32x4 acc[4][4] = {};
    mfma_core(xb, W, row0, col0, smem, acc);

    const int tid = threadIdx.x;
    const int wave = tid >> 6, lane = tid & 63;
    const int lg = lane >> 4, ln = lane & 15;
    const int wr = wave >> 1, wc = wave & 1;
    const bool isV = (blockIdx.z == 2);

    __syncthreads();
    ushort_t* Cs = smem;
#pragma unroll
    for (int mi = 0; mi < 4; ++mi)
#pragma unroll
        for (int ni = 0; ni < 4; ++ni)
#pragma unroll
            for (int r = 0; r < 4; ++r) {
                int mrel = wr * 64 + mi * 16 + lg * 4 + r;
                int nrel = wc * 64 + ni * 16 + ln;
                float v = acc[mi][ni][r] + bias[col0 + nrel];
                Cs[isV ? (nrel * 128 + mrel) : (mrel * 128 + nrel)] = f2b(v);
            }
    __syncthreads();

    if (!isV) {
        ushort_t* out = (blockIdx.z == 0) ? qb : kb;
#pragma unroll
        for (int i = 0; i < 8; ++i) {
            int f = i * 256 + tid;
            int rrow = f >> 4, c8 = f & 15;
            int m = row0 + rrow;
            int b = m >> 11, s = m & (SEQ - 1);
            int n = col0 + c8 * 8;
            int h = n >> 6, d = n & 63;
            short8 val;
            if (d < 16) {
                // fused partial RoPE: chunk pair lives at head-chunk 0/1
                const ushort_t* base = &Cs[rrow * 128 + (c8 & 8) * 8];
                const bool hi = (d >= 8);
#pragma unroll
                for (int j = 0; j < 8; ++j) {
                    float t1 = b2f(base[j]);
                    float t2 = b2f(base[8 + j]);
                    float invf = __expf(-(float)j * 1.1512925465f); // ln(1e4)/8
                    float ang = (float)s * invf;
                    float c_, si_;
                    __sincosf(ang, &si_, &c_);
                    val[j] = (short)f2b(hi ? (t1 * si_ + t2 * c_)
                                           : (t1 * c_ - t2 * si_));
                }
            } else {
                val = *(const short8*)&Cs[rrow * 128 + c8 * 8];
            }
            *(short8*)&out[((size_t)((b * NH + h) * SEQ) + s) * DH + d] = val;
        }
    } else {
#pragma unroll
        for (int i = 0; i < 8; ++i) {
            int f = i * 256 + tid;
            int nrow = f >> 4, c8 = f & 15;
            int n = col0 + nrow;
            int h = n >> 6, d = n & 63;
            int m = row0 + c8 * 8;
            int b = m >> 11, s = m & (SEQ - 1);
            *(short8*)&vtb[((size_t)((b * NH + h) * DH) + d) * SEQ + s] =
                *(const short8*)&Cs[nrow * 128 + c8 * 8];
        }
    }
}

// Output projection: A = ctxb bf16 [M][DM], B = Wot, out fp32 [M][DM] + bo.
__global__ __launch_bounds__(256) void mfma_gemm_out(
    const ushort_t* __restrict__ ctxb, const ushort_t* __restrict__ Wot,
    const float* __restrict__ bo, float* __restrict__ out) {
    const int row0 = blockIdx.y * BM;
    const int col0 = blockIdx.x * BN;
    __shared__ ushort_t smem[16384];
    f32x4 acc[4][4] = {};
    mfma_core(ctxb, Wot, row0, col0, smem, acc);

    const int tid = threadIdx.x;
    const int wave = tid >> 6, lane = tid & 63;
    const int lg = lane >> 4, ln = lane & 15;
    const int wr = wave >> 1, wc = wave & 1;
#pragma unroll
    for (int mi = 0; mi < 4; ++mi)
#pragma unroll
        for (int ni = 0; ni < 4; ++ni)
#pragma unroll
            for (int r = 0; r < 4; ++r) {
                int m = row0 + wr * 64 + mi * 16 + lg * 4 + r;
                int n = col0 + wc * 64 + ni * 16 + ln;
                out[(size_t)m * DM + n] = acc[mi][ni][r] + bo[n];
            }
}

// ---------------- Causal flash attention, bf16 MFMA, swapped QK^T -----------
// Grid: (32 bh, 32 qt-slots). One block per 64-row q-tile; all 1024 blocks
// co-resident (40 KB LDS -> 4 blocks/CU, 16 waves/CU). qt-slot y is permuted
// {y0, 15-y0, 16+y0, 31-y0} so the 4 blocks a CU hosts (id stride 256) have
// a constant work sum (dispatch heuristic only; correctness independent).
#define AQT 64
#define AKT 64
#define NQT (SEQ / AQT)   // 32

__global__ __launch_bounds__(256) void attn_mfma(
    const ushort_t* __restrict__ qb, const ushort_t* __restrict__ kb,
    const ushort_t* __restrict__ vtb, ushort_t* __restrict__ ctxb) {
    constexpr float C1 = 0.18033688f;        // SCALE * log2(e)
    constexpr float THR2 = 11.5415603f;      // 8 * log2(e)
    const int bh = blockIdx.x;
    const int y = blockIdx.y;
    const int y0 = y & 7, g = y >> 3;
    const int qt = (g == 0) ? y0 : (g == 1) ? (15 - y0)
                 : (g == 2) ? (16 + y0) : (31 - y0);
    const int q0 = qt * AQT;

    const int tid = threadIdx.x;
    const int wave = tid >> 6;
    const int lane = tid & 63;
    const int lg = lane >> 4;
    const int ln = lane & 15;

    __shared__ ushort_t KT[2][64 * 64];
    __shared__ ushort_t VT[2][64 * 64];
    __shared__ ushort_t PT[4][16 * 64];

    const ushort_t* kbase = kb + (size_t)bh * SEQ * DH;
    const ushort_t* vbase = vtb + (size_t)bh * DH * SEQ;
    const int b = bh >> 4, h = bh & 15;

    const ushort_t* qrow = qb + ((size_t)bh * SEQ + q0 + wave * 16 + ln) * DH;
    short8 qf0 = *(const short8*)&qrow[lg * 8];
    short8 qf1 = *(const short8*)&qrow[32 + lg * 8];

    f32x4 o[4];
#pragma unroll
    for (int nt = 0; nt < 4; nt++) o[nt] = f32x4{0.f, 0.f, 0.f, 0.f};
    float m2 = -1e30f, l = 0.f;          // per-lane stats for q-row = ln

    const int ntiles = qt + 1;

    // prologue: stage tile 0 into buffer 0
#pragma unroll
    for (int i = 0; i < 2; i++) {
        int f = i * 256 + tid;
        int r = f >> 3, p = f & 7, c = p ^ (r & 7);
        gload16(&kbase[(size_t)r * DH + c * 8], &KT[0][f * 8]);
        gload16(&vbase[(size_t)r * SEQ + c * 8], &VT[0][f * 8]);
    }

    int cur = 0;
    for (int t = 0; t < ntiles; ++t) {
        __syncthreads();   // staged data for tile t visible

        // prefetch tile t+1 into the other buffer
        if (t + 1 < ntiles) {
            const int nb0 = (t + 1) * AKT;
            const int nxt = cur ^ 1;
#pragma unroll
            for (int i = 0; i < 2; i++) {
                int f = i * 256 + tid;
                int r = f >> 3, p = f & 7, c = p ^ (r & 7);
                gload16(&kbase[(size_t)(nb0 + r) * DH + c * 8], &KT[nxt][f * 8]);
                gload16(&vbase[(size_t)r * SEQ + nb0 + c * 8], &VT[nxt][f * 8]);
            }
        }

        // ---- swapped QK^T: S^T tile, lane holds q=ln, keys kt*16+lg*4+r
        float st[4][4];
        __builtin_amdgcn_s_setprio(1);
#pragma unroll
        for (int kt = 0; kt < 4; kt++) {
            f32x4 acc = f32x4{0.f, 0.f, 0.f, 0.f};
            int krow = kt * 16 + ln;
            short8 b0 = *(const short8*)&KT[cur][krow * 64 + ((lg ^ (krow & 7)) * 8)];
            short8 b1 = *(const short8*)&KT[cur][krow * 64 + (((4 + lg) ^ (krow & 7)) * 8)];
            acc = __builtin_amdgcn_mfma_f32_16x16x32_bf16(b0, qf0, acc, 0, 0, 0);
            acc = __builtin_amdgcn_mfma_f32_16x16x32_bf16(b1, qf1, acc, 0, 0, 0);
#pragma unroll
            for (int r = 0; r < 4; r++) st[kt][r] = acc[r];
        }
        __builtin_amdgcn_s_setprio(0);

        // causal mask only on the diagonal (last) tile: key > q
        if (t == ntiles - 1) {
            const int qrel = wave * 16 + ln;
#pragma unroll
            for (int kt = 0; kt < 4; kt++)
#pragma unroll
                for (int r = 0; r < 4; r++)
                    if (kt * 16 + lg * 4 + r > qrel) st[kt][r] = -1e30f;
        }

        // ---- online softmax (exp2 domain), defer-max THR=8
        float smax = st[0][0];
#pragma unroll
        for (int kt = 0; kt < 4; kt++)
#pragma unroll
            for (int r = 0; r < 4; r++) smax = fmaxf(smax, st[kt][r]);
        smax = fmaxf(smax, __shfl_xor(smax, 16));
        smax = fmaxf(smax, __shfl_xor(smax, 32));
        const float m2c = C1 * smax;

        if (!__all(m2c <= m2 + THR2)) {
            float m2n = fmaxf(m2, m2c);
            float corr = exp2f(m2 - m2n);
            m2 = m2n;
            l *= corr;
#pragma unroll
            for (int r = 0; r < 4; r++) {
                float c_o = __shfl(corr, (lane & 48) | (lg * 4 + r));
#pragma unroll
                for (int nt = 0; nt < 4; nt++) o[nt][r] *= c_o;
            }
        }

        float lsum = 0.f;
#pragma unroll
        for (int kt = 0; kt < 4; kt++) {
            float pv[4];
#pragma unroll
            for (int r = 0; r < 4; r++) {
                pv[r] = exp2f(fmaf(C1, st[kt][r], -m2));
                lsum += pv[r];
            }
            uint2 pk;
            pk.x = cvtpk_bf16(pv[0], pv[1]);
            pk.y = cvtpk_bf16(pv[2], pv[3]);
            // PT[q=ln][k=kt*16+lg*4 ..+3], 16B-chunk XOR swizzle
            int addr = ln * 64 + (((kt * 2 + (lg >> 1)) ^ (ln & 7)) * 8) + (lg & 1) * 4;
            *(uint2*)&PT[wave][addr] = pk;
        }
        lsum += __shfl_xor(lsum, 16);
        lsum += __shfl_xor(lsum, 32);
        l += lsum;

        // ---- PV (A=P[q][k], B=V^T[d][k])
        short8 pa0 = *(const short8*)&PT[wave][ln * 64 + ((lg ^ (ln & 7)) * 8)];
        short8 pa1 = *(const short8*)&PT[wave][ln * 64 + (((4 + lg) ^ (ln & 7)) * 8)];
        __builtin_amdgcn_s_setprio(1);
#pragma unroll
        for (int nt = 0; nt < 4; nt++) {
            int vrow = nt * 16 + ln;
            short8 vb0 = *(const short8*)&VT[cur][vrow * 64 + ((lg ^ (vrow & 7)) * 8)];
            short8 vb1 = *(const short8*)&VT[cur][vrow * 64 + (((4 + lg) ^ (vrow & 7)) * 8)];
            o[nt] = __builtin_amdgcn_mfma_f32_16x16x32_bf16(pa0, vb0, o[nt], 0, 0, 0);
            o[nt] = __builtin_amdgcn_mfma_f32_16x16x32_bf16(pa1, vb1, o[nt], 0, 0, 0);
        }
        __builtin_amdgcn_s_setprio(0);

        cur ^= 1;
    }

    // ---- epilogue: gather 1/l for q=lg*4+r, bf16 ctx write
    const float rcp = 1.f / l;
#pragma unroll
    for (int r = 0; r < 4; r++) {
        float invl = __shfl(rcp, (lane & 48) | (lg * 4 + r));
        int qg = q0 + wave * 16 + lg * 4 + r;
        ushort_t* op = ctxb + ((size_t)(b * SEQ + qg)) * DM + h * DH;
#pragma unroll
        for (int nt = 0; nt < 4; nt++)
            op[nt * 16 + ln] = f2b(o[nt][r] * invl);
    }
}

// ---------------- launch ------------------------------------------------------
extern "C" void kernel_launch(void* const* d_in, const int* in_sizes, int n_in,
                              void* d_out, int out_size, void* d_ws, size_t ws_size,
                              hipStream_t stream) {
    const float* x  = (const float*)d_in[0];
    const float* Wq = (const float*)d_in[1];
    const float* bq = (const float*)d_in[2];
    const float* Wk = (const float*)d_in[3];
    const float* bk = (const float*)d_in[4];
    const float* Wv = (const float*)d_in[5];
    const float* bv = (const float*)d_in[6];
    const float* Wo = (const float*)d_in[7];
    const float* bo = (const float*)d_in[8];
    float* out = (float*)d_out;

    constexpr size_t TSZ = (size_t)MROWS * DM;   // 4194304
    constexpr size_t WSZ = (size_t)DM * DM;      // 1048576
    ushort_t* xb  = (ushort_t*)d_ws;
    ushort_t* Wqt = xb + TSZ;
    ushort_t* Wkt = Wqt + WSZ;
    ushort_t* Wvt = Wkt + WSZ;
    ushort_t* Wot = Wvt + WSZ;
    ushort_t* qbp = Wot + WSZ;
    ushort_t* kbp = qbp + TSZ;
    ushort_t* vtp = kbp + TSZ;
    ushort_t* ctxb = vtp + TSZ;

    conv_x<<<TSZ / 8 / 256, 256, 0, stream>>>(x, xb);
    conv_w<<<dim3(16, 16, 4), 256, 0, stream>>>(Wq, Wk, Wv, Wo, Wqt, Wkt, Wvt, Wot);

    // QKV projections (+bias, fused partial RoPE, bf16 head layout, V^T)
    mfma_gemm_qkv<<<dim3(DM / BN, MROWS / BM, 3), 256, 0, stream>>>(
        xb, Wqt, Wkt, Wvt, bq, bk, bv, qbp, kbp, vtp);

    // causal MFMA attention -> ctx bf16 [B,S,DM]
    attn_mfma<<<dim3(BATCH * NH, NQT), 256, 0, stream>>>(qbp, kbp, vtp, ctxb);

    // output projection (MFMA, fp32 out)
    mfma_gemm_out<<<dim3(DM / BN, MROWS / BM), 256, 0, stream>>>(ctxb, Wot, bo, out);
}

// Round 7
// 123.929 us; speedup vs baseline: 16.2937x; 1.1100x over previous
//
#include <hip/hip_runtime.h>
#include <hip/hip_bf16.h>
#include <math.h>

// Problem constants
constexpr int DM = 1024;
constexpr int SEQ = 2048;
constexpr int BATCH = 2;
constexpr int NH = 16;
constexpr int DH = 64;
constexpr int MROWS = BATCH * SEQ;  // 4096
constexpr float SCALE = 0.125f;

typedef __attribute__((ext_vector_type(8))) short short8;
typedef __attribute__((ext_vector_type(4))) float f32x4;
typedef unsigned short ushort_t;

__device__ __forceinline__ unsigned short f2b(float f) {
    __hip_bfloat16 h = __float2bfloat16(f);
    return __builtin_bit_cast(unsigned short, h);
}
__device__ __forceinline__ float b2f(unsigned short u) {
    unsigned int t = ((unsigned int)u) << 16;
    return __builtin_bit_cast(float, t);
}
// v_cvt_pk_bf16_f32: D = {bf16(hi) : bf16(lo)} (no builtin on gfx950 -> asm)
__device__ __forceinline__ unsigned int cvtpk_bf16(float lo, float hi) {
    unsigned int r;
    asm("v_cvt_pk_bf16_f32 %0, %1, %2" : "=v"(r) : "v"(lo), "v"(hi));
    return r;
}

__device__ __forceinline__ void gload16(const ushort_t* g, ushort_t* l) {
    __builtin_amdgcn_global_load_lds(
        (const __attribute__((address_space(1))) void*)g,
        (__attribute__((address_space(3))) void*)l, 16, 0, 0);
}

// ---------------- converters --------------------------------------------------
__global__ __launch_bounds__(256) void conv_x(const float* __restrict__ x,
                                              ushort_t* __restrict__ xb) {
    const size_t idx = (size_t)blockIdx.x * 256 + threadIdx.x;
    const float4* src = (const float4*)(x + idx * 8);
    float4 a = src[0], b = src[1];
    short8 v;
    v[0] = (short)f2b(a.x); v[1] = (short)f2b(a.y);
    v[2] = (short)f2b(a.z); v[3] = (short)f2b(a.w);
    v[4] = (short)f2b(b.x); v[5] = (short)f2b(b.y);
    v[6] = (short)f2b(b.z); v[7] = (short)f2b(b.w);
    *(short8*)(xb + idx * 8) = v;
}

// Transpose + convert weights: W [K][N] fp32 -> Wt [N][K] bf16
__global__ __launch_bounds__(256) void conv_w(
    const float* __restrict__ Wq, const float* __restrict__ Wk,
    const float* __restrict__ Wv, const float* __restrict__ Wo,
    ushort_t* __restrict__ Wqt, ushort_t* __restrict__ Wkt,
    ushort_t* __restrict__ Wvt, ushort_t* __restrict__ Wot) {
    const float* W; ushort_t* Wt;
    switch (blockIdx.z) {
        case 0:  W = Wq; Wt = Wqt; break;
        case 1:  W = Wk; Wt = Wkt; break;
        case 2:  W = Wv; Wt = Wvt; break;
        default: W = Wo; Wt = Wot; break;
    }
    __shared__ float L[64][65];
    const int n0 = blockIdx.x * 64, k0 = blockIdx.y * 64;
    const int t = threadIdx.x;
    const int tr = t >> 4, tc4 = (t & 15) * 4;
#pragma unroll
    for (int i = 0; i < 4; ++i) {
        int kk = tr + i * 16;
        float4 v = *(const float4*)&W[(size_t)(k0 + kk) * DM + n0 + tc4];
        L[kk][tc4 + 0] = v.x; L[kk][tc4 + 1] = v.y;
        L[kk][tc4 + 2] = v.z; L[kk][tc4 + 3] = v.w;
    }
    __syncthreads();
#pragma unroll
    for (int i = 0; i < 4; ++i) {
        int nn = tr + i * 16;
        ushort4 u;
        u.x = f2b(L[tc4 + 0][nn]); u.y = f2b(L[tc4 + 1][nn]);
        u.z = f2b(L[tc4 + 2][nn]); u.w = f2b(L[tc4 + 3][nn]);
        *(ushort4*)&Wt[(size_t)(n0 + nn) * DM + k0 + tc4] = u;
    }
}

// ---------------- MFMA GEMM core: 128x128 tile, BK=32, double-buffered -------
// 2-phase pipeline (T3-minimum): issue next tile's global_load_lds BEFORE
// computing current tile; single __syncthreads (vmcnt drain) per K-step.
// LDS: 2 x (A 8KB + B 8KB) = 32 KB -> 5 blocks/CU capacity, grid fully resident.
#define BM 128
#define BN 128
#define BKK 32
#define NKT (DM / BKK)   // 32

__device__ __forceinline__ void stage_tile(const ushort_t* __restrict__ A,
                                           const ushort_t* __restrict__ B,
                                           int row0, int col0, int kt,
                                           ushort_t* As, ushort_t* Bs, int tid) {
#pragma unroll
    for (int i = 0; i < 2; ++i) {
        int f = i * 256 + tid;                    // [0,512)
        int r = f >> 2, c = (f & 3) ^ (r & 3);    // inverse-swizzled source
        gload16(&A[(size_t)(row0 + r) * DM + kt * BKK + c * 8], &As[f * 8]);
        gload16(&B[(size_t)(col0 + r) * DM + kt * BKK + c * 8], &Bs[f * 8]);
    }
}

__device__ __forceinline__ void mfma_core(const ushort_t* __restrict__ A,
                                          const ushort_t* __restrict__ B,
                                          int row0, int col0,
                                          ushort_t* smem, f32x4 (&acc)[4][4]) {
    const int tid = threadIdx.x;
    const int wave = tid >> 6, lane = tid & 63;
    const int lg = lane >> 4, ln = lane & 15;
    const int wr = wave >> 1, wc = wave & 1;

    // prologue: stage K-tile 0 into buffer 0
    stage_tile(A, B, row0, col0, 0, smem, smem + 4096, tid);
    __syncthreads();

    int cur = 0;
    for (int kt = 0; kt < NKT; ++kt) {
        ushort_t* As = smem + cur * 8192;
        ushort_t* Bs = As + 4096;
        // prefetch next K-tile into the other buffer (stays in flight
        // across the compute; the end-of-step barrier drains it)
        if (kt + 1 < NKT) {
            ushort_t* An = smem + (cur ^ 1) * 8192;
            stage_tile(A, B, row0, col0, kt + 1, An, An + 4096, tid);
        }

        short8 af[4], bf[4];
#pragma unroll
        for (int mi = 0; mi < 4; ++mi) {
            int r = wr * 64 + mi * 16 + ln;
            af[mi] = *(const short8*)&As[r * 32 + ((lg ^ (r & 3)) * 8)];
        }
#pragma unroll
        for (int ni = 0; ni < 4; ++ni) {
            int r = wc * 64 + ni * 16 + ln;
            bf[ni] = *(const short8*)&Bs[r * 32 + ((lg ^ (r & 3)) * 8)];
        }
        __builtin_amdgcn_s_setprio(1);
#pragma unroll
        for (int mi = 0; mi < 4; ++mi)
#pragma unroll
            for (int ni = 0; ni < 4; ++ni)
                acc[mi][ni] = __builtin_amdgcn_mfma_f32_16x16x32_bf16(
                    af[mi], bf[ni], acc[mi][ni], 0, 0, 0);
        __builtin_amdgcn_s_setprio(0);

        __syncthreads();   // drains prefetch (vmcnt 0) + guards buffer reuse
        cur ^= 1;
    }
}

// QKV: z=0 -> qb [B,H,S,DH]; z=1 -> kb; z=2 -> vtb [B,H,DH,S]; all bf16 +bias.
// Partial RoPE (rot dim 16) fused into the q/k scatter.
__global__ __launch_bounds__(256) void mfma_gemm_qkv(
    const ushort_t* __restrict__ xb,
    const ushort_t* __restrict__ Wqt, const ushort_t* __restrict__ Wkt,
    const ushort_t* __restrict__ Wvt,
    const float* __restrict__ bq, const float* __restrict__ bk,
    const float* __restrict__ bv,
    ushort_t* __restrict__ qb, ushort_t* __restrict__ kb,
    ushort_t* __restrict__ vtb) {
    const ushort_t* W; const float* bias;
    if (blockIdx.z == 0)      { W = Wqt; bias = bq; }
    else if (blockIdx.z == 1) { W = Wkt; bias = bk; }
    else                      { W = Wvt; bias = bv; }

    const int row0 = blockIdx.y * BM;
    const int col0 = blockIdx.x * BN;
    __shared__ ushort_t smem[16384];
    f32x4 acc[4][4] = {};
    mfma_core(xb, W, row0, col0, smem, acc);

    const int tid = threadIdx.x;
    const int wave = tid >> 6, lane = tid & 63;
    const int lg = lane >> 4, ln = lane & 15;
    const int wr = wave >> 1, wc = wave & 1;
    const bool isV = (blockIdx.z == 2);

    __syncthreads();
    ushort_t* Cs = smem;   // 128x128 bf16 = 32 KB (aliases the dbuf)
#pragma unroll
    for (int mi = 0; mi < 4; ++mi)
#pragma unroll
        for (int ni = 0; ni < 4; ++ni)
#pragma unroll
            for (int r = 0; r < 4; ++r) {
                int mrel = wr * 64 + mi * 16 + lg * 4 + r;
                int nrel = wc * 64 + ni * 16 + ln;
                float v = acc[mi][ni][r] + bias[col0 + nrel];
                Cs[isV ? (nrel * 128 + mrel) : (mrel * 128 + nrel)] = f2b(v);
            }
    __syncthreads();

    if (!isV) {
        ushort_t* out = (blockIdx.z == 0) ? qb : kb;
#pragma unroll
        for (int i = 0; i < 8; ++i) {
            int f = i * 256 + tid;
            int rrow = f >> 4, c8 = f & 15;
            int m = row0 + rrow;
            int b = m >> 11, s = m & (SEQ - 1);
            int n = col0 + c8 * 8;
            int h = n >> 6, d = n & 63;
            short8 val;
            if (d < 16) {
                // fused partial RoPE: chunk pair lives at head-chunk 0/1
                const ushort_t* base = &Cs[rrow * 128 + (c8 & 8) * 8];
                const bool hi = (d >= 8);
#pragma unroll
                for (int j = 0; j < 8; ++j) {
                    float t1 = b2f(base[j]);
                    float t2 = b2f(base[8 + j]);
                    float invf = __expf(-(float)j * 1.1512925465f); // ln(1e4)/8
                    float ang = (float)s * invf;
                    float c_, si_;
                    __sincosf(ang, &si_, &c_);
                    val[j] = (short)f2b(hi ? (t1 * si_ + t2 * c_)
                                           : (t1 * c_ - t2 * si_));
                }
            } else {
                val = *(const short8*)&Cs[rrow * 128 + c8 * 8];
            }
            *(short8*)&out[((size_t)((b * NH + h) * SEQ) + s) * DH + d] = val;
        }
    } else {
#pragma unroll
        for (int i = 0; i < 8; ++i) {
            int f = i * 256 + tid;
            int nrow = f >> 4, c8 = f & 15;
            int n = col0 + nrow;
            int h = n >> 6, d = n & 63;
            int m = row0 + c8 * 8;
            int b = m >> 11, s = m & (SEQ - 1);
            *(short8*)&vtb[((size_t)((b * NH + h) * DH) + d) * SEQ + s] =
                *(const short8*)&Cs[nrow * 128 + c8 * 8];
        }
    }
}

// Output projection: A = ctxb bf16 [M][DM], B = Wot, out fp32 [M][DM] + bo.
__global__ __launch_bounds__(256) void mfma_gemm_out(
    const ushort_t* __restrict__ ctxb, const ushort_t* __restrict__ Wot,
    const float* __restrict__ bo, float* __restrict__ out) {
    const int row0 = blockIdx.y * BM;
    const int col0 = blockIdx.x * BN;
    __shared__ ushort_t smem[16384];
    f32x4 acc[4][4] = {};
    mfma_core(ctxb, Wot, row0, col0, smem, acc);

    const int tid = threadIdx.x;
    const int wave = tid >> 6, lane = tid & 63;
    const int lg = lane >> 4, ln = lane & 15;
    const int wr = wave >> 1, wc = wave & 1;
#pragma unroll
    for (int mi = 0; mi < 4; ++mi)
#pragma unroll
        for (int ni = 0; ni < 4; ++ni)
#pragma unroll
            for (int r = 0; r < 4; ++r) {
                int m = row0 + wr * 64 + mi * 16 + lg * 4 + r;
                int n = col0 + wc * 64 + ni * 16 + ln;
                out[(size_t)m * DM + n] = acc[mi][ni][r] + bo[n];
            }
}

// ---------------- Causal flash attention, bf16 MFMA, swapped QK^T -----------
// Grid: (32 bh, 32 qt-slots). One block per 64-row q-tile; all 1024 blocks
// co-resident. qt-slot y permuted {y0, 15-y0, 16+y0, 31-y0} for balance.
#define AQT 64
#define AKT 64
#define NQT (SEQ / AQT)   // 32

__global__ __launch_bounds__(256) void attn_mfma(
    const ushort_t* __restrict__ qb, const ushort_t* __restrict__ kb,
    const ushort_t* __restrict__ vtb, ushort_t* __restrict__ ctxb) {
    constexpr float C1 = 0.18033688f;        // SCALE * log2(e)
    constexpr float THR2 = 11.5415603f;      // 8 * log2(e)
    const int bh = blockIdx.x;
    const int y = blockIdx.y;
    const int y0 = y & 7, g = y >> 3;
    const int qt = (g == 0) ? y0 : (g == 1) ? (15 - y0)
                 : (g == 2) ? (16 + y0) : (31 - y0);
    const int q0 = qt * AQT;

    const int tid = threadIdx.x;
    const int wave = tid >> 6;
    const int lane = tid & 63;
    const int lg = lane >> 4;
    const int ln = lane & 15;

    __shared__ ushort_t KT[2][64 * 64];
    __shared__ ushort_t VT[2][64 * 64];
    __shared__ ushort_t PT[4][16 * 64];

    const ushort_t* kbase = kb + (size_t)bh * SEQ * DH;
    const ushort_t* vbase = vtb + (size_t)bh * DH * SEQ;
    const int b = bh >> 4, h = bh & 15;

    const ushort_t* qrow = qb + ((size_t)bh * SEQ + q0 + wave * 16 + ln) * DH;
    short8 qf0 = *(const short8*)&qrow[lg * 8];
    short8 qf1 = *(const short8*)&qrow[32 + lg * 8];

    f32x4 o[4];
#pragma unroll
    for (int nt = 0; nt < 4; nt++) o[nt] = f32x4{0.f, 0.f, 0.f, 0.f};
    float m2 = -1e30f, l = 0.f;          // per-lane stats for q-row = ln

    const int ntiles = qt + 1;

    // prologue: stage tile 0 into buffer 0
#pragma unroll
    for (int i = 0; i < 2; i++) {
        int f = i * 256 + tid;
        int r = f >> 3, p = f & 7, c = p ^ (r & 7);
        gload16(&kbase[(size_t)r * DH + c * 8], &KT[0][f * 8]);
        gload16(&vbase[(size_t)r * SEQ + c * 8], &VT[0][f * 8]);
    }

    int cur = 0;
    for (int t = 0; t < ntiles; ++t) {
        __syncthreads();   // staged data for tile t visible

        // prefetch tile t+1 into the other buffer
        if (t + 1 < ntiles) {
            const int nb0 = (t + 1) * AKT;
            const int nxt = cur ^ 1;
#pragma unroll
            for (int i = 0; i < 2; i++) {
                int f = i * 256 + tid;
                int r = f >> 3, p = f & 7, c = p ^ (r & 7);
                gload16(&kbase[(size_t)(nb0 + r) * DH + c * 8], &KT[nxt][f * 8]);
                gload16(&vbase[(size_t)r * SEQ + nb0 + c * 8], &VT[nxt][f * 8]);
            }
        }

        // ---- swapped QK^T: S^T tile, lane holds q=ln, keys kt*16+lg*4+r
        float st[4][4];
        __builtin_amdgcn_s_setprio(1);
#pragma unroll
        for (int kt = 0; kt < 4; kt++) {
            f32x4 acc = f32x4{0.f, 0.f, 0.f, 0.f};
            int krow = kt * 16 + ln;
            short8 b0 = *(const short8*)&KT[cur][krow * 64 + ((lg ^ (krow & 7)) * 8)];
            short8 b1 = *(const short8*)&KT[cur][krow * 64 + (((4 + lg) ^ (krow & 7)) * 8)];
            acc = __builtin_amdgcn_mfma_f32_16x16x32_bf16(b0, qf0, acc, 0, 0, 0);
            acc = __builtin_amdgcn_mfma_f32_16x16x32_bf16(b1, qf1, acc, 0, 0, 0);
#pragma unroll
            for (int r = 0; r < 4; r++) st[kt][r] = acc[r];
        }
        __builtin_amdgcn_s_setprio(0);

        // causal mask only on the diagonal (last) tile: key > q
        if (t == ntiles - 1) {
            const int qrel = wave * 16 + ln;
#pragma unroll
            for (int kt = 0; kt < 4; kt++)
#pragma unroll
                for (int r = 0; r < 4; r++)
                    if (kt * 16 + lg * 4 + r > qrel) st[kt][r] = -1e30f;
        }

        // ---- online softmax (exp2 domain), defer-max THR=8
        float smax = st[0][0];
#pragma unroll
        for (int kt = 0; kt < 4; kt++)
#pragma unroll
            for (int r = 0; r < 4; r++) smax = fmaxf(smax, st[kt][r]);
        smax = fmaxf(smax, __shfl_xor(smax, 16));
        smax = fmaxf(smax, __shfl_xor(smax, 32));
        const float m2c = C1 * smax;

        if (!__all(m2c <= m2 + THR2)) {
            float m2n = fmaxf(m2, m2c);
            float corr = exp2f(m2 - m2n);
            m2 = m2n;
            l *= corr;
#pragma unroll
            for (int r = 0; r < 4; r++) {
                float c_o = __shfl(corr, (lane & 48) | (lg * 4 + r));
#pragma unroll
                for (int nt = 0; nt < 4; nt++) o[nt][r] *= c_o;
            }
        }

        float lsum = 0.f;
#pragma unroll
        for (int kt = 0; kt < 4; kt++) {
            float pv[4];
#pragma unroll
            for (int r = 0; r < 4; r++) {
                pv[r] = exp2f(fmaf(C1, st[kt][r], -m2));
                lsum += pv[r];
            }
            uint2 pk;
            pk.x = cvtpk_bf16(pv[0], pv[1]);
            pk.y = cvtpk_bf16(pv[2], pv[3]);
            // PT[q=ln][k=kt*16+lg*4 ..+3], 16B-chunk XOR swizzle
            int addr = ln * 64 + (((kt * 2 + (lg >> 1)) ^ (ln & 7)) * 8) + (lg & 1) * 4;
            *(uint2*)&PT[wave][addr] = pk;
        }
        lsum += __shfl_xor(lsum, 16);
        lsum += __shfl_xor(lsum, 32);
        l += lsum;

        // ---- PV (A=P[q][k], B=V^T[d][k])
        short8 pa0 = *(const short8*)&PT[wave][ln * 64 + ((lg ^ (ln & 7)) * 8)];
        short8 pa1 = *(const short8*)&PT[wave][ln * 64 + (((4 + lg) ^ (ln & 7)) * 8)];
        __builtin_amdgcn_s_setprio(1);
#pragma unroll
        for (int nt = 0; nt < 4; nt++) {
            int vrow = nt * 16 + ln;
            short8 vb0 = *(const short8*)&VT[cur][vrow * 64 + ((lg ^ (vrow & 7)) * 8)];
            short8 vb1 = *(const short8*)&VT[cur][vrow * 64 + (((4 + lg) ^ (vrow & 7)) * 8)];
            o[nt] = __builtin_amdgcn_mfma_f32_16x16x32_bf16(pa0, vb0, o[nt], 0, 0, 0);
            o[nt] = __builtin_amdgcn_mfma_f32_16x16x32_bf16(pa1, vb1, o[nt], 0, 0, 0);
        }
        __builtin_amdgcn_s_setprio(0);

        cur ^= 1;
    }

    // ---- epilogue: gather 1/l for q=lg*4+r, bf16 ctx write
    const float rcp = 1.f / l;
#pragma unroll
    for (int r = 0; r < 4; r++) {
        float invl = __shfl(rcp, (lane & 48) | (lg * 4 + r));
        int qg = q0 + wave * 16 + lg * 4 + r;
        ushort_t* op = ctxb + ((size_t)(b * SEQ + qg)) * DM + h * DH;
#pragma unroll
        for (int nt = 0; nt < 4; nt++)
            op[nt * 16 + ln] = f2b(o[nt][r] * invl);
    }
}

// ---------------- launch ------------------------------------------------------
extern "C" void kernel_launch(void* const* d_in, const int* in_sizes, int n_in,
                              void* d_out, int out_size, void* d_ws, size_t ws_size,
                              hipStream_t stream) {
    const float* x  = (const float*)d_in[0];
    const float* Wq = (const float*)d_in[1];
    const float* bq = (const float*)d_in[2];
    const float* Wk = (const float*)d_in[3];
    const float* bk = (const float*)d_in[4];
    const float* Wv = (const float*)d_in[5];
    const float* bv = (const float*)d_in[6];
    const float* Wo = (const float*)d_in[7];
    const float* bo = (const float*)d_in[8];
    float* out = (float*)d_out;

    constexpr size_t TSZ = (size_t)MROWS * DM;   // 4194304
    constexpr size_t WSZ = (size_t)DM * DM;      // 1048576
    ushort_t* xb  = (ushort_t*)d_ws;
    ushort_t* Wqt = xb + TSZ;
    ushort_t* Wkt = Wqt + WSZ;
    ushort_t* Wvt = Wkt + WSZ;
    ushort_t* Wot = Wvt + WSZ;
    ushort_t* qbp = Wot + WSZ;
    ushort_t* kbp = qbp + TSZ;
    ushort_t* vtp = kbp + TSZ;
    ushort_t* ctxb = vtp + TSZ;

    conv_x<<<TSZ / 8 / 256, 256, 0, stream>>>(x, xb);
    conv_w<<<dim3(16, 16, 4), 256, 0, stream>>>(Wq, Wk, Wv, Wo, Wqt, Wkt, Wvt, Wot);

    // QKV projections (+bias, fused partial RoPE, bf16 head layout, V^T)
    mfma_gemm_qkv<<<dim3(DM / BN, MROWS / BM, 3), 256, 0, stream>>>(
        xb, Wqt, Wkt, Wvt, bq, bk, bv, qbp, kbp, vtp);

    // causal MFMA attention -> ctx bf16 [B,S,DM]
    attn_mfma<<<dim3(BATCH * NH, NQT), 256, 0, stream>>>(qbp, kbp, vtp, ctxb);

    // output projection (MFMA, fp32 out)
    mfma_gemm_out<<<dim3(DM / BN, MROWS / BM), 256, 0, stream>>>(ctxb, Wot, bo, out);
}

// Round 8
// 120.779 us; speedup vs baseline: 16.7187x; 1.0261x over previous
//
#include <hip/hip_runtime.h>
#include <hip/hip_bf16.h>
#include <math.h>

// Problem constants
constexpr int DM = 1024;
constexpr int SEQ = 2048;
constexpr int BATCH = 2;
constexpr int NH = 16;
constexpr int DH = 64;
constexpr int MROWS = BATCH * SEQ;  // 4096
constexpr float SCALE = 0.125f;

typedef __attribute__((ext_vector_type(8))) short short8;
typedef __attribute__((ext_vector_type(4))) float f32x4;
typedef unsigned short ushort_t;

__device__ __forceinline__ unsigned short f2b(float f) {
    __hip_bfloat16 h = __float2bfloat16(f);
    return __builtin_bit_cast(unsigned short, h);
}
__device__ __forceinline__ float b2f(unsigned short u) {
    unsigned int t = ((unsigned int)u) << 16;
    return __builtin_bit_cast(float, t);
}
// v_cvt_pk_bf16_f32: D = {bf16(hi) : bf16(lo)} (no builtin on gfx950 -> asm)
__device__ __forceinline__ unsigned int cvtpk_bf16(float lo, float hi) {
    unsigned int r;
    asm("v_cvt_pk_bf16_f32 %0, %1, %2" : "=v"(r) : "v"(lo), "v"(hi));
    return r;
}
// v_mfma_f32_16x16x16_bf16: A,B = 4 bf16 (2 VGPRs); C/D = 4 f32.
// A: row=lane&15, k=(lane>>4)*4+b ; B: col=lane&15, k=(lane>>4)*4+b.
__device__ __forceinline__ f32x4 mfma16_bf16(uint2 a, uint2 b, f32x4 c) {
    asm volatile("v_mfma_f32_16x16x16_bf16 %0, %1, %2, %0"
                 : "+v"(c) : "v"(a), "v"(b));
    return c;
}

__device__ __forceinline__ void gload16(const ushort_t* g, ushort_t* l) {
    __builtin_amdgcn_global_load_lds(
        (const __attribute__((address_space(1))) void*)g,
        (__attribute__((address_space(3))) void*)l, 16, 0, 0);
}

// ---------------- converters --------------------------------------------------
__global__ __launch_bounds__(256) void conv_x(const float* __restrict__ x,
                                              ushort_t* __restrict__ xb) {
    const size_t idx = (size_t)blockIdx.x * 256 + threadIdx.x;
    const float4* src = (const float4*)(x + idx * 8);
    float4 a = src[0], b = src[1];
    short8 v;
    v[0] = (short)f2b(a.x); v[1] = (short)f2b(a.y);
    v[2] = (short)f2b(a.z); v[3] = (short)f2b(a.w);
    v[4] = (short)f2b(b.x); v[5] = (short)f2b(b.y);
    v[6] = (short)f2b(b.z); v[7] = (short)f2b(b.w);
    *(short8*)(xb + idx * 8) = v;
}

// Transpose + convert weights: W [K][N] fp32 -> Wt [N][K] bf16
__global__ __launch_bounds__(256) void conv_w(
    const float* __restrict__ Wq, const float* __restrict__ Wk,
    const float* __restrict__ Wv, const float* __restrict__ Wo,
    ushort_t* __restrict__ Wqt, ushort_t* __restrict__ Wkt,
    ushort_t* __restrict__ Wvt, ushort_t* __restrict__ Wot) {
    const float* W; ushort_t* Wt;
    switch (blockIdx.z) {
        case 0:  W = Wq; Wt = Wqt; break;
        case 1:  W = Wk; Wt = Wkt; break;
        case 2:  W = Wv; Wt = Wvt; break;
        default: W = Wo; Wt = Wot; break;
    }
    __shared__ float L[64][65];
    const int n0 = blockIdx.x * 64, k0 = blockIdx.y * 64;
    const int t = threadIdx.x;
    const int tr = t >> 4, tc4 = (t & 15) * 4;
#pragma unroll
    for (int i = 0; i < 4; ++i) {
        int kk = tr + i * 16;
        float4 v = *(const float4*)&W[(size_t)(k0 + kk) * DM + n0 + tc4];
        L[kk][tc4 + 0] = v.x; L[kk][tc4 + 1] = v.y;
        L[kk][tc4 + 2] = v.z; L[kk][tc4 + 3] = v.w;
    }
    __syncthreads();
#pragma unroll
    for (int i = 0; i < 4; ++i) {
        int nn = tr + i * 16;
        ushort4 u;
        u.x = f2b(L[tc4 + 0][nn]); u.y = f2b(L[tc4 + 1][nn]);
        u.z = f2b(L[tc4 + 2][nn]); u.w = f2b(L[tc4 + 3][nn]);
        *(ushort4*)&Wt[(size_t)(n0 + nn) * DM + k0 + tc4] = u;
    }
}

// ---------------- MFMA GEMM core: 128x128 tile, BK=32, double-buffered -------
#define BM 128
#define BN 128
#define BKK 32
#define NKT (DM / BKK)   // 32

__device__ __forceinline__ void stage_tile(const ushort_t* __restrict__ A,
                                           const ushort_t* __restrict__ B,
                                           int row0, int col0, int kt,
                                           ushort_t* As, ushort_t* Bs, int tid) {
#pragma unroll
    for (int i = 0; i < 2; ++i) {
        int f = i * 256 + tid;                    // [0,512)
        int r = f >> 2, c = (f & 3) ^ (r & 3);    // inverse-swizzled source
        gload16(&A[(size_t)(row0 + r) * DM + kt * BKK + c * 8], &As[f * 8]);
        gload16(&B[(size_t)(col0 + r) * DM + kt * BKK + c * 8], &Bs[f * 8]);
    }
}

__device__ __forceinline__ void mfma_core(const ushort_t* __restrict__ A,
                                          const ushort_t* __restrict__ B,
                                          int row0, int col0,
                                          ushort_t* smem, f32x4 (&acc)[4][4]) {
    const int tid = threadIdx.x;
    const int wave = tid >> 6, lane = tid & 63;
    const int lg = lane >> 4, ln = lane & 15;
    const int wr = wave >> 1, wc = wave & 1;

    stage_tile(A, B, row0, col0, 0, smem, smem + 4096, tid);
    __syncthreads();

    int cur = 0;
    for (int kt = 0; kt < NKT; ++kt) {
        ushort_t* As = smem + cur * 8192;
        ushort_t* Bs = As + 4096;
        if (kt + 1 < NKT) {
            ushort_t* An = smem + (cur ^ 1) * 8192;
            stage_tile(A, B, row0, col0, kt + 1, An, An + 4096, tid);
        }

        short8 af[4], bf[4];
#pragma unroll
        for (int mi = 0; mi < 4; ++mi) {
            int r = wr * 64 + mi * 16 + ln;
            af[mi] = *(const short8*)&As[r * 32 + ((lg ^ (r & 3)) * 8)];
        }
#pragma unroll
        for (int ni = 0; ni < 4; ++ni) {
            int r = wc * 64 + ni * 16 + ln;
            bf[ni] = *(const short8*)&Bs[r * 32 + ((lg ^ (r & 3)) * 8)];
        }
        __builtin_amdgcn_s_setprio(1);
#pragma unroll
        for (int mi = 0; mi < 4; ++mi)
#pragma unroll
            for (int ni = 0; ni < 4; ++ni)
                acc[mi][ni] = __builtin_amdgcn_mfma_f32_16x16x32_bf16(
                    af[mi], bf[ni], acc[mi][ni], 0, 0, 0);
        __builtin_amdgcn_s_setprio(0);

        __syncthreads();
        cur ^= 1;
    }
}

// QKV: z=0 -> qb [B,H,S,DH]; z=1 -> kb; z=2 -> vtb [B,H,DH,S]; all bf16 +bias.
// Partial RoPE (rot dim 16) fused into the q/k scatter.
__global__ __launch_bounds__(256) void mfma_gemm_qkv(
    const ushort_t* __restrict__ xb,
    const ushort_t* __restrict__ Wqt, const ushort_t* __restrict__ Wkt,
    const ushort_t* __restrict__ Wvt,
    const float* __restrict__ bq, const float* __restrict__ bk,
    const float* __restrict__ bv,
    ushort_t* __restrict__ qb, ushort_t* __restrict__ kb,
    ushort_t* __restrict__ vtb) {
    const ushort_t* W; const float* bias;
    if (blockIdx.z == 0)      { W = Wqt; bias = bq; }
    else if (blockIdx.z == 1) { W = Wkt; bias = bk; }
    else                      { W = Wvt; bias = bv; }

    const int row0 = blockIdx.y * BM;
    const int col0 = blockIdx.x * BN;
    __shared__ ushort_t smem[16384];
    f32x4 acc[4][4] = {};
    mfma_core(xb, W, row0, col0, smem, acc);

    const int tid = threadIdx.x;
    const int wave = tid >> 6, lane = tid & 63;
    const int lg = lane >> 4, ln = lane & 15;
    const int wr = wave >> 1, wc = wave & 1;
    const bool isV = (blockIdx.z == 2);

    __syncthreads();
    ushort_t* Cs = smem;
#pragma unroll
    for (int mi = 0; mi < 4; ++mi)
#pragma unroll
        for (int ni = 0; ni < 4; ++ni)
#pragma unroll
            for (int r = 0; r < 4; ++r) {
                int mrel = wr * 64 + mi * 16 + lg * 4 + r;
                int nrel = wc * 64 + ni * 16 + ln;
                float v = acc[mi][ni][r] + bias[col0 + nrel];
                Cs[isV ? (nrel * 128 + mrel) : (mrel * 128 + nrel)] = f2b(v);
            }
    __syncthreads();

    if (!isV) {
        ushort_t* out = (blockIdx.z == 0) ? qb : kb;
#pragma unroll
        for (int i = 0; i < 8; ++i) {
            int f = i * 256 + tid;
            int rrow = f >> 4, c8 = f & 15;
            int m = row0 + rrow;
            int b = m >> 11, s = m & (SEQ - 1);
            int n = col0 + c8 * 8;
            int h = n >> 6, d = n & 63;
            short8 val;
            if (d < 16) {
                const ushort_t* base = &Cs[rrow * 128 + (c8 & 8) * 8];
                const bool hi = (d >= 8);
#pragma unroll
                for (int j = 0; j < 8; ++j) {
                    float t1 = b2f(base[j]);
                    float t2 = b2f(base[8 + j]);
                    float invf = __expf(-(float)j * 1.1512925465f); // ln(1e4)/8
                    float ang = (float)s * invf;
                    float c_, si_;
                    __sincosf(ang, &si_, &c_);
                    val[j] = (short)f2b(hi ? (t1 * si_ + t2 * c_)
                                           : (t1 * c_ - t2 * si_));
                }
            } else {
                val = *(const short8*)&Cs[rrow * 128 + c8 * 8];
            }
            *(short8*)&out[((size_t)((b * NH + h) * SEQ) + s) * DH + d] = val;
        }
    } else {
#pragma unroll
        for (int i = 0; i < 8; ++i) {
            int f = i * 256 + tid;
            int nrow = f >> 4, c8 = f & 15;
            int n = col0 + nrow;
            int h = n >> 6, d = n & 63;
            int m = row0 + c8 * 8;
            int b = m >> 11, s = m & (SEQ - 1);
            *(short8*)&vtb[((size_t)((b * NH + h) * DH) + d) * SEQ + s] =
                *(const short8*)&Cs[nrow * 128 + c8 * 8];
        }
    }
}

// Output projection: A = ctxb bf16 [M][DM], B = Wot, out fp32 [M][DM] + bo.
__global__ __launch_bounds__(256) void mfma_gemm_out(
    const ushort_t* __restrict__ ctxb, const ushort_t* __restrict__ Wot,
    const float* __restrict__ bo, float* __restrict__ out) {
    const int row0 = blockIdx.y * BM;
    const int col0 = blockIdx.x * BN;
    __shared__ ushort_t smem[16384];
    f32x4 acc[4][4] = {};
    mfma_core(ctxb, Wot, row0, col0, smem, acc);

    const int tid = threadIdx.x;
    const int wave = tid >> 6, lane = tid & 63;
    const int lg = lane >> 4, ln = lane & 15;
    const int wr = wave >> 1, wc = wave & 1;
#pragma unroll
    for (int mi = 0; mi < 4; ++mi)
#pragma unroll
        for (int ni = 0; ni < 4; ++ni)
#pragma unroll
            for (int r = 0; r < 4; ++r) {
                int m = row0 + wr * 64 + mi * 16 + lg * 4 + r;
                int n = col0 + wc * 64 + ni * 16 + ln;
                out[(size_t)m * DM + n] = acc[mi][ni][r] + bo[n];
            }
}

// ---------------- Causal flash attention, bf16 MFMA, swapped QK^T -----------
// Fixed-max softmax (M2 = C1*8 = log2 e): no max tracking, no rescale, no
// cross-lane traffic in the loop. P stays in registers: the cvt_pk output
// IS the A-fragment of v_mfma_f32_16x16x16_bf16 (k=(lane>>4)*4+b), so PV
// runs 16 small MFMAs off registers + 8B VT reads — no P LDS buffer at all.
// LDS 32 KB -> 5 blocks/CU capacity.
#define AQT 64
#define AKT 64
#define NQT (SEQ / AQT)   // 32

__global__ __launch_bounds__(256) void attn_mfma(
    const ushort_t* __restrict__ qb, const ushort_t* __restrict__ kb,
    const ushort_t* __restrict__ vtb, ushort_t* __restrict__ ctxb) {
    constexpr float C1 = 0.18033688f;        // SCALE * log2(e)
    constexpr float M2 = 1.44269504f;        // C1 * 8 (score bound 8 sigma)
    const int bh = blockIdx.x;
    const int y = blockIdx.y;
    const int y0 = y & 7, g = y >> 3;
    const int qt = (g == 0) ? y0 : (g == 1) ? (15 - y0)
                 : (g == 2) ? (16 + y0) : (31 - y0);
    const int q0 = qt * AQT;

    const int tid = threadIdx.x;
    const int wave = tid >> 6;
    const int lane = tid & 63;
    const int lg = lane >> 4;
    const int ln = lane & 15;

    __shared__ ushort_t KT[2][64 * 64];
    __shared__ ushort_t VT[2][64 * 64];

    const ushort_t* kbase = kb + (size_t)bh * SEQ * DH;
    const ushort_t* vbase = vtb + (size_t)bh * DH * SEQ;
    const int b = bh >> 4, h = bh & 15;

    const ushort_t* qrow = qb + ((size_t)bh * SEQ + q0 + wave * 16 + ln) * DH;
    short8 qf0 = *(const short8*)&qrow[lg * 8];
    short8 qf1 = *(const short8*)&qrow[32 + lg * 8];

    f32x4 o[4];
#pragma unroll
    for (int nt = 0; nt < 4; nt++) o[nt] = f32x4{0.f, 0.f, 0.f, 0.f};
    float l = 0.f;                        // per-lane partial for q-row = ln

    const int ntiles = qt + 1;

    // prologue: stage tile 0 into buffer 0
#pragma unroll
    for (int i = 0; i < 2; i++) {
        int f = i * 256 + tid;
        int r = f >> 3, p = f & 7, c = p ^ (r & 7);
        gload16(&kbase[(size_t)r * DH + c * 8], &KT[0][f * 8]);
        gload16(&vbase[(size_t)r * SEQ + c * 8], &VT[0][f * 8]);
    }

    int cur = 0;
    for (int t = 0; t < ntiles; ++t) {
        __syncthreads();   // staged data for tile t visible

        if (t + 1 < ntiles) {
            const int nb0 = (t + 1) * AKT;
            const int nxt = cur ^ 1;
#pragma unroll
            for (int i = 0; i < 2; i++) {
                int f = i * 256 + tid;
                int r = f >> 3, p = f & 7, c = p ^ (r & 7);
                gload16(&kbase[(size_t)(nb0 + r) * DH + c * 8], &KT[nxt][f * 8]);
                gload16(&vbase[(size_t)r * SEQ + nb0 + c * 8], &VT[nxt][f * 8]);
            }
        }

        // ---- swapped QK^T: st[kt][r] = S[key=16kt+lg*4+r][q=ln]
        float st[4][4];
        __builtin_amdgcn_s_setprio(1);
#pragma unroll
        for (int kt = 0; kt < 4; kt++) {
            f32x4 acc = f32x4{0.f, 0.f, 0.f, 0.f};
            int krow = kt * 16 + ln;
            short8 b0 = *(const short8*)&KT[cur][krow * 64 + ((lg ^ (krow & 7)) * 8)];
            short8 b1 = *(const short8*)&KT[cur][krow * 64 + (((4 + lg) ^ (krow & 7)) * 8)];
            acc = __builtin_amdgcn_mfma_f32_16x16x32_bf16(b0, qf0, acc, 0, 0, 0);
            acc = __builtin_amdgcn_mfma_f32_16x16x32_bf16(b1, qf1, acc, 0, 0, 0);
#pragma unroll
            for (int r = 0; r < 4; r++) st[kt][r] = acc[r];
        }
        __builtin_amdgcn_s_setprio(0);

        // causal mask only on the diagonal (last) tile: key > q
        if (t == ntiles - 1) {
            const int qrel = wave * 16 + ln;
#pragma unroll
            for (int kt = 0; kt < 4; kt++)
#pragma unroll
                for (int r = 0; r < 4; r++)
                    if (kt * 16 + lg * 4 + r > qrel) st[kt][r] = -1e30f;
        }

        // ---- fixed-max softmax: p = exp2(C1*s - M2); P packed in registers
        uint2 pkq[4];
#pragma unroll
        for (int kt = 0; kt < 4; kt++) {
            float pv[4];
#pragma unroll
            for (int r = 0; r < 4; r++) {
                pv[r] = exp2f(fmaf(C1, st[kt][r], -M2));
                l += pv[r];
            }
            pkq[kt].x = cvtpk_bf16(pv[0], pv[1]);
            pkq[kt].y = cvtpk_bf16(pv[2], pv[3]);
        }

        // ---- PV: o[nt] += P(16x16 A-frag, reg) x V^T(8B LDS reads)
        __builtin_amdgcn_s_setprio(1);
#pragma unroll
        for (int nt = 0; nt < 4; nt++) {
            int vrow = nt * 16 + ln;
#pragma unroll
            for (int kt = 0; kt < 4; kt++) {
                int chunk = (2 * kt + (lg >> 1)) ^ (vrow & 7);
                uint2 vb = *(const uint2*)&VT[cur][vrow * 64 + chunk * 8 + (lg & 1) * 4];
                o[nt] = mfma16_bf16(pkq[kt], vb, o[nt]);
            }
        }
        __builtin_amdgcn_s_setprio(0);

        cur ^= 1;
    }

    // ---- epilogue: deferred cross-lane l reduction, then bf16 ctx write
    l += __shfl_xor(l, 16);
    l += __shfl_xor(l, 32);
    const float rcp = 1.f / l;
#pragma unroll
    for (int r = 0; r < 4; r++) {
        float invl = __shfl(rcp, (lane & 48) | (lg * 4 + r));
        int qg = q0 + wave * 16 + lg * 4 + r;
        ushort_t* op = ctxb + ((size_t)(b * SEQ + qg)) * DM + h * DH;
#pragma unroll
        for (int nt = 0; nt < 4; nt++)
            op[nt * 16 + ln] = f2b(o[nt][r] * invl);
    }
}

// ---------------- launch ------------------------------------------------------
extern "C" void kernel_launch(void* const* d_in, const int* in_sizes, int n_in,
                              void* d_out, int out_size, void* d_ws, size_t ws_size,
                              hipStream_t stream) {
    const float* x  = (const float*)d_in[0];
    const float* Wq = (const float*)d_in[1];
    const float* bq = (const float*)d_in[2];
    const float* Wk = (const float*)d_in[3];
    const float* bk = (const float*)d_in[4];
    const float* Wv = (const float*)d_in[5];
    const float* bv = (const float*)d_in[6];
    const float* Wo = (const float*)d_in[7];
    const float* bo = (const float*)d_in[8];
    float* out = (float*)d_out;

    constexpr size_t TSZ = (size_t)MROWS * DM;   // 4194304
    constexpr size_t WSZ = (size_t)DM * DM;      // 1048576
    ushort_t* xb  = (ushort_t*)d_ws;
    ushort_t* Wqt = xb + TSZ;
    ushort_t* Wkt = Wqt + WSZ;
    ushort_t* Wvt = Wkt + WSZ;
    ushort_t* Wot = Wvt + WSZ;
    ushort_t* qbp = Wot + WSZ;
    ushort_t* kbp = qbp + TSZ;
    ushort_t* vtp = kbp + TSZ;
    ushort_t* ctxb = vtp + TSZ;

    conv_x<<<TSZ / 8 / 256, 256, 0, stream>>>(x, xb);
    conv_w<<<dim3(16, 16, 4), 256, 0, stream>>>(Wq, Wk, Wv, Wo, Wqt, Wkt, Wvt, Wot);

    mfma_gemm_qkv<<<dim3(DM / BN, MROWS / BM, 3), 256, 0, stream>>>(
        xb, Wqt, Wkt, Wvt, bq, bk, bv, qbp, kbp, vtp);

    attn_mfma<<<dim3(BATCH * NH, NQT), 256, 0, stream>>>(qbp, kbp, vtp, ctxb);

    mfma_gemm_out<<<dim3(DM / BN, MROWS / BM), 256, 0, stream>>>(ctxb, Wot, bo, out);
}

// Round 9
// 117.485 us; speedup vs baseline: 17.1874x; 1.0280x over previous
//
#include <hip/hip_runtime.h>
#include <hip/hip_bf16.h>
#include <math.h>

// Problem constants
constexpr int DM = 1024;
constexpr int SEQ = 2048;
constexpr int BATCH = 2;
constexpr int NH = 16;
constexpr int DH = 64;
constexpr int MROWS = BATCH * SEQ;  // 4096
constexpr float SCALE = 0.125f;

typedef __attribute__((ext_vector_type(8))) short short8;
typedef __attribute__((ext_vector_type(4))) float f32x4;
typedef unsigned short ushort_t;

__device__ __forceinline__ unsigned short f2b(float f) {
    __hip_bfloat16 h = __float2bfloat16(f);
    return __builtin_bit_cast(unsigned short, h);
}
__device__ __forceinline__ float b2f(unsigned short u) {
    unsigned int t = ((unsigned int)u) << 16;
    return __builtin_bit_cast(float, t);
}
// v_cvt_pk_bf16_f32: D = {bf16(hi) : bf16(lo)} (no builtin on gfx950 -> asm)
__device__ __forceinline__ unsigned int cvtpk_bf16(float lo, float hi) {
    unsigned int r;
    asm("v_cvt_pk_bf16_f32 %0, %1, %2" : "=v"(r) : "v"(lo), "v"(hi));
    return r;
}
// v_mfma_f32_16x16x16_bf16: A,B = 4 bf16 (2 VGPRs); C/D = 4 f32.
// Non-volatile: pure via constraints, lets the scheduler interleave.
__device__ __forceinline__ f32x4 mfma16_bf16(uint2 a, uint2 b, f32x4 c) {
    asm("v_mfma_f32_16x16x16_bf16 %0, %1, %2, %0"
        : "+v"(c) : "v"(a), "v"(b));
    return c;
}

__device__ __forceinline__ void gload16(const ushort_t* g, ushort_t* l) {
    __builtin_amdgcn_global_load_lds(
        (const __attribute__((address_space(1))) void*)g,
        (__attribute__((address_space(3))) void*)l, 16, 0, 0);
}

// ---------------- converters --------------------------------------------------
__global__ __launch_bounds__(256) void conv_x(const float* __restrict__ x,
                                              ushort_t* __restrict__ xb) {
    const size_t idx = (size_t)blockIdx.x * 256 + threadIdx.x;
    const float4* src = (const float4*)(x + idx * 8);
    float4 a = src[0], b = src[1];
    short8 v;
    v[0] = (short)f2b(a.x); v[1] = (short)f2b(a.y);
    v[2] = (short)f2b(a.z); v[3] = (short)f2b(a.w);
    v[4] = (short)f2b(b.x); v[5] = (short)f2b(b.y);
    v[6] = (short)f2b(b.z); v[7] = (short)f2b(b.w);
    *(short8*)(xb + idx * 8) = v;
}

// Transpose + convert weights: W [K][N] fp32 -> Wt [N][K] bf16
__global__ __launch_bounds__(256) void conv_w(
    const float* __restrict__ Wq, const float* __restrict__ Wk,
    const float* __restrict__ Wv, const float* __restrict__ Wo,
    ushort_t* __restrict__ Wqt, ushort_t* __restrict__ Wkt,
    ushort_t* __restrict__ Wvt, ushort_t* __restrict__ Wot) {
    const float* W; ushort_t* Wt;
    switch (blockIdx.z) {
        case 0:  W = Wq; Wt = Wqt; break;
        case 1:  W = Wk; Wt = Wkt; break;
        case 2:  W = Wv; Wt = Wvt; break;
        default: W = Wo; Wt = Wot; break;
    }
    __shared__ float L[64][65];
    const int n0 = blockIdx.x * 64, k0 = blockIdx.y * 64;
    const int t = threadIdx.x;
    const int tr = t >> 4, tc4 = (t & 15) * 4;
#pragma unroll
    for (int i = 0; i < 4; ++i) {
        int kk = tr + i * 16;
        float4 v = *(const float4*)&W[(size_t)(k0 + kk) * DM + n0 + tc4];
        L[kk][tc4 + 0] = v.x; L[kk][tc4 + 1] = v.y;
        L[kk][tc4 + 2] = v.z; L[kk][tc4 + 3] = v.w;
    }
    __syncthreads();
#pragma unroll
    for (int i = 0; i < 4; ++i) {
        int nn = tr + i * 16;
        ushort4 u;
        u.x = f2b(L[tc4 + 0][nn]); u.y = f2b(L[tc4 + 1][nn]);
        u.z = f2b(L[tc4 + 2][nn]); u.w = f2b(L[tc4 + 3][nn]);
        *(ushort4*)&Wt[(size_t)(n0 + nn) * DM + k0 + tc4] = u;
    }
}

// ---------------- MFMA GEMM core: 128x128 tile, BK=32, double-buffered -------
#define BM 128
#define BN 128
#define BKK 32
#define NKT (DM / BKK)   // 32

__device__ __forceinline__ void stage_tile(const ushort_t* __restrict__ A,
                                           const ushort_t* __restrict__ B,
                                           int row0, int col0, int kt,
                                           ushort_t* As, ushort_t* Bs, int tid) {
#pragma unroll
    for (int i = 0; i < 2; ++i) {
        int f = i * 256 + tid;                    // [0,512)
        int r = f >> 2, c = (f & 3) ^ (r & 3);    // inverse-swizzled source
        gload16(&A[(size_t)(row0 + r) * DM + kt * BKK + c * 8], &As[f * 8]);
        gload16(&B[(size_t)(col0 + r) * DM + kt * BKK + c * 8], &Bs[f * 8]);
    }
}

__device__ __forceinline__ void mfma_core(const ushort_t* __restrict__ A,
                                          const ushort_t* __restrict__ B,
                                          int row0, int col0,
                                          ushort_t* smem, f32x4 (&acc)[4][4]) {
    const int tid = threadIdx.x;
    const int wave = tid >> 6, lane = tid & 63;
    const int lg = lane >> 4, ln = lane & 15;
    const int wr = wave >> 1, wc = wave & 1;

    stage_tile(A, B, row0, col0, 0, smem, smem + 4096, tid);
    __syncthreads();

    int cur = 0;
    for (int kt = 0; kt < NKT; ++kt) {
        ushort_t* As = smem + cur * 8192;
        ushort_t* Bs = As + 4096;
        if (kt + 1 < NKT) {
            ushort_t* An = smem + (cur ^ 1) * 8192;
            stage_tile(A, B, row0, col0, kt + 1, An, An + 4096, tid);
        }

        short8 af[4], bf[4];
#pragma unroll
        for (int mi = 0; mi < 4; ++mi) {
            int r = wr * 64 + mi * 16 + ln;
            af[mi] = *(const short8*)&As[r * 32 + ((lg ^ (r & 3)) * 8)];
        }
#pragma unroll
        for (int ni = 0; ni < 4; ++ni) {
            int r = wc * 64 + ni * 16 + ln;
            bf[ni] = *(const short8*)&Bs[r * 32 + ((lg ^ (r & 3)) * 8)];
        }
        __builtin_amdgcn_s_setprio(1);
#pragma unroll
        for (int mi = 0; mi < 4; ++mi)
#pragma unroll
            for (int ni = 0; ni < 4; ++ni)
                acc[mi][ni] = __builtin_amdgcn_mfma_f32_16x16x32_bf16(
                    af[mi], bf[ni], acc[mi][ni], 0, 0, 0);
        __builtin_amdgcn_s_setprio(0);

        __syncthreads();
        cur ^= 1;
    }
}

// QKV: z=0 -> qb [B,H,S,DH]; z=1 -> kb; z=2 -> vtb [B,H,DH,S]; all bf16 +bias.
// Partial RoPE (rot dim 16) fused into the q/k scatter.
__global__ __launch_bounds__(256) void mfma_gemm_qkv(
    const ushort_t* __restrict__ xb,
    const ushort_t* __restrict__ Wqt, const ushort_t* __restrict__ Wkt,
    const ushort_t* __restrict__ Wvt,
    const float* __restrict__ bq, const float* __restrict__ bk,
    const float* __restrict__ bv,
    ushort_t* __restrict__ qb, ushort_t* __restrict__ kb,
    ushort_t* __restrict__ vtb) {
    const ushort_t* W; const float* bias;
    if (blockIdx.z == 0)      { W = Wqt; bias = bq; }
    else if (blockIdx.z == 1) { W = Wkt; bias = bk; }
    else                      { W = Wvt; bias = bv; }

    const int row0 = blockIdx.y * BM;
    const int col0 = blockIdx.x * BN;
    __shared__ ushort_t smem[16384];
    f32x4 acc[4][4] = {};
    mfma_core(xb, W, row0, col0, smem, acc);

    const int tid = threadIdx.x;
    const int wave = tid >> 6, lane = tid & 63;
    const int lg = lane >> 4, ln = lane & 15;
    const int wr = wave >> 1, wc = wave & 1;
    const bool isV = (blockIdx.z == 2);

    __syncthreads();
    ushort_t* Cs = smem;
#pragma unroll
    for (int mi = 0; mi < 4; ++mi)
#pragma unroll
        for (int ni = 0; ni < 4; ++ni)
#pragma unroll
            for (int r = 0; r < 4; ++r) {
                int mrel = wr * 64 + mi * 16 + lg * 4 + r;
                int nrel = wc * 64 + ni * 16 + ln;
                float v = acc[mi][ni][r] + bias[col0 + nrel];
                Cs[isV ? (nrel * 128 + mrel) : (mrel * 128 + nrel)] = f2b(v);
            }
    __syncthreads();

    if (!isV) {
        ushort_t* out = (blockIdx.z == 0) ? qb : kb;
#pragma unroll
        for (int i = 0; i < 8; ++i) {
            int f = i * 256 + tid;
            int rrow = f >> 4, c8 = f & 15;
            int m = row0 + rrow;
            int b = m >> 11, s = m & (SEQ - 1);
            int n = col0 + c8 * 8;
            int h = n >> 6, d = n & 63;
            short8 val;
            if (d < 16) {
                const ushort_t* base = &Cs[rrow * 128 + (c8 & 8) * 8];
                const bool hi = (d >= 8);
#pragma unroll
                for (int j = 0; j < 8; ++j) {
                    float t1 = b2f(base[j]);
                    float t2 = b2f(base[8 + j]);
                    float invf = __expf(-(float)j * 1.1512925465f); // ln(1e4)/8
                    float ang = (float)s * invf;
                    float c_, si_;
                    __sincosf(ang, &si_, &c_);
                    val[j] = (short)f2b(hi ? (t1 * si_ + t2 * c_)
                                           : (t1 * c_ - t2 * si_));
                }
            } else {
                val = *(const short8*)&Cs[rrow * 128 + c8 * 8];
            }
            *(short8*)&out[((size_t)((b * NH + h) * SEQ) + s) * DH + d] = val;
        }
    } else {
#pragma unroll
        for (int i = 0; i < 8; ++i) {
            int f = i * 256 + tid;
            int nrow = f >> 4, c8 = f & 15;
            int n = col0 + nrow;
            int h = n >> 6, d = n & 63;
            int m = row0 + c8 * 8;
            int b = m >> 11, s = m & (SEQ - 1);
            *(short8*)&vtb[((size_t)((b * NH + h) * DH) + d) * SEQ + s] =
                *(const short8*)&Cs[nrow * 128 + c8 * 8];
        }
    }
}

// Output projection: A = ctxb bf16 [M][DM], B = Wot, out fp32 [M][DM] + bo.
__global__ __launch_bounds__(256) void mfma_gemm_out(
    const ushort_t* __restrict__ ctxb, const ushort_t* __restrict__ Wot,
    const float* __restrict__ bo, float* __restrict__ out) {
    const int row0 = blockIdx.y * BM;
    const int col0 = blockIdx.x * BN;
    __shared__ ushort_t smem[16384];
    f32x4 acc[4][4] = {};
    mfma_core(ctxb, Wot, row0, col0, smem, acc);

    const int tid = threadIdx.x;
    const int wave = tid >> 6, lane = tid & 63;
    const int lg = lane >> 4, ln = lane & 15;
    const int wr = wave >> 1, wc = wave & 1;
#pragma unroll
    for (int mi = 0; mi < 4; ++mi)
#pragma unroll
        for (int ni = 0; ni < 4; ++ni)
#pragma unroll
            for (int r = 0; r < 4; ++r) {
                int m = row0 + wr * 64 + mi * 16 + lg * 4 + r;
                int n = col0 + wc * 64 + ni * 16 + ln;
                out[(size_t)m * DM + n] = acc[mi][ni][r] + bo[n];
            }
}

// ---------------- Causal flash attention, k-split partials -------------------
// Fixed-max softmax => partial (o, l) over disjoint key ranges are ADDITIVE.
// Block mapping (y = blockIdx.y, 48 slots per bh, longest-first):
//   y in [0,16):  qt = 16+y,  tiles [0,16)      -> partial chunk 0 (len 16)
//   y in [16,32): qt = 47-y,  tiles [16,qt+1)   -> partial chunk 1 (len 16..1)
//   y in [32,48): qt = 47-y,  tiles [0,qt+1)    -> direct ctx write (len 16..1)
// 1536 blocks x 4 waves = 6144 waves > 5120-wave LDS capacity -> real backfill.
#define AQT 64
#define AKT 64
#define NQT (SEQ / AQT)   // 32

__global__ __launch_bounds__(256) void attn_mfma(
    const ushort_t* __restrict__ qb, const ushort_t* __restrict__ kb,
    const ushort_t* __restrict__ vtb, ushort_t* __restrict__ ctxb,
    ushort_t* __restrict__ opart, float* __restrict__ lpart) {
    constexpr float C1 = 0.18033688f;        // SCALE * log2(e)
    constexpr float M2 = 1.44269504f;        // C1 * 8 (score bound 8 sigma)
    const int bh = blockIdx.x;
    const int y = blockIdx.y;

    int qt, t0, t1, chunk;
    if (y < 16)      { qt = 16 + y;  t0 = 0;  t1 = 16;     chunk = 0; }
    else if (y < 32) { qt = 47 - y;  t0 = 16; t1 = qt + 1; chunk = 1; }
    else             { qt = 47 - y;  t0 = 0;  t1 = qt + 1; chunk = -1; }
    const int q0 = qt * AQT;

    const int tid = threadIdx.x;
    const int wave = tid >> 6;
    const int lane = tid & 63;
    const int lg = lane >> 4;
    const int ln = lane & 15;

    __shared__ ushort_t KT[2][64 * 64];
    __shared__ ushort_t VT[2][64 * 64];

    const ushort_t* kbase = kb + (size_t)bh * SEQ * DH;
    const ushort_t* vbase = vtb + (size_t)bh * DH * SEQ;
    const int b = bh >> 4, h = bh & 15;

    const ushort_t* qrow = qb + ((size_t)bh * SEQ + q0 + wave * 16 + ln) * DH;
    short8 qf0 = *(const short8*)&qrow[lg * 8];
    short8 qf1 = *(const short8*)&qrow[32 + lg * 8];

    f32x4 o[4];
#pragma unroll
    for (int nt = 0; nt < 4; nt++) o[nt] = f32x4{0.f, 0.f, 0.f, 0.f};
    float l = 0.f;                        // per-lane partial for q-row = ln

    // prologue: stage tile t0 into buffer 0
#pragma unroll
    for (int i = 0; i < 2; i++) {
        int f = i * 256 + tid;
        int r = f >> 3, p = f & 7, c = p ^ (r & 7);
        gload16(&kbase[(size_t)(t0 * AKT + r) * DH + c * 8], &KT[0][f * 8]);
        gload16(&vbase[(size_t)r * SEQ + t0 * AKT + c * 8], &VT[0][f * 8]);
    }

    int cur = 0;
    for (int t = t0; t < t1; ++t) {
        __syncthreads();   // staged data for tile t visible

        if (t + 1 < t1) {
            const int nb0 = (t + 1) * AKT;
            const int nxt = cur ^ 1;
#pragma unroll
            for (int i = 0; i < 2; i++) {
                int f = i * 256 + tid;
                int r = f >> 3, p = f & 7, c = p ^ (r & 7);
                gload16(&kbase[(size_t)(nb0 + r) * DH + c * 8], &KT[nxt][f * 8]);
                gload16(&vbase[(size_t)r * SEQ + nb0 + c * 8], &VT[nxt][f * 8]);
            }
        }

        // ---- swapped QK^T: st[kt][r] = S[key=16kt+lg*4+r][q=ln]
        float st[4][4];
        __builtin_amdgcn_s_setprio(1);
#pragma unroll
        for (int kt = 0; kt < 4; kt++) {
            f32x4 acc = f32x4{0.f, 0.f, 0.f, 0.f};
            int krow = kt * 16 + ln;
            short8 b0 = *(const short8*)&KT[cur][krow * 64 + ((lg ^ (krow & 7)) * 8)];
            short8 b1 = *(const short8*)&KT[cur][krow * 64 + (((4 + lg) ^ (krow & 7)) * 8)];
            acc = __builtin_amdgcn_mfma_f32_16x16x32_bf16(b0, qf0, acc, 0, 0, 0);
            acc = __builtin_amdgcn_mfma_f32_16x16x32_bf16(b1, qf1, acc, 0, 0, 0);
#pragma unroll
            for (int r = 0; r < 4; r++) st[kt][r] = acc[r];
        }
        __builtin_amdgcn_s_setprio(0);

        // causal mask only on the diagonal tile (t == qt; never in chunk 0)
        if (t == qt) {
            const int qrel = wave * 16 + ln;
#pragma unroll
            for (int kt = 0; kt < 4; kt++)
#pragma unroll
                for (int r = 0; r < 4; r++)
                    if (kt * 16 + lg * 4 + r > qrel) st[kt][r] = -1e30f;
        }

        // ---- fixed-max softmax: p = exp2(C1*s - M2); P packed in registers
        uint2 pkq[4];
#pragma unroll
        for (int kt = 0; kt < 4; kt++) {
            float pv[4];
#pragma unroll
            for (int r = 0; r < 4; r++) {
                pv[r] = exp2f(fmaf(C1, st[kt][r], -M2));
                l += pv[r];
            }
            pkq[kt].x = cvtpk_bf16(pv[0], pv[1]);
            pkq[kt].y = cvtpk_bf16(pv[2], pv[3]);
        }

        // ---- PV: o[nt] += P(16x16 A-frag, reg) x V^T(8B LDS reads)
        __builtin_amdgcn_s_setprio(1);
#pragma unroll
        for (int nt = 0; nt < 4; nt++) {
            int vrow = nt * 16 + ln;
#pragma unroll
            for (int kt = 0; kt < 4; kt++) {
                int chunk16 = (2 * kt + (lg >> 1)) ^ (vrow & 7);
                uint2 vb = *(const uint2*)&VT[cur][vrow * 64 + chunk16 * 8 + (lg & 1) * 4];
                o[nt] = mfma16_bf16(pkq[kt], vb, o[nt]);
            }
        }
        __builtin_amdgcn_s_setprio(0);

        cur ^= 1;
    }

    // ---- epilogue
    l += __shfl_xor(l, 16);
    l += __shfl_xor(l, 32);

    if (chunk >= 0) {
        // partial: write bf16 o (undivided) + f32 l
        const int pid = ((bh << 4) + (qt - 16)) * 2 + chunk;
        if (lg == 0) lpart[pid * 64 + wave * 16 + ln] = l;
        ushort_t* ob = opart + (size_t)pid * 4096;
#pragma unroll
        for (int r = 0; r < 4; r++) {
            int qrel = wave * 16 + lg * 4 + r;
#pragma unroll
            for (int nt = 0; nt < 4; nt++)
                ob[qrel * 64 + nt * 16 + ln] = f2b(o[nt][r]);
        }
    } else {
        const float rcp = 1.f / l;
#pragma unroll
        for (int r = 0; r < 4; r++) {
            float invl = __shfl(rcp, (lane & 48) | (lg * 4 + r));
            int qg = q0 + wave * 16 + lg * 4 + r;
            ushort_t* op = ctxb + ((size_t)(b * SEQ + qg)) * DM + h * DH;
#pragma unroll
            for (int nt = 0; nt < 4; nt++)
                op[nt * 16 + ln] = f2b(o[nt][r] * invl);
        }
    }
}

// Combine the two partials for qt >= 16: ctx = (o0 + o1) / (l0 + l1).
__global__ __launch_bounds__(256) void attn_reduce(
    const ushort_t* __restrict__ opart, const float* __restrict__ lpart,
    ushort_t* __restrict__ ctxb) {
    const int bh = blockIdx.x;             // 0..31
    const int qt = 16 + blockIdx.y;        // 16..31
    const int tid = threadIdx.x;
    const int q = tid >> 2;                // 0..63
    const int d0 = (tid & 3) * 16;         // 0,16,32,48

    const int pid0 = ((bh << 4) + (qt - 16)) * 2;
    const ushort_t* o0 = opart + (size_t)pid0 * 4096 + q * 64 + d0;
    const ushort_t* o1 = opart + (size_t)(pid0 + 1) * 4096 + q * 64 + d0;
    const float inv = 1.f / (lpart[pid0 * 64 + q] + lpart[(pid0 + 1) * 64 + q]);

    const int b = bh >> 4, h = bh & 15;
    ushort_t* op = ctxb + ((size_t)(b * SEQ + qt * 64 + q)) * DM + h * DH + d0;
#pragma unroll
    for (int half = 0; half < 2; ++half) {
        short8 a = *(const short8*)&o0[half * 8];
        short8 c = *(const short8*)&o1[half * 8];
        short8 r;
#pragma unroll
        for (int j = 0; j < 8; ++j)
            r[j] = (short)f2b((b2f((unsigned short)a[j]) +
                               b2f((unsigned short)c[j])) * inv);
        *(short8*)&op[half * 8] = r;
    }
}

// ---------------- launch ------------------------------------------------------
extern "C" void kernel_launch(void* const* d_in, const int* in_sizes, int n_in,
                              void* d_out, int out_size, void* d_ws, size_t ws_size,
                              hipStream_t stream) {
    const float* x  = (const float*)d_in[0];
    const float* Wq = (const float*)d_in[1];
    const float* bq = (const float*)d_in[2];
    const float* Wk = (const float*)d_in[3];
    const float* bk = (const float*)d_in[4];
    const float* Wv = (const float*)d_in[5];
    const float* bv = (const float*)d_in[6];
    const float* Wo = (const float*)d_in[7];
    const float* bo = (const float*)d_in[8];
    float* out = (float*)d_out;

    constexpr size_t TSZ = (size_t)MROWS * DM;   // 4194304
    constexpr size_t WSZ = (size_t)DM * DM;      // 1048576
    ushort_t* xb  = (ushort_t*)d_ws;
    ushort_t* Wqt = xb + TSZ;
    ushort_t* Wkt = Wqt + WSZ;
    ushort_t* Wvt = Wkt + WSZ;
    ushort_t* Wot = Wvt + WSZ;
    ushort_t* qbp = Wot + WSZ;
    ushort_t* kbp = qbp + TSZ;
    ushort_t* vtp = kbp + TSZ;
    ushort_t* ctxb = vtp + TSZ;

    // attn partials alias regions that are dead by the time attn runs:
    // opart (1024 x 64 x 64 bf16 = TSZ ushorts) over xb; lpart (256 KB) over Wqt.
    ushort_t* opart = xb;
    float* lpart = (float*)Wqt;

    conv_x<<<TSZ / 8 / 256, 256, 0, stream>>>(x, xb);
    conv_w<<<dim3(16, 16, 4), 256, 0, stream>>>(Wq, Wk, Wv, Wo, Wqt, Wkt, Wvt, Wot);

    mfma_gemm_qkv<<<dim3(DM / BN, MROWS / BM, 3), 256, 0, stream>>>(
        xb, Wqt, Wkt, Wvt, bq, bk, bv, qbp, kbp, vtp);

    attn_mfma<<<dim3(BATCH * NH, 48), 256, 0, stream>>>(
        qbp, kbp, vtp, ctxb, opart, lpart);
    attn_reduce<<<dim3(BATCH * NH, 16), 256, 0, stream>>>(opart, lpart, ctxb);

    mfma_gemm_out<<<dim3(DM / BN, MROWS / BM), 256, 0, stream>>>(ctxb, Wot, bo, out);
}

// Round 10
// 116.285 us; speedup vs baseline: 17.3648x; 1.0103x over previous
//
#include <hip/hip_runtime.h>
#include <hip/hip_bf16.h>
#include <math.h>

// Problem constants
constexpr int DM = 1024;
constexpr int SEQ = 2048;
constexpr int BATCH = 2;
constexpr int NH = 16;
constexpr int DH = 64;
constexpr int MROWS = BATCH * SEQ;  // 4096
constexpr float SCALE = 0.125f;

typedef __attribute__((ext_vector_type(8))) short short8;
typedef __attribute__((ext_vector_type(4))) float f32x4;
typedef unsigned short ushort_t;

__device__ __forceinline__ unsigned short f2b(float f) {
    __hip_bfloat16 h = __float2bfloat16(f);
    return __builtin_bit_cast(unsigned short, h);
}
__device__ __forceinline__ float b2f(unsigned short u) {
    unsigned int t = ((unsigned int)u) << 16;
    return __builtin_bit_cast(float, t);
}
// v_cvt_pk_bf16_f32: D = {bf16(hi) : bf16(lo)} (no builtin on gfx950 -> asm)
__device__ __forceinline__ unsigned int cvtpk_bf16(float lo, float hi) {
    unsigned int r;
    asm("v_cvt_pk_bf16_f32 %0, %1, %2" : "=v"(r) : "v"(lo), "v"(hi));
    return r;
}
// v_mfma_f32_16x16x16_bf16: A,B = 4 bf16 (2 VGPRs); C/D = 4 f32.
__device__ __forceinline__ f32x4 mfma16_bf16(uint2 a, uint2 b, f32x4 c) {
    asm("v_mfma_f32_16x16x16_bf16 %0, %1, %2, %0"
        : "+v"(c) : "v"(a), "v"(b));
    return c;
}

__device__ __forceinline__ void gload16(const ushort_t* g, ushort_t* l) {
    __builtin_amdgcn_global_load_lds(
        (const __attribute__((address_space(1))) void*)g,
        (__attribute__((address_space(3))) void*)l, 16, 0, 0);
}

// ---------------- converters --------------------------------------------------
__global__ __launch_bounds__(256) void conv_x(const float* __restrict__ x,
                                              ushort_t* __restrict__ xb) {
    const size_t idx = (size_t)blockIdx.x * 256 + threadIdx.x;
    const float4* src = (const float4*)(x + idx * 8);
    float4 a = src[0], b = src[1];
    short8 v;
    v[0] = (short)f2b(a.x); v[1] = (short)f2b(a.y);
    v[2] = (short)f2b(a.z); v[3] = (short)f2b(a.w);
    v[4] = (short)f2b(b.x); v[5] = (short)f2b(b.y);
    v[6] = (short)f2b(b.z); v[7] = (short)f2b(b.w);
    *(short8*)(xb + idx * 8) = v;
}

// Transpose + convert weights: W [K][N] fp32 -> Wt [N][K] bf16
__global__ __launch_bounds__(256) void conv_w(
    const float* __restrict__ Wq, const float* __restrict__ Wk,
    const float* __restrict__ Wv, const float* __restrict__ Wo,
    ushort_t* __restrict__ Wqt, ushort_t* __restrict__ Wkt,
    ushort_t* __restrict__ Wvt, ushort_t* __restrict__ Wot) {
    const float* W; ushort_t* Wt;
    switch (blockIdx.z) {
        case 0:  W = Wq; Wt = Wqt; break;
        case 1:  W = Wk; Wt = Wkt; break;
        case 2:  W = Wv; Wt = Wvt; break;
        default: W = Wo; Wt = Wot; break;
    }
    __shared__ float L[64][65];
    const int n0 = blockIdx.x * 64, k0 = blockIdx.y * 64;
    const int t = threadIdx.x;
    const int tr = t >> 4, tc4 = (t & 15) * 4;
#pragma unroll
    for (int i = 0; i < 4; ++i) {
        int kk = tr + i * 16;
        float4 v = *(const float4*)&W[(size_t)(k0 + kk) * DM + n0 + tc4];
        L[kk][tc4 + 0] = v.x; L[kk][tc4 + 1] = v.y;
        L[kk][tc4 + 2] = v.z; L[kk][tc4 + 3] = v.w;
    }
    __syncthreads();
#pragma unroll
    for (int i = 0; i < 4; ++i) {
        int nn = tr + i * 16;
        ushort4 u;
        u.x = f2b(L[tc4 + 0][nn]); u.y = f2b(L[tc4 + 1][nn]);
        u.z = f2b(L[tc4 + 2][nn]); u.w = f2b(L[tc4 + 3][nn]);
        *(ushort4*)&Wt[(size_t)(n0 + nn) * DM + k0 + tc4] = u;
    }
}

// ---------------- MFMA GEMM core: 128x128 tile, BK=32, triple-buffered -------
// Counted-vmcnt pipeline (T4): per K-step wait vmcnt(4) (only the OLDEST
// stage drained; the next stays in flight across the barrier), raw s_barrier,
// issue stage kt+2, then ds_read+MFMA. 4 vmem insts per stage per wave.
// LDS superrow swizzle: buffer = 64 superrows (2 rows) x 8 slots x 16B.
// Element (r, c16) lives at slot p = (((r&1)<<2)|c16) ^ ((r>>1)&7): a b128
// read by 16 lanes hits all 8 slots 2x -> 2-way = free (m136).
#define BM 128
#define BN 128
#define BKK 32
#define NKT (DM / BKK)   // 32

__device__ __forceinline__ void stage_tile(const ushort_t* __restrict__ A,
                                           const ushort_t* __restrict__ B,
                                           int row0, int col0, int kt,
                                           ushort_t* As, ushort_t* Bs, int tid) {
#pragma unroll
    for (int i = 0; i < 2; ++i) {
        int f = i * 256 + tid;                    // [0,512)
        int sr = f >> 3, p = f & 7;
        int u = p ^ (sr & 7);
        int r = 2 * sr + (u >> 2);                // inverse-swizzled source
        int c = u & 3;
        gload16(&A[(size_t)(row0 + r) * DM + kt * BKK + c * 8], &As[f * 8]);
        gload16(&B[(size_t)(col0 + r) * DM + kt * BKK + c * 8], &Bs[f * 8]);
    }
}

__device__ __forceinline__ void mfma_core(const ushort_t* __restrict__ A,
                                          const ushort_t* __restrict__ B,
                                          int row0, int col0,
                                          ushort_t* smem, f32x4 (&acc)[4][4]) {
    const int tid = threadIdx.x;
    const int wave = tid >> 6, lane = tid & 63;
    const int lg = lane >> 4, ln = lane & 15;
    const int wr = wave >> 1, wc = wave & 1;

    // prologue: stages 0 and 1 in flight (order pinned for FIFO vmcnt math)
    stage_tile(A, B, row0, col0, 0, smem, smem + 4096, tid);
    __builtin_amdgcn_sched_barrier(0);
    stage_tile(A, B, row0, col0, 1, smem + 8192, smem + 12288, tid);

    for (int kt = 0; kt < NKT; ++kt) {
        if (kt + 1 < NKT)
            asm volatile("s_waitcnt vmcnt(4)" ::: "memory");
        else
            asm volatile("s_waitcnt vmcnt(0)" ::: "memory");
        __builtin_amdgcn_s_barrier();

        // issue stage kt+2 early; it flies across this step's compute
        if (kt + 2 < NKT) {
            ushort_t* An = smem + ((kt + 2) % 3) * 8192;
            stage_tile(A, B, row0, col0, kt + 2, An, An + 4096, tid);
        }

        const ushort_t* As = smem + (kt % 3) * 8192;
        const ushort_t* Bs = As + 4096;
        short8 af[4], bf[4];
#pragma unroll
        for (int mi = 0; mi < 4; ++mi) {
            int r = wr * 64 + mi * 16 + ln;
            int sr = r >> 1;
            int p = (((r & 1) << 2) | lg) ^ (sr & 7);
            af[mi] = *(const short8*)&As[sr * 64 + p * 8];
        }
#pragma unroll
        for (int ni = 0; ni < 4; ++ni) {
            int r = wc * 64 + ni * 16 + ln;
            int sr = r >> 1;
            int p = (((r & 1) << 2) | lg) ^ (sr & 7);
            bf[ni] = *(const short8*)&Bs[sr * 64 + p * 8];
        }
        __builtin_amdgcn_s_setprio(1);
#pragma unroll
        for (int mi = 0; mi < 4; ++mi)
#pragma unroll
            for (int ni = 0; ni < 4; ++ni)
                acc[mi][ni] = __builtin_amdgcn_mfma_f32_16x16x32_bf16(
                    af[mi], bf[ni], acc[mi][ni], 0, 0, 0);
        __builtin_amdgcn_s_setprio(0);
    }
}

// QKV: z=0 -> qb [B,H,S,DH]; z=1 -> kb; z=2 -> vtb [B,H,DH,S]; all bf16 +bias.
// Partial RoPE (rot dim 16) fused into the q/k scatter.
__global__ __launch_bounds__(256) void mfma_gemm_qkv(
    const ushort_t* __restrict__ xb,
    const ushort_t* __restrict__ Wqt, const ushort_t* __restrict__ Wkt,
    const ushort_t* __restrict__ Wvt,
    const float* __restrict__ bq, const float* __restrict__ bk,
    const float* __restrict__ bv,
    ushort_t* __restrict__ qb, ushort_t* __restrict__ kb,
    ushort_t* __restrict__ vtb) {
    const ushort_t* W; const float* bias;
    if (blockIdx.z == 0)      { W = Wqt; bias = bq; }
    else if (blockIdx.z == 1) { W = Wkt; bias = bk; }
    else                      { W = Wvt; bias = bv; }

    const int row0 = blockIdx.y * BM;
    const int col0 = blockIdx.x * BN;
    __shared__ ushort_t smem[24576];   // 48 KB: 3 stage buffers; Cs aliases
    f32x4 acc[4][4] = {};
    mfma_core(xb, W, row0, col0, smem, acc);

    const int tid = threadIdx.x;
    const int wave = tid >> 6, lane = tid & 63;
    const int lg = lane >> 4, ln = lane & 15;
    const int wr = wave >> 1, wc = wave & 1;
    const bool isV = (blockIdx.z == 2);

    __syncthreads();
    ushort_t* Cs = smem;
#pragma unroll
    for (int mi = 0; mi < 4; ++mi)
#pragma unroll
        for (int ni = 0; ni < 4; ++ni)
#pragma unroll
            for (int r = 0; r < 4; ++r) {
                int mrel = wr * 64 + mi * 16 + lg * 4 + r;
                int nrel = wc * 64 + ni * 16 + ln;
                float v = acc[mi][ni][r] + bias[col0 + nrel];
                Cs[isV ? (nrel * 128 + mrel) : (mrel * 128 + nrel)] = f2b(v);
            }
    __syncthreads();

    if (!isV) {
        ushort_t* out = (blockIdx.z == 0) ? qb : kb;
#pragma unroll
        for (int i = 0; i < 8; ++i) {
            int f = i * 256 + tid;
            int rrow = f >> 4, c8 = f & 15;
            int m = row0 + rrow;
            int b = m >> 11, s = m & (SEQ - 1);
            int n = col0 + c8 * 8;
            int h = n >> 6, d = n & 63;
            short8 val;
            if (d < 16) {
                const ushort_t* base = &Cs[rrow * 128 + (c8 & 8) * 8];
                const bool hi = (d >= 8);
#pragma unroll
                for (int j = 0; j < 8; ++j) {
                    float t1 = b2f(base[j]);
                    float t2 = b2f(base[8 + j]);
                    float invf = __expf(-(float)j * 1.1512925465f); // ln(1e4)/8
                    float ang = (float)s * invf;
                    float c_, si_;
                    __sincosf(ang, &si_, &c_);
                    val[j] = (short)f2b(hi ? (t1 * si_ + t2 * c_)
                                           : (t1 * c_ - t2 * si_));
                }
            } else {
                val = *(const short8*)&Cs[rrow * 128 + c8 * 8];
            }
            *(short8*)&out[((size_t)((b * NH + h) * SEQ) + s) * DH + d] = val;
        }
    } else {
#pragma unroll
        for (int i = 0; i < 8; ++i) {
            int f = i * 256 + tid;
            int nrow = f >> 4, c8 = f & 15;
            int n = col0 + nrow;
            int h = n >> 6, d = n & 63;
            int m = row0 + c8 * 8;
            int b = m >> 11, s = m & (SEQ - 1);
            *(short8*)&vtb[((size_t)((b * NH + h) * DH) + d) * SEQ + s] =
                *(const short8*)&Cs[nrow * 128 + c8 * 8];
        }
    }
}

// Output projection: A = ctxb bf16 [M][DM], B = Wot, out fp32 [M][DM] + bo.
__global__ __launch_bounds__(256) void mfma_gemm_out(
    const ushort_t* __restrict__ ctxb, const ushort_t* __restrict__ Wot,
    const float* __restrict__ bo, float* __restrict__ out) {
    const int row0 = blockIdx.y * BM;
    const int col0 = blockIdx.x * BN;
    __shared__ ushort_t smem[24576];
    f32x4 acc[4][4] = {};
    mfma_core(ctxb, Wot, row0, col0, smem, acc);

    const int tid = threadIdx.x;
    const int wave = tid >> 6, lane = tid & 63;
    const int lg = lane >> 4, ln = lane & 15;
    const int wr = wave >> 1, wc = wave & 1;
#pragma unroll
    for (int mi = 0; mi < 4; ++mi)
#pragma unroll
        for (int ni = 0; ni < 4; ++ni)
#pragma unroll
            for (int r = 0; r < 4; ++r) {
                int m = row0 + wr * 64 + mi * 16 + lg * 4 + r;
                int n = col0 + wc * 64 + ni * 16 + ln;
                out[(size_t)m * DM + n] = acc[mi][ni][r] + bo[n];
            }
}

// ---------------- Causal flash attention, k-split partials -------------------
// Fixed-max softmax => partial (o, l) over disjoint key ranges are ADDITIVE.
//   y in [0,16):  qt = 16+y,  tiles [0,16)      -> partial chunk 0 (len 16)
//   y in [16,32): qt = 47-y,  tiles [16,qt+1)   -> partial chunk 1 (len 16..1)
//   y in [32,48): qt = 47-y,  tiles [0,qt+1)    -> direct ctx write (len 16..1)
#define AQT 64
#define AKT 64
#define NQT (SEQ / AQT)   // 32

__global__ __launch_bounds__(256) void attn_mfma(
    const ushort_t* __restrict__ qb, const ushort_t* __restrict__ kb,
    const ushort_t* __restrict__ vtb, ushort_t* __restrict__ ctxb,
    ushort_t* __restrict__ opart, float* __restrict__ lpart) {
    constexpr float C1 = 0.18033688f;        // SCALE * log2(e)
    constexpr float M2 = 1.44269504f;        // C1 * 8 (score bound 8 sigma)
    const int bh = blockIdx.x;
    const int y = blockIdx.y;

    int qt, t0, t1, chunk;
    if (y < 16)      { qt = 16 + y;  t0 = 0;  t1 = 16;     chunk = 0; }
    else if (y < 32) { qt = 47 - y;  t0 = 16; t1 = qt + 1; chunk = 1; }
    else             { qt = 47 - y;  t0 = 0;  t1 = qt + 1; chunk = -1; }
    const int q0 = qt * AQT;

    const int tid = threadIdx.x;
    const int wave = tid >> 6;
    const int lane = tid & 63;
    const int lg = lane >> 4;
    const int ln = lane & 15;

    __shared__ ushort_t KT[2][64 * 64];
    __shared__ ushort_t VT[2][64 * 64];

    const ushort_t* kbase = kb + (size_t)bh * SEQ * DH;
    const ushort_t* vbase = vtb + (size_t)bh * DH * SEQ;
    const int b = bh >> 4, h = bh & 15;

    const ushort_t* qrow = qb + ((size_t)bh * SEQ + q0 + wave * 16 + ln) * DH;
    short8 qf0 = *(const short8*)&qrow[lg * 8];
    short8 qf1 = *(const short8*)&qrow[32 + lg * 8];

    f32x4 o[4];
#pragma unroll
    for (int nt = 0; nt < 4; nt++) o[nt] = f32x4{0.f, 0.f, 0.f, 0.f};
    float l = 0.f;                        // per-lane partial for q-row = ln

    // prologue: stage tile t0 into buffer 0
#pragma unroll
    for (int i = 0; i < 2; i++) {
        int f = i * 256 + tid;
        int r = f >> 3, p = f & 7, c = p ^ (r & 7);
        gload16(&kbase[(size_t)(t0 * AKT + r) * DH + c * 8], &KT[0][f * 8]);
        gload16(&vbase[(size_t)r * SEQ + t0 * AKT + c * 8], &VT[0][f * 8]);
    }

    int cur = 0;
    for (int t = t0; t < t1; ++t) {
        __syncthreads();   // staged data for tile t visible

        if (t + 1 < t1) {
            const int nb0 = (t + 1) * AKT;
            const int nxt = cur ^ 1;
#pragma unroll
            for (int i = 0; i < 2; i++) {
                int f = i * 256 + tid;
                int r = f >> 3, p = f & 7, c = p ^ (r & 7);
                gload16(&kbase[(size_t)(nb0 + r) * DH + c * 8], &KT[nxt][f * 8]);
                gload16(&vbase[(size_t)r * SEQ + nb0 + c * 8], &VT[nxt][f * 8]);
            }
        }

        // ---- swapped QK^T: st[kt][r] = S[key=16kt+lg*4+r][q=ln]
        float st[4][4];
        __builtin_amdgcn_s_setprio(1);
#pragma unroll
        for (int kt = 0; kt < 4; kt++) {
            f32x4 acc = f32x4{0.f, 0.f, 0.f, 0.f};
            int krow = kt * 16 + ln;
            short8 b0 = *(const short8*)&KT[cur][krow * 64 + ((lg ^ (krow & 7)) * 8)];
            short8 b1 = *(const short8*)&KT[cur][krow * 64 + (((4 + lg) ^ (krow & 7)) * 8)];
            acc = __builtin_amdgcn_mfma_f32_16x16x32_bf16(b0, qf0, acc, 0, 0, 0);
            acc = __builtin_amdgcn_mfma_f32_16x16x32_bf16(b1, qf1, acc, 0, 0, 0);
#pragma unroll
            for (int r = 0; r < 4; r++) st[kt][r] = acc[r];
        }
        __builtin_amdgcn_s_setprio(0);

        // causal mask only on the diagonal tile (t == qt; never in chunk 0)
        if (t == qt) {
            const int qrel = wave * 16 + ln;
#pragma unroll
            for (int kt = 0; kt < 4; kt++)
#pragma unroll
                for (int r = 0; r < 4; r++)
                    if (kt * 16 + lg * 4 + r > qrel) st[kt][r] = -1e30f;
        }

        // ---- fixed-max softmax: p = exp2(C1*s - M2); P packed in registers
        uint2 pkq[4];
#pragma unroll
        for (int kt = 0; kt < 4; kt++) {
            float pv[4];
#pragma unroll
            for (int r = 0; r < 4; r++) {
                pv[r] = exp2f(fmaf(C1, st[kt][r], -M2));
                l += pv[r];
            }
            pkq[kt].x = cvtpk_bf16(pv[0], pv[1]);
            pkq[kt].y = cvtpk_bf16(pv[2], pv[3]);
        }

        // ---- PV: o[nt] += P(16x16 A-frag, reg) x V^T(8B LDS reads)
        __builtin_amdgcn_s_setprio(1);
#pragma unroll
        for (int nt = 0; nt < 4; nt++) {
            int vrow = nt * 16 + ln;
#pragma unroll
            for (int kt = 0; kt < 4; kt++) {
                int chunk16 = (2 * kt + (lg >> 1)) ^ (vrow & 7);
                uint2 vb = *(const uint2*)&VT[cur][vrow * 64 + chunk16 * 8 + (lg & 1) * 4];
                o[nt] = mfma16_bf16(pkq[kt], vb, o[nt]);
            }
        }
        __builtin_amdgcn_s_setprio(0);

        cur ^= 1;
    }

    // ---- epilogue
    l += __shfl_xor(l, 16);
    l += __shfl_xor(l, 32);

    if (chunk >= 0) {
        // partial: write bf16 o (undivided) + f32 l
        const int pid = ((bh << 4) + (qt - 16)) * 2 + chunk;
        if (lg == 0) lpart[pid * 64 + wave * 16 + ln] = l;
        ushort_t* ob = opart + (size_t)pid * 4096;
#pragma unroll
        for (int r = 0; r < 4; r++) {
            int qrel = wave * 16 + lg * 4 + r;
#pragma unroll
            for (int nt = 0; nt < 4; nt++)
                ob[qrel * 64 + nt * 16 + ln] = f2b(o[nt][r]);
        }
    } else {
        const float rcp = 1.f / l;
#pragma unroll
        for (int r = 0; r < 4; r++) {
            float invl = __shfl(rcp, (lane & 48) | (lg * 4 + r));
            int qg = q0 + wave * 16 + lg * 4 + r;
            ushort_t* op = ctxb + ((size_t)(b * SEQ + qg)) * DM + h * DH;
#pragma unroll
            for (int nt = 0; nt < 4; nt++)
                op[nt * 16 + ln] = f2b(o[nt][r] * invl);
        }
    }
}

// Combine the two partials for qt >= 16: ctx = (o0 + o1) / (l0 + l1).
__global__ __launch_bounds__(256) void attn_reduce(
    const ushort_t* __restrict__ opart, const float* __restrict__ lpart,
    ushort_t* __restrict__ ctxb) {
    const int bh = blockIdx.x;             // 0..31
    const int qt = 16 + blockIdx.y;        // 16..31
    const int tid = threadIdx.x;
    const int q = tid >> 2;                // 0..63
    const int d0 = (tid & 3) * 16;         // 0,16,32,48

    const int pid0 = ((bh << 4) + (qt - 16)) * 2;
    const ushort_t* o0 = opart + (size_t)pid0 * 4096 + q * 64 + d0;
    const ushort_t* o1 = opart + (size_t)(pid0 + 1) * 4096 + q * 64 + d0;
    const float inv = 1.f / (lpart[pid0 * 64 + q] + lpart[(pid0 + 1) * 64 + q]);

    const int b = bh >> 4, h = bh & 15;
    ushort_t* op = ctxb + ((size_t)(b * SEQ + qt * 64 + q)) * DM + h * DH + d0;
#pragma unroll
    for (int half = 0; half < 2; ++half) {
        short8 a = *(const short8*)&o0[half * 8];
        short8 c = *(const short8*)&o1[half * 8];
        short8 r;
#pragma unroll
        for (int j = 0; j < 8; ++j)
            r[j] = (short)f2b((b2f((unsigned short)a[j]) +
                               b2f((unsigned short)c[j])) * inv);
        *(short8*)&op[half * 8] = r;
    }
}

// ---------------- launch ------------------------------------------------------
extern "C" void kernel_launch(void* const* d_in, const int* in_sizes, int n_in,
                              void* d_out, int out_size, void* d_ws, size_t ws_size,
                              hipStream_t stream) {
    const float* x  = (const float*)d_in[0];
    const float* Wq = (const float*)d_in[1];
    const float* bq = (const float*)d_in[2];
    const float* Wk = (const float*)d_in[3];
    const float* bk = (const float*)d_in[4];
    const float* Wv = (const float*)d_in[5];
    const float* bv = (const float*)d_in[6];
    const float* Wo = (const float*)d_in[7];
    const float* bo = (const float*)d_in[8];
    float* out = (float*)d_out;

    constexpr size_t TSZ = (size_t)MROWS * DM;   // 4194304
    constexpr size_t WSZ = (size_t)DM * DM;      // 1048576
    ushort_t* xb  = (ushort_t*)d_ws;
    ushort_t* Wqt = xb + TSZ;
    ushort_t* Wkt = Wqt + WSZ;
    ushort_t* Wvt = Wkt + WSZ;
    ushort_t* Wot = Wvt + WSZ;
    ushort_t* qbp = Wot + WSZ;
    ushort_t* kbp = qbp + TSZ;
    ushort_t* vtp = kbp + TSZ;
    ushort_t* ctxb = vtp + TSZ;

    // attn partials alias regions dead by the time attn runs.
    ushort_t* opart = xb;
    float* lpart = (float*)Wqt;

    conv_x<<<TSZ / 8 / 256, 256, 0, stream>>>(x, xb);
    conv_w<<<dim3(16, 16, 4), 256, 0, stream>>>(Wq, Wk, Wv, Wo, Wqt, Wkt, Wvt, Wot);

    mfma_gemm_qkv<<<dim3(DM / BN, MROWS / BM, 3), 256, 0, stream>>>(
        xb, Wqt, Wkt, Wvt, bq, bk, bv, qbp, kbp, vtp);

    attn_mfma<<<dim3(BATCH * NH, 48), 256, 0, stream>>>(
        qbp, kbp, vtp, ctxb, opart, lpart);
    attn_reduce<<<dim3(BATCH * NH, 16), 256, 0, stream>>>(opart, lpart, ctxb);

    mfma_gemm_out<<<dim3(DM / BN, MROWS / BM), 256, 0, stream>>>(ctxb, Wot, bo, out);
}